// Round 18
// baseline (286.184 us; speedup 1.0000x reference)
//
#include <hip/hip_runtime.h>
#include <cstdint>
#include <cstddef>

#define BATCH 2
#define SEQ 2048
#define DMODEL 1024
#define NHEAD 16
#define DFF 4096
#define MTOT (BATCH * SEQ) /* 4096 */

typedef __bf16 bf16x8 __attribute__((ext_vector_type(8)));
typedef __bf16 bf16x4 __attribute__((ext_vector_type(4)));
typedef short s16x4 __attribute__((ext_vector_type(4)));
typedef float f32x4 __attribute__((ext_vector_type(4)));

#define S_BARRIER() __builtin_amdgcn_s_barrier()
#define SCHED_FENCE() __builtin_amdgcn_sched_barrier(0)
#define VMCNT8() asm volatile("s_waitcnt vmcnt(8)" ::: "memory")
#define VMCNT4() asm volatile("s_waitcnt vmcnt(4)" ::: "memory")
#define VMCNT0() asm volatile("s_waitcnt vmcnt(0)" ::: "memory")

// async global->LDS, 16B/lane; LDS dest = wave-uniform base + lane*16 (m104).
__device__ __forceinline__ void gload_lds16(const void* g, void* l) {
  __builtin_amdgcn_global_load_lds(
      (__attribute__((address_space(1))) void*)(uintptr_t)g,
      (__attribute__((address_space(3))) void*)(uint32_t)(uintptr_t)l,
      16, 0, 0);
}

// ---------------------------------------------------------------------------
// fp32 [K,N] -> bf16 [N,K] transpose (weights -> B^T layout)
// ---------------------------------------------------------------------------
__global__ __launch_bounds__(256) void k_transpose_to_bf16(
    const float* __restrict__ w, __bf16* __restrict__ wt, int K, int N) {
  __shared__ float t[32][33];
  const int n0 = blockIdx.x * 32, k0 = blockIdx.y * 32;
  const int tx = threadIdx.x & 31, ty = threadIdx.x >> 5;
#pragma unroll
  for (int i = ty; i < 32; i += 8) t[i][tx] = w[(size_t)(k0 + i) * N + n0 + tx];
  __syncthreads();
#pragma unroll
  for (int i = ty; i < 32; i += 8)
    wt[(size_t)(n0 + i) * K + k0 + tx] = (__bf16)t[tx][i];
}

__global__ __launch_bounds__(256) void k_cvt_bf16(
    const float* __restrict__ in, __bf16* __restrict__ out, int n) {
  const int i = (blockIdx.x * 256 + threadIdx.x) * 4;
  if (i >= n) return;
  const float4 v = *(const float4*)(in + i);
  bf16x4 r;
  r[0] = (__bf16)v.x; r[1] = (__bf16)v.y; r[2] = (__bf16)v.z; r[3] = (__bf16)v.w;
  *(bf16x4*)(out + i) = r;
}

__global__ void k_concat3(const float* __restrict__ a, const float* __restrict__ b,
                          const float* __restrict__ c, float* __restrict__ o) {
  const int i = blockIdx.x * 256 + threadIdx.x;
  if (i >= 3072) return;
  o[i] = (i < 1024) ? a[i] : (i < 2048) ? b[i - 1024] : c[i - 2048];
}

// mask * log2(e) for exp2-domain softmax
__global__ void k_scale_mask(const float* __restrict__ in, float* __restrict__ o, int n) {
  const int i = blockIdx.x * 256 + threadIdx.x;
  if (i < n) o[i] = in[i] * 1.44269504f;
}

// bf16 V-section transpose: qkvb[b*S+s][2048+c] -> vT[b*1024+c][s]
__global__ __launch_bounds__(256) void k_transpose_v(
    const __bf16* __restrict__ qkvb, __bf16* __restrict__ vT) {
  __shared__ __bf16 t[32][33];
  const int s0 = blockIdx.x * 32, c0 = blockIdx.y * 32, b = blockIdx.z;
  const int tx = threadIdx.x & 31, ty = threadIdx.x >> 5;
#pragma unroll
  for (int i = ty; i < 32; i += 8)
    t[i][tx] = qkvb[(size_t)(b * SEQ + s0 + i) * 3072 + 2048 + c0 + tx];
  __syncthreads();
#pragma unroll
  for (int i = ty; i < 32; i += 8)
    vT[((size_t)b * 1024 + c0 + i) * SEQ + s0 + tx] = t[tx][i];
}

// ---------------------------------------------------------------------------
// 256x256 deep-pipelined MFMA GEMM (T3+T4 counted-vmcnt, ALL-BUILTIN MFMAs).
// R16-verified. 512 thr = 8 waves (2M x 4N); wave owns 128x64.
// ---------------------------------------------------------------------------
template <bool RELU, typename OutT>
__global__ __launch_bounds__(512) void k_gemm256(
    const __bf16* __restrict__ A, const __bf16* __restrict__ BT,
    const float* __restrict__ bias, OutT* __restrict__ C,
    int M, int N, int K) {
  __shared__ __align__(16) __bf16 sA[4 * 8192];
  __shared__ __align__(16) __bf16 sB[4 * 8192];
  const int tid = threadIdx.x, lane = tid & 63, wv = tid >> 6;
  const int wm = wv >> 2, wn = wv & 3;
  const int lrow = lane & 15, hi = lane >> 4;
  const int nwg = gridDim.x * gridDim.y;
  const int flat = blockIdx.y * gridDim.x + blockIdx.x;
  const int cpx = nwg >> 3;
  const int swzb = (flat & 7) * cpx + (flat >> 3);
  const int m0 = (swzb / gridDim.x) * 256;
  const int n0 = (swzb % gridDim.x) * 256;
  const int NT = K >> 6;

  const int lsub = lane >> 2;
  const int gg = (lane & 3) ^ ((lane >> 3) & 3);
  const int gr = hi ^ ((lrow >> 1) & 3);

  f32x4 acc[8][4];
#pragma unroll
  for (int r = 0; r < 8; ++r)
#pragma unroll
    for (int c = 0; c < 4; ++c) acc[r][c] = f32x4{0.f, 0.f, 0.f, 0.f};

  auto stage = [&](int p) {
    const int tile = p >> 1;
    const int slot = (((tile & 1) * 2) + (p & 1)) * 8192;
    const int kcol = tile * 64 + (p & 1) * 32 + gg * 8;
#pragma unroll
    for (int i = 0; i < 2; ++i) {
      const int c = wv * 2 + i;
      gload_lds16(A + (size_t)(m0 + c * 16 + lsub) * K + kcol, &sA[slot + c * 512]);
      gload_lds16(BT + (size_t)(n0 + c * 16 + lsub) * K + kcol, &sB[slot + c * 512]);
    }
  };

  auto compute = [&](int p) {
    const int slot = ((((p >> 1) & 1) * 2) + (p & 1)) * 8192;
    bf16x8 af[8], bfv[4];
#pragma unroll
    for (int r = 0; r < 8; ++r)
      af[r] = *(const bf16x8*)&sA[slot + (wm * 128 + r * 16 + lrow) * 32 + gr * 8];
#pragma unroll
    for (int c = 0; c < 4; ++c)
      bfv[c] = *(const bf16x8*)&sB[slot + (wn * 64 + c * 16 + lrow) * 32 + gr * 8];
    __builtin_amdgcn_s_setprio(1);
#pragma unroll
    for (int r = 0; r < 8; ++r)
#pragma unroll
      for (int c = 0; c < 4; ++c)
        acc[r][c] = __builtin_amdgcn_mfma_f32_16x16x32_bf16(af[r], bfv[c],
                                                            acc[r][c], 0, 0, 0);
    __builtin_amdgcn_s_setprio(0);
  };

  stage(0); stage(1); stage(2);
  int p = 0;
  for (; p < 2 * NT - 3; ++p) {
    VMCNT8(); S_BARRIER(); SCHED_FENCE();
    stage(p + 3);
    compute(p);
  }
  VMCNT8(); S_BARRIER(); SCHED_FENCE(); compute(p); ++p;
  VMCNT4(); S_BARRIER(); SCHED_FENCE(); compute(p); ++p;
  VMCNT0(); S_BARRIER(); SCHED_FENCE(); compute(p);

#pragma unroll
  for (int r = 0; r < 8; ++r) {
    const int row = m0 + wm * 128 + r * 16 + hi * 4;
#pragma unroll
    for (int c = 0; c < 4; ++c) {
      const int col = n0 + wn * 64 + c * 16 + lrow;
      const float bb = bias[col];
#pragma unroll
      for (int j = 0; j < 4; ++j) {
        float v = acc[r][c][j] + bb;
        if (RELU) v = fmaxf(v, 0.f);
        C[(size_t)(row + j) * N + col] = (OutT)v;
      }
    }
  }
}

// ---------------------------------------------------------------------------
// bf16 MFMA GEMM (R9-verified: round-2 body + XCD swizzle, plain epilogue).
// BM=MF*32, BN=128, BK=64, 4 waves (2x2). Used for N=1024 GEMMs.
// ---------------------------------------------------------------------------
template <int MF, bool RELU, typename OutT>
__global__ __launch_bounds__(256) void k_gemm(
    const __bf16* __restrict__ A, const __bf16* __restrict__ BT,
    const float* __restrict__ bias, OutT* __restrict__ C, int M, int N, int K) {
  __shared__ __bf16 sA[MF * 32 * 64];
  __shared__ __bf16 sB[128 * 64];
  const int tid = threadIdx.x, lane = tid & 63, wv = tid >> 6;
  const int wm = wv >> 1, wn = wv & 1;
  const int lrow = lane & 15, hi = lane >> 4;
  const int nwg = gridDim.x * gridDim.y;
  const int flat = blockIdx.y * gridDim.x + blockIdx.x;
  const int cpx = nwg >> 3;
  const int swzb = (flat & 7) * cpx + (flat >> 3);
  const int m0 = (swzb / gridDim.x) * (MF * 32);
  const int n0 = (swzb % gridDim.x) * 128;
  const int srow = lane >> 3;
  const int scolE = ((lane & 7) ^ srow) * 8;
  const int swz = (lrow & 7) << 4;

  f32x4 acc[MF][4];
#pragma unroll
  for (int r = 0; r < MF; ++r)
#pragma unroll
    for (int c = 0; c < 4; ++c) acc[r][c] = f32x4{0.f, 0.f, 0.f, 0.f};

  for (int k0 = 0; k0 < K; k0 += 64) {
    __syncthreads();
#pragma unroll
    for (int rb = wv; rb < MF * 4; rb += 4) {
      const int row = rb * 8 + srow;
      gload_lds16(A + (size_t)(m0 + row) * K + k0 + scolE, &sA[rb * 512]);
    }
#pragma unroll
    for (int rb = wv; rb < 16; rb += 4) {
      const int row = rb * 8 + srow;
      gload_lds16(BT + (size_t)(n0 + row) * K + k0 + scolE, &sB[rb * 512]);
    }
    __syncthreads();
#pragma unroll
    for (int kc = 0; kc < 2; ++kc) {
      bf16x8 af[MF], bfr[4];
#pragma unroll
      for (int r = 0; r < MF; ++r) {
        const int row = wm * (MF * 16) + r * 16 + lrow;
        af[r] = *(const bf16x8*)((const char*)sA + row * 128 + ((kc * 64 + hi * 16) ^ swz));
      }
#pragma unroll
      for (int c = 0; c < 4; ++c) {
        const int row = wn * 64 + c * 16 + lrow;
        bfr[c] = *(const bf16x8*)((const char*)sB + row * 128 + ((kc * 64 + hi * 16) ^ swz));
      }
#pragma unroll
      for (int r = 0; r < MF; ++r)
#pragma unroll
        for (int c = 0; c < 4; ++c)
          acc[r][c] = __builtin_amdgcn_mfma_f32_16x16x32_bf16(af[r], bfr[c],
                                                              acc[r][c], 0, 0, 0);
    }
  }

#pragma unroll
  for (int r = 0; r < MF; ++r) {
    const int row = m0 + wm * (MF * 16) + r * 16 + hi * 4;
#pragma unroll
    for (int c = 0; c < 4; ++c) {
      const int col = n0 + wn * 64 + c * 16 + lrow;
      const float bb = bias[col];
#pragma unroll
      for (int j = 0; j < 4; ++j) {
        float v = acc[r][c][j] + bb;
        if (RELU) v = fmaxf(v, 0.f);
        C[(size_t)(row + j) * N + col] = (OutT)v;
      }
    }
  }
}

// ---------------------------------------------------------------------------
// Flash attention, SPLIT-K x2 over keys: blockIdx.z = split*BATCH + b; each
// block processes keys [split*1024, split*1024+1024) with the R13-verified
// single-buffer sync->gload->sync protocol (16KB LDS -> 8 blocks/CU -> 32
// waves/CU, double the old 16-wave invariant). Softmax body = R17-verified
// (exp2-domain + defer-max, all-builtin MFMAs). Emits UNNORMALIZED O (f32)
// + per-row l,m partials; k_merge combines the two splits exactly.
// ---------------------------------------------------------------------------
__global__ __launch_bounds__(256) void k_attn(
    const __bf16* __restrict__ qkv, const __bf16* __restrict__ vT,
    const float* __restrict__ mask2, float* __restrict__ po,
    float* __restrict__ pl, float* __restrict__ pmv) {
  const int qb = blockIdx.x, h = blockIdx.y, bz = blockIdx.z;
  const int b = bz & 1, split = bz >> 1;
  const int koff = split * (SEQ / 2);
  const int tid = threadIdx.x, lane = tid & 63, wv = tid >> 6;
  const int lrow = lane & 15, hi = lane >> 4;

  __shared__ __bf16 sK[64 * 64];  // [key][d], swizzled
  __shared__ __bf16 sV[64 * 64];  // [d][key], swizzled

  const size_t base = (size_t)b * SEQ * 3072;
  const __bf16* Qb = qkv + base + h * 64;
  const __bf16* Kb = qkv + base + 1024 + h * 64;
  const __bf16* vTb = vT + ((size_t)b * 1024 + h * 64) * SEQ;
  const float* maskb = mask2 + (size_t)b * SEQ;

  const int q0 = qb * 64 + wv * 16;
  const bf16x8 qf0 = *(const bf16x8*)&Qb[(size_t)(q0 + lrow) * 3072 + hi * 8];
  const bf16x8 qf1 = *(const bf16x8*)&Qb[(size_t)(q0 + lrow) * 3072 + 32 + hi * 8];

  float m_r = -3e38f, l_r = 0.f;
  f32x4 o[4];
#pragma unroll
  for (int d = 0; d < 4; ++d) o[d] = f32x4{0.f, 0.f, 0.f, 0.f};

  const int srow = lane >> 3;
  const int scolE = ((lane & 7) ^ srow) * 8;
  const int swz = (lrow & 7) << 4;

  for (int k0 = 0; k0 < SEQ / 2; k0 += 64) {
    __syncthreads();
#pragma unroll
    for (int r = 0; r < 2; ++r) {
      const int rb = r * 4 + wv;
      const int row = rb * 8 + srow;
      gload_lds16(Kb + (size_t)(koff + k0 + row) * 3072 + scolE, &sK[rb * 512]);
      gload_lds16(vTb + (size_t)row * SEQ + koff + k0 + scolE, &sV[rb * 512]);
    }
    __syncthreads();

    // S^T = K * Q^T : st[t4][j] = S[key = t4*16 + 4hi + j][q = lrow]
    f32x4 st[4];
#pragma unroll
    for (int t4 = 0; t4 < 4; ++t4) {
      const char* rp = (const char*)sK + (t4 * 16 + lrow) * 128;
      const bf16x8 ka = *(const bf16x8*)(rp + ((hi * 16) ^ swz));
      const bf16x8 kb = *(const bf16x8*)(rp + ((64 + hi * 16) ^ swz));
      f32x4 a = f32x4{0.f, 0.f, 0.f, 0.f};
      a = __builtin_amdgcn_mfma_f32_16x16x32_bf16(ka, qf0, a, 0, 0, 0);
      a = __builtin_amdgcn_mfma_f32_16x16x32_bf16(kb, qf1, a, 0, 0, 0);
      st[t4] = a;
    }

    // exp2-domain logits: st*0.125*log2e + mask2
    float pm = -3e38f;
#pragma unroll
    for (int t4 = 0; t4 < 4; ++t4) {
      const f32x4 mk = *(const f32x4*)&maskb[koff + k0 + t4 * 16 + hi * 4];
#pragma unroll
      for (int j = 0; j < 4; ++j) {
        st[t4][j] = st[t4][j] * 0.18033688f + mk[j];
        pm = fmaxf(pm, st[t4][j]);
      }
    }
    pm = fmaxf(pm, __shfl_xor(pm, 16));
    pm = fmaxf(pm, __shfl_xor(pm, 32));

    // T13 defer-max
    if (__any(pm > m_r + 11.5f)) {
      const float mn = fmaxf(m_r, pm);
      const float so = __builtin_amdgcn_exp2f(m_r - mn);
      m_r = mn;
      l_r *= so;
      float so_o[4];
#pragma unroll
      for (int jj = 0; jj < 4; ++jj) so_o[jj] = __shfl(so, hi * 4 + jj);
#pragma unroll
      for (int d = 0; d < 4; ++d)
#pragma unroll
        for (int jj = 0; jj < 4; ++jj) o[d][jj] *= so_o[jj];
    }

    float rs = 0.f;
#pragma unroll
    for (int t4 = 0; t4 < 4; ++t4)
#pragma unroll
      for (int j = 0; j < 4; ++j) {
        st[t4][j] = __builtin_amdgcn_exp2f(st[t4][j] - m_r);
        rs += st[t4][j];
      }
    rs += __shfl_xor(rs, 16);
    rs += __shfl_xor(rs, 32);
    l_r += rs;

    // P -> bf16 A-frags of 16x16x16 (k = 4hi+j)
    s16x4 pa[4];
#pragma unroll
    for (int t4 = 0; t4 < 4; ++t4)
#pragma unroll
      for (int j = 0; j < 4; ++j) {
        const __bf16 pb = (__bf16)st[t4][j];
        pa[t4][j] = __builtin_bit_cast(short, pb);
      }

#pragma unroll
    for (int d = 0; d < 4; ++d) {
      const char* rp = (const char*)sV + (d * 16 + lrow) * 128;
#pragma unroll
      for (int t4 = 0; t4 < 4; ++t4) {
        const s16x4 vb = *(const s16x4*)(rp + ((t4 * 32 + hi * 8) ^ swz));
        o[d] = __builtin_amdgcn_mfma_f32_16x16x16bf16_1k(pa[t4], vb, o[d], 0, 0, 0);
      }
    }
  }

  // write unnormalized partials: po [split*B+b][q][1024] f32; pl/pm per row
  const size_t porow = (size_t)(split * BATCH + b) * SEQ;
#pragma unroll
  for (int d = 0; d < 4; ++d)
#pragma unroll
    for (int jj = 0; jj < 4; ++jj)
      po[(porow + q0 + hi * 4 + jj) * 1024 + h * 64 + d * 16 + lrow] = o[d][jj];
  if (lane < 16) {
    const size_t li = ((size_t)(split * BATCH + b) * NHEAD + h) * SEQ + q0 + lane;
    pl[li] = l_r;
    pmv[li] = m_r;
  }
}

// ---------------------------------------------------------------------------
// Flash split-K merge: out = (O1*w1 + O2*w2) / (l1*w1 + l2*w2),
// w_i = exp2(m_i - max(m1,m2)). Grid (SEQ, BATCH), 256 thr x 4 cols.
// ---------------------------------------------------------------------------
__global__ __launch_bounds__(256) void k_merge(
    const float* __restrict__ po, const float* __restrict__ pl,
    const float* __restrict__ pmv, __bf16* __restrict__ out) {
  const int s = blockIdx.x, b = blockIdx.y;
  const int col = threadIdx.x * 4;
  const int h = col >> 6;
  const size_t r1 = ((size_t)b * SEQ + s) * 1024;
  const size_t r2 = ((size_t)(BATCH + b) * SEQ + s) * 1024;
  const float4 o1 = *(const float4*)(po + r1 + col);
  const float4 o2 = *(const float4*)(po + r2 + col);
  const size_t li1 = ((size_t)b * NHEAD + h) * SEQ + s;
  const size_t li2 = ((size_t)(BATCH + b) * NHEAD + h) * SEQ + s;
  const float m1 = pmv[li1], m2 = pmv[li2];
  const float m = fmaxf(m1, m2);
  const float w1 = __builtin_amdgcn_exp2f(m1 - m);
  const float w2 = __builtin_amdgcn_exp2f(m2 - m);
  const float inv = 1.0f / (pl[li1] * w1 + pl[li2] * w2);
  bf16x4 r;
  r[0] = (__bf16)((o1.x * w1 + o2.x * w2) * inv);
  r[1] = (__bf16)((o1.y * w1 + o2.y * w2) * inv);
  r[2] = (__bf16)((o1.z * w1 + o2.z * w2) * inv);
  r[3] = (__bf16)((o1.w * w1 + o2.w * w2) * inv);
  *(bf16x4*)(out + r1 + col) = r;
}

// ---------------------------------------------------------------------------
// out = LayerNorm(x + y) * g + beta ; writes fp32 residual and optional bf16
// ---------------------------------------------------------------------------
__global__ __launch_bounds__(256) void k_add_ln(
    const float* __restrict__ x, const float* __restrict__ y,
    const float* __restrict__ g, const float* __restrict__ be,
    float* __restrict__ of, __bf16* __restrict__ ob) {
  const int row = blockIdx.x, tid = threadIdx.x;
  const float4 a = ((const float4*)(x + (size_t)row * 1024))[tid];
  const float4 b = ((const float4*)(y + (size_t)row * 1024))[tid];
  const float v0 = a.x + b.x, v1 = a.y + b.y, v2 = a.z + b.z, v3 = a.w + b.w;
  float s = v0 + v1 + v2 + v3;
  float s2 = v0 * v0 + v1 * v1 + v2 * v2 + v3 * v3;
#pragma unroll
  for (int off = 32; off > 0; off >>= 1) {
    s += __shfl_xor(s, off);
    s2 += __shfl_xor(s2, off);
  }
  __shared__ float red[2][4];
  const int wv = tid >> 6, lane = tid & 63;
  if (lane == 0) { red[0][wv] = s; red[1][wv] = s2; }
  __syncthreads();
  s = red[0][0] + red[0][1] + red[0][2] + red[0][3];
  s2 = red[1][0] + red[1][1] + red[1][2] + red[1][3];
  const float mean = s * (1.0f / 1024.0f);
  const float var = s2 * (1.0f / 1024.0f) - mean * mean;
  const float rstd = rsqrtf(var + 1e-5f);
  const float4 gg = ((const float4*)g)[tid];
  const float4 bt = ((const float4*)be)[tid];
  float4 r;
  r.x = (v0 - mean) * rstd * gg.x + bt.x;
  r.y = (v1 - mean) * rstd * gg.y + bt.y;
  r.z = (v2 - mean) * rstd * gg.z + bt.z;
  r.w = (v3 - mean) * rstd * gg.w + bt.w;
  ((float4*)(of + (size_t)row * 1024))[tid] = r;
  if (ob) {
    bf16x4 rb;
    rb[0] = (__bf16)r.x; rb[1] = (__bf16)r.y; rb[2] = (__bf16)r.z; rb[3] = (__bf16)r.w;
    *(bf16x4*)(ob + (size_t)row * 1024 + tid * 4) = rb;
  }
}

// ---------------------------------------------------------------------------
extern "C" void kernel_launch(void* const* d_in, const int* in_sizes, int n_in,
                              void* d_out, int out_size, void* d_ws, size_t ws_size,
                              hipStream_t stream) {
  const float* x = (const float*)d_in[0];
  const float* src_mask = (const float*)d_in[1];
  const float* w_q = (const float*)d_in[2];
  const float* b_q = (const float*)d_in[3];
  const float* w_k = (const float*)d_in[4];
  const float* b_k = (const float*)d_in[5];
  const float* w_v = (const float*)d_in[6];
  const float* b_v = (const float*)d_in[7];
  const float* w_o = (const float*)d_in[8];
  const float* b_o = (const float*)d_in[9];
  const float* w_ff1 = (const float*)d_in[10];
  const float* b_ff1 = (const float*)d_in[11];
  const float* w_ff2 = (const float*)d_in[12];
  const float* b_ff2 = (const float*)d_in[13];
  const float* ln1_g = (const float*)d_in[14];
  const float* ln1_b = (const float*)d_in[15];
  const float* ln2_g = (const float*)d_in[16];
  const float* ln2_b = (const float*)d_in[17];

  char* ws = (char*)d_ws;
  constexpr size_t O_WQKVT = 0;                               // 3072x1024 bf16
  constexpr size_t O_WOT = O_WQKVT + 3072ull * 1024 * 2;      // 1024x1024 bf16
  constexpr size_t O_WFF1T = O_WOT + 1024ull * 1024 * 2;      // 4096x1024 bf16
  constexpr size_t O_WFF2T = O_WFF1T + 4096ull * 1024 * 2;    // 1024x4096 bf16
  constexpr size_t O_BQKV = O_WFF2T + 4096ull * 1024 * 2;     // 3072 f32
  constexpr size_t O_XBF = O_BQKV + 3072ull * 4;              // 4096x1024 bf16
  constexpr size_t O_QKV = O_XBF + 4096ull * 1024 * 2;        // 4096x3072 bf16
  constexpr size_t O_ATTN = O_QKV + 4096ull * 3072 * 2;       // 4096x1024 bf16
  constexpr size_t O_PROJ = O_ATTN + 4096ull * 1024 * 2;      // 4096x1024 f32
  constexpr size_t O_H1F = O_PROJ + 4096ull * 1024 * 4;       // 4096x1024 f32
  constexpr size_t O_H1B = O_H1F + 4096ull * 1024 * 4;        // 4096x1024 bf16
  constexpr size_t O_MASK2 = O_H1B + 4096ull * 1024 * 2;      // 4096 f32 (end)
  // dead-space reuse during attention:
  constexpr size_t O_VT = O_H1B;    // 8MB: vT (dead before ln1 writes h1b)
  constexpr size_t O_PO = O_PROJ;   // 32MB: po spans PROJ+H1F (dead til proj)
  constexpr size_t O_PL = O_XBF;    // 512KB in dead xbf (dead after QKV gemm)
  constexpr size_t O_PM = O_XBF + (512ull << 10);  // 512KB
  constexpr size_t O_FF = O_QKV;    // 4096x4096 bf16 (reuse)
  constexpr size_t O_FF2 = O_PROJ;  // 4096x1024 f32 (reuse, po dead by then)

  __bf16* wqkvT = (__bf16*)(ws + O_WQKVT);
  __bf16* woT = (__bf16*)(ws + O_WOT);
  __bf16* wff1T = (__bf16*)(ws + O_WFF1T);
  __bf16* wff2T = (__bf16*)(ws + O_WFF2T);
  float* bqkv = (float*)(ws + O_BQKV);
  __bf16* xbf = (__bf16*)(ws + O_XBF);
  __bf16* qkvb = (__bf16*)(ws + O_QKV);
  __bf16* attnb = (__bf16*)(ws + O_ATTN);
  float* proj = (float*)(ws + O_PROJ);
  float* h1f = (float*)(ws + O_H1F);
  __bf16* h1b = (__bf16*)(ws + O_H1B);
  float* mask2 = (float*)(ws + O_MASK2);
  __bf16* vT = (__bf16*)(ws + O_VT);
  float* po = (float*)(ws + O_PO);
  float* pl = (float*)(ws + O_PL);
  float* pm = (float*)(ws + O_PM);
  __bf16* ffb = (__bf16*)(ws + O_FF);
  float* ff2 = (float*)(ws + O_FF2);

  // weight prep
  k_transpose_to_bf16<<<dim3(32, 32), 256, 0, stream>>>(w_q, wqkvT, 1024, 1024);
  k_transpose_to_bf16<<<dim3(32, 32), 256, 0, stream>>>(w_k, wqkvT + 1024 * 1024, 1024, 1024);
  k_transpose_to_bf16<<<dim3(32, 32), 256, 0, stream>>>(w_v, wqkvT + 2 * 1024 * 1024, 1024, 1024);
  k_transpose_to_bf16<<<dim3(32, 32), 256, 0, stream>>>(w_o, woT, 1024, 1024);
  k_transpose_to_bf16<<<dim3(128, 32), 256, 0, stream>>>(w_ff1, wff1T, 1024, 4096);
  k_transpose_to_bf16<<<dim3(32, 128), 256, 0, stream>>>(w_ff2, wff2T, 4096, 1024);
  k_concat3<<<12, 256, 0, stream>>>(b_q, b_k, b_v, bqkv);
  k_scale_mask<<<16, 256, 0, stream>>>(src_mask, mask2, BATCH * SEQ);
  k_cvt_bf16<<<4096, 256, 0, stream>>>(x, xbf, MTOT * DMODEL);

  // fused QKV projection (256^2 counted-vmcnt pipeline)
  k_gemm256<false, __bf16><<<dim3(12, 16), 512, 0, stream>>>(xbf, wqkvT, bqkv, qkvb,
                                                             MTOT, 3072, 1024);
  // V transpose for attention B-frags
  k_transpose_v<<<dim3(64, 32, 2), 256, 0, stream>>>(qkvb, vT);
  // attention split-K x2 (32 waves/CU) + exact flash merge
  k_attn<<<dim3(SEQ / 64, NHEAD, BATCH * 2), 256, 0, stream>>>(qkvb, vT, mask2,
                                                               po, pl, pm);
  k_merge<<<dim3(SEQ, BATCH), 256, 0, stream>>>(po, pl, pm, attnb);
  // output projection (f32)
  k_gemm<2, false, float><<<dim3(8, 64), 256, 0, stream>>>(attnb, woT, b_o, proj,
                                                           MTOT, 1024, 1024);
  // ln1
  k_add_ln<<<4096, 256, 0, stream>>>(x, proj, ln1_g, ln1_b, h1f, h1b);
  // ff1 + relu (256^2 counted-vmcnt pipeline)
  k_gemm256<true, __bf16><<<dim3(16, 16), 512, 0, stream>>>(h1b, wff1T, b_ff1, ffb,
                                                            MTOT, DFF, 1024);
  // ff2
  k_gemm<2, false, float><<<dim3(8, 64), 256, 0, stream>>>(ffb, wff2T, b_ff2, ff2,
                                                           MTOT, 1024, DFF);
  // ln2 -> d_out
  k_add_ln<<<4096, 256, 0, stream>>>(h1f, ff2, ln2_g, ln2_b, (float*)d_out, nullptr);
}

// Round 19
// 282.986 us; speedup vs baseline: 1.0113x; 1.0113x over previous
//
#include <hip/hip_runtime.h>
#include <cstdint>
#include <cstddef>

#define BATCH 2
#define SEQ 2048
#define DMODEL 1024
#define NHEAD 16
#define DFF 4096
#define MTOT (BATCH * SEQ) /* 4096 */

typedef __bf16 bf16x8 __attribute__((ext_vector_type(8)));
typedef __bf16 bf16x4 __attribute__((ext_vector_type(4)));
typedef short s16x4 __attribute__((ext_vector_type(4)));
typedef float f32x4 __attribute__((ext_vector_type(4)));

#define S_BARRIER() __builtin_amdgcn_s_barrier()
#define SCHED_FENCE() __builtin_amdgcn_sched_barrier(0)
#define VMCNT8() asm volatile("s_waitcnt vmcnt(8)" ::: "memory")
#define VMCNT4() asm volatile("s_waitcnt vmcnt(4)" ::: "memory")
#define VMCNT0() asm volatile("s_waitcnt vmcnt(0)" ::: "memory")

// async global->LDS, 16B/lane; LDS dest = wave-uniform base + lane*16 (m104).
__device__ __forceinline__ void gload_lds16(const void* g, void* l) {
  __builtin_amdgcn_global_load_lds(
      (__attribute__((address_space(1))) void*)(uintptr_t)g,
      (__attribute__((address_space(3))) void*)(uint32_t)(uintptr_t)l,
      16, 0, 0);
}

// ---------------------------------------------------------------------------
// fp32 [K,N] -> bf16 [N,K] transpose (weights -> B^T layout)
// ---------------------------------------------------------------------------
__global__ __launch_bounds__(256) void k_transpose_to_bf16(
    const float* __restrict__ w, __bf16* __restrict__ wt, int K, int N) {
  __shared__ float t[32][33];
  const int n0 = blockIdx.x * 32, k0 = blockIdx.y * 32;
  const int tx = threadIdx.x & 31, ty = threadIdx.x >> 5;
#pragma unroll
  for (int i = ty; i < 32; i += 8) t[i][tx] = w[(size_t)(k0 + i) * N + n0 + tx];
  __syncthreads();
#pragma unroll
  for (int i = ty; i < 32; i += 8)
    wt[(size_t)(n0 + i) * K + k0 + tx] = (__bf16)t[tx][i];
}

__global__ __launch_bounds__(256) void k_cvt_bf16(
    const float* __restrict__ in, __bf16* __restrict__ out, int n) {
  const int i = (blockIdx.x * 256 + threadIdx.x) * 4;
  if (i >= n) return;
  const float4 v = *(const float4*)(in + i);
  bf16x4 r;
  r[0] = (__bf16)v.x; r[1] = (__bf16)v.y; r[2] = (__bf16)v.z; r[3] = (__bf16)v.w;
  *(bf16x4*)(out + i) = r;
}

__global__ void k_concat3(const float* __restrict__ a, const float* __restrict__ b,
                          const float* __restrict__ c, float* __restrict__ o) {
  const int i = blockIdx.x * 256 + threadIdx.x;
  if (i >= 3072) return;
  o[i] = (i < 1024) ? a[i] : (i < 2048) ? b[i - 1024] : c[i - 2048];
}

// mask * log2(e) for exp2-domain softmax
__global__ void k_scale_mask(const float* __restrict__ in, float* __restrict__ o, int n) {
  const int i = blockIdx.x * 256 + threadIdx.x;
  if (i < n) o[i] = in[i] * 1.44269504f;
}

__global__ void k_zero(float* __restrict__ o, int n) {
  const int i = blockIdx.x * 256 + threadIdx.x;
  if (i < n) o[i] = 0.f;
}

// bf16 V-section transpose: qkvb[b*S+s][2048+c] -> vT[b*1024+c][s]
__global__ __launch_bounds__(256) void k_transpose_v(
    const __bf16* __restrict__ qkvb, __bf16* __restrict__ vT) {
  __shared__ __bf16 t[32][33];
  const int s0 = blockIdx.x * 32, c0 = blockIdx.y * 32, b = blockIdx.z;
  const int tx = threadIdx.x & 31, ty = threadIdx.x >> 5;
#pragma unroll
  for (int i = ty; i < 32; i += 8)
    t[i][tx] = qkvb[(size_t)(b * SEQ + s0 + i) * 3072 + 2048 + c0 + tx];
  __syncthreads();
#pragma unroll
  for (int i = ty; i < 32; i += 8)
    vT[((size_t)b * 1024 + c0 + i) * SEQ + s0 + tx] = t[tx][i];
}

// ---------------------------------------------------------------------------
// 256x256 deep-pipelined MFMA GEMM (T3+T4 counted-vmcnt, ALL-BUILTIN MFMAs).
// R16-verified. 512 thr = 8 waves (2M x 4N); wave owns 128x64.
// ---------------------------------------------------------------------------
template <bool RELU, typename OutT>
__global__ __launch_bounds__(512) void k_gemm256(
    const __bf16* __restrict__ A, const __bf16* __restrict__ BT,
    const float* __restrict__ bias, OutT* __restrict__ C,
    int M, int N, int K) {
  __shared__ __align__(16) __bf16 sA[4 * 8192];
  __shared__ __align__(16) __bf16 sB[4 * 8192];
  const int tid = threadIdx.x, lane = tid & 63, wv = tid >> 6;
  const int wm = wv >> 2, wn = wv & 3;
  const int lrow = lane & 15, hi = lane >> 4;
  const int nwg = gridDim.x * gridDim.y;
  const int flat = blockIdx.y * gridDim.x + blockIdx.x;
  const int cpx = nwg >> 3;
  const int swzb = (flat & 7) * cpx + (flat >> 3);
  const int m0 = (swzb / gridDim.x) * 256;
  const int n0 = (swzb % gridDim.x) * 256;
  const int NT = K >> 6;

  const int lsub = lane >> 2;
  const int gg = (lane & 3) ^ ((lane >> 3) & 3);
  const int gr = hi ^ ((lrow >> 1) & 3);

  f32x4 acc[8][4];
#pragma unroll
  for (int r = 0; r < 8; ++r)
#pragma unroll
    for (int c = 0; c < 4; ++c) acc[r][c] = f32x4{0.f, 0.f, 0.f, 0.f};

  auto stage = [&](int p) {
    const int tile = p >> 1;
    const int slot = (((tile & 1) * 2) + (p & 1)) * 8192;
    const int kcol = tile * 64 + (p & 1) * 32 + gg * 8;
#pragma unroll
    for (int i = 0; i < 2; ++i) {
      const int c = wv * 2 + i;
      gload_lds16(A + (size_t)(m0 + c * 16 + lsub) * K + kcol, &sA[slot + c * 512]);
      gload_lds16(BT + (size_t)(n0 + c * 16 + lsub) * K + kcol, &sB[slot + c * 512]);
    }
  };

  auto compute = [&](int p) {
    const int slot = ((((p >> 1) & 1) * 2) + (p & 1)) * 8192;
    bf16x8 af[8], bfv[4];
#pragma unroll
    for (int r = 0; r < 8; ++r)
      af[r] = *(const bf16x8*)&sA[slot + (wm * 128 + r * 16 + lrow) * 32 + gr * 8];
#pragma unroll
    for (int c = 0; c < 4; ++c)
      bfv[c] = *(const bf16x8*)&sB[slot + (wn * 64 + c * 16 + lrow) * 32 + gr * 8];
    __builtin_amdgcn_s_setprio(1);
#pragma unroll
    for (int r = 0; r < 8; ++r)
#pragma unroll
      for (int c = 0; c < 4; ++c)
        acc[r][c] = __builtin_amdgcn_mfma_f32_16x16x32_bf16(af[r], bfv[c],
                                                            acc[r][c], 0, 0, 0);
    __builtin_amdgcn_s_setprio(0);
  };

  stage(0); stage(1); stage(2);
  int p = 0;
  for (; p < 2 * NT - 3; ++p) {
    VMCNT8(); S_BARRIER(); SCHED_FENCE();
    stage(p + 3);
    compute(p);
  }
  VMCNT8(); S_BARRIER(); SCHED_FENCE(); compute(p); ++p;
  VMCNT4(); S_BARRIER(); SCHED_FENCE(); compute(p); ++p;
  VMCNT0(); S_BARRIER(); SCHED_FENCE(); compute(p);

#pragma unroll
  for (int r = 0; r < 8; ++r) {
    const int row = m0 + wm * 128 + r * 16 + hi * 4;
#pragma unroll
    for (int c = 0; c < 4; ++c) {
      const int col = n0 + wn * 64 + c * 16 + lrow;
      const float bb = bias[col];
#pragma unroll
      for (int j = 0; j < 4; ++j) {
        float v = acc[r][c][j] + bb;
        if (RELU) v = fmaxf(v, 0.f);
        C[(size_t)(row + j) * N + col] = (OutT)v;
      }
    }
  }
}

// ---------------------------------------------------------------------------
// bf16 MFMA GEMM (R9-verified body + XCD swizzle). KS = K-range per launch;
// caller offsets A/BT/K pointers for split-K halves. BM=MF*32, BN=128, BK=64.
// ---------------------------------------------------------------------------
template <int MF, bool RELU, typename OutT>
__global__ __launch_bounds__(256) void k_gemm(
    const __bf16* __restrict__ A, const __bf16* __restrict__ BT,
    const float* __restrict__ bias, OutT* __restrict__ C, int M, int N,
    int lda, int KS) {
  __shared__ __bf16 sA[MF * 32 * 64];
  __shared__ __bf16 sB[128 * 64];
  const int tid = threadIdx.x, lane = tid & 63, wv = tid >> 6;
  const int wm = wv >> 1, wn = wv & 1;
  const int lrow = lane & 15, hi = lane >> 4;
  const int nwg = gridDim.x * gridDim.y;
  const int flat = blockIdx.y * gridDim.x + blockIdx.x;
  const int cpx = nwg >> 3;
  const int swzb = (flat & 7) * cpx + (flat >> 3);
  const int m0 = (swzb / gridDim.x) * (MF * 32);
  const int n0 = (swzb % gridDim.x) * 128;
  const int srow = lane >> 3;
  const int scolE = ((lane & 7) ^ srow) * 8;
  const int swz = (lrow & 7) << 4;

  f32x4 acc[MF][4];
#pragma unroll
  for (int r = 0; r < MF; ++r)
#pragma unroll
    for (int c = 0; c < 4; ++c) acc[r][c] = f32x4{0.f, 0.f, 0.f, 0.f};

  for (int k0 = 0; k0 < KS; k0 += 64) {
    __syncthreads();
#pragma unroll
    for (int rb = wv; rb < MF * 4; rb += 4) {
      const int row = rb * 8 + srow;
      gload_lds16(A + (size_t)(m0 + row) * lda + k0 + scolE, &sA[rb * 512]);
    }
#pragma unroll
    for (int rb = wv; rb < 16; rb += 4) {
      const int row = rb * 8 + srow;
      gload_lds16(BT + (size_t)(n0 + row) * lda + k0 + scolE, &sB[rb * 512]);
    }
    __syncthreads();
#pragma unroll
    for (int kc = 0; kc < 2; ++kc) {
      bf16x8 af[MF], bfr[4];
#pragma unroll
      for (int r = 0; r < MF; ++r) {
        const int row = wm * (MF * 16) + r * 16 + lrow;
        af[r] = *(const bf16x8*)((const char*)sA + row * 128 + ((kc * 64 + hi * 16) ^ swz));
      }
#pragma unroll
      for (int c = 0; c < 4; ++c) {
        const int row = wn * 64 + c * 16 + lrow;
        bfr[c] = *(const bf16x8*)((const char*)sB + row * 128 + ((kc * 64 + hi * 16) ^ swz));
      }
#pragma unroll
      for (int r = 0; r < MF; ++r)
#pragma unroll
        for (int c = 0; c < 4; ++c)
          acc[r][c] = __builtin_amdgcn_mfma_f32_16x16x32_bf16(af[r], bfr[c],
                                                              acc[r][c], 0, 0, 0);
    }
  }

#pragma unroll
  for (int r = 0; r < MF; ++r) {
    const int row = m0 + wm * (MF * 16) + r * 16 + hi * 4;
#pragma unroll
    for (int c = 0; c < 4; ++c) {
      const int col = n0 + wn * 64 + c * 16 + lrow;
      const float bb = bias[col];
#pragma unroll
      for (int j = 0; j < 4; ++j) {
        float v = acc[r][c][j] + bb;
        if (RELU) v = fmaxf(v, 0.f);
        C[(size_t)(row + j) * N + col] = (OutT)v;
      }
    }
  }
}

// ---------------------------------------------------------------------------
// Flash attention — R17-verified exactly (builtin MFMAs, KVBLK=64, dbuf
// issue-early staging, exp2-domain softmax + defer-max). Split-K reverted.
// ---------------------------------------------------------------------------
__global__ __launch_bounds__(256) void k_attn(
    const __bf16* __restrict__ qkv, const __bf16* __restrict__ vT,
    const float* __restrict__ mask2, __bf16* __restrict__ out) {
  const int qb = blockIdx.x, h = blockIdx.y, b = blockIdx.z;
  const int tid = threadIdx.x, lane = tid & 63, wv = tid >> 6;
  const int lrow = lane & 15, hi = lane >> 4;

  __shared__ __bf16 sK[2][64 * 64];
  __shared__ __bf16 sV[2][64 * 64];

  const size_t base = (size_t)b * SEQ * 3072;
  const __bf16* Qb = qkv + base + h * 64;
  const __bf16* Kb = qkv + base + 1024 + h * 64;
  const __bf16* vTb = vT + ((size_t)b * 1024 + h * 64) * SEQ;
  const float* maskb = mask2 + (size_t)b * SEQ;

  const int q0 = qb * 64 + wv * 16;
  const bf16x8 qf0 = *(const bf16x8*)&Qb[(size_t)(q0 + lrow) * 3072 + hi * 8];
  const bf16x8 qf1 = *(const bf16x8*)&Qb[(size_t)(q0 + lrow) * 3072 + 32 + hi * 8];

  float m_r = -3e38f, l_r = 0.f;
  f32x4 o[4];
#pragma unroll
  for (int d = 0; d < 4; ++d) o[d] = f32x4{0.f, 0.f, 0.f, 0.f};

  const int srow = lane >> 3;
  const int scolE = ((lane & 7) ^ srow) * 8;
  const int swz = (lrow & 7) << 4;

  auto stage = [&](int t) {
    const int k0s = t * 64;
    __bf16* dK = sK[t & 1];
    __bf16* dV = sV[t & 1];
#pragma unroll
    for (int r = 0; r < 2; ++r) {
      const int rb = r * 4 + wv;
      const int row = rb * 8 + srow;
      gload_lds16(Kb + (size_t)(k0s + row) * 3072 + scolE, &dK[rb * 512]);
      gload_lds16(vTb + (size_t)row * SEQ + k0s + scolE, &dV[rb * 512]);
    }
  };

  stage(0);
  const int NT = SEQ / 64;
  for (int t = 0; t < NT; ++t) {
    __syncthreads();
    if (t + 1 < NT) stage(t + 1);
    const __bf16* cK = sK[t & 1];
    const __bf16* cV = sV[t & 1];
    const int k0 = t * 64;

    f32x4 st[4];
#pragma unroll
    for (int t4 = 0; t4 < 4; ++t4) {
      const char* rp = (const char*)cK + (t4 * 16 + lrow) * 128;
      const bf16x8 ka = *(const bf16x8*)(rp + ((hi * 16) ^ swz));
      const bf16x8 kb = *(const bf16x8*)(rp + ((64 + hi * 16) ^ swz));
      f32x4 a = f32x4{0.f, 0.f, 0.f, 0.f};
      a = __builtin_amdgcn_mfma_f32_16x16x32_bf16(ka, qf0, a, 0, 0, 0);
      a = __builtin_amdgcn_mfma_f32_16x16x32_bf16(kb, qf1, a, 0, 0, 0);
      st[t4] = a;
    }

    float pm = -3e38f;
#pragma unroll
    for (int t4 = 0; t4 < 4; ++t4) {
      const f32x4 mk = *(const f32x4*)&maskb[k0 + t4 * 16 + hi * 4];
#pragma unroll
      for (int j = 0; j < 4; ++j) {
        st[t4][j] = st[t4][j] * 0.18033688f + mk[j];
        pm = fmaxf(pm, st[t4][j]);
      }
    }
    pm = fmaxf(pm, __shfl_xor(pm, 16));
    pm = fmaxf(pm, __shfl_xor(pm, 32));

    if (__any(pm > m_r + 11.5f)) {
      const float mn = fmaxf(m_r, pm);
      const float so = __builtin_amdgcn_exp2f(m_r - mn);
      m_r = mn;
      l_r *= so;
      float so_o[4];
#pragma unroll
      for (int jj = 0; jj < 4; ++jj) so_o[jj] = __shfl(so, hi * 4 + jj);
#pragma unroll
      for (int d = 0; d < 4; ++d)
#pragma unroll
        for (int jj = 0; jj < 4; ++jj) o[d][jj] *= so_o[jj];
    }

    float rs = 0.f;
#pragma unroll
    for (int t4 = 0; t4 < 4; ++t4)
#pragma unroll
      for (int j = 0; j < 4; ++j) {
        st[t4][j] = __builtin_amdgcn_exp2f(st[t4][j] - m_r);
        rs += st[t4][j];
      }
    rs += __shfl_xor(rs, 16);
    rs += __shfl_xor(rs, 32);
    l_r += rs;

    s16x4 pa[4];
#pragma unroll
    for (int t4 = 0; t4 < 4; ++t4)
#pragma unroll
      for (int j = 0; j < 4; ++j) {
        const __bf16 pb = (__bf16)st[t4][j];
        pa[t4][j] = __builtin_bit_cast(short, pb);
      }

#pragma unroll
    for (int d = 0; d < 4; ++d) {
      const char* rp = (const char*)cV + (d * 16 + lrow) * 128;
#pragma unroll
      for (int t4 = 0; t4 < 4; ++t4) {
        const s16x4 vb = *(const s16x4*)(rp + ((t4 * 32 + hi * 8) ^ swz));
        o[d] = __builtin_amdgcn_mfma_f32_16x16x16bf16_1k(pa[t4], vb, o[d], 0, 0, 0);
      }
    }
  }

  __syncthreads();
  float linv[4];
#pragma unroll
  for (int jj = 0; jj < 4; ++jj) linv[jj] = 1.0f / __shfl(l_r, hi * 4 + jj);
#pragma unroll
  for (int d = 0; d < 4; ++d)
#pragma unroll
    for (int jj = 0; jj < 4; ++jj)
      out[((size_t)b * SEQ + q0 + hi * 4 + jj) * DMODEL + h * 64 + d * 16 + lrow] =
          (__bf16)(o[d][jj] * linv[jj]);
}

// ---------------------------------------------------------------------------
// out = LayerNorm(x + y [+ y2]) * g + beta ; y/y2 nullable.
// ---------------------------------------------------------------------------
__global__ __launch_bounds__(256) void k_add_ln(
    const float* __restrict__ x, const float* __restrict__ y,
    const float* __restrict__ y2, const float* __restrict__ g,
    const float* __restrict__ be, float* __restrict__ of,
    __bf16* __restrict__ ob) {
  const int row = blockIdx.x, tid = threadIdx.x;
  const float4 a = ((const float4*)(x + (size_t)row * 1024))[tid];
  float4 b = {0.f, 0.f, 0.f, 0.f};
  if (y) b = ((const float4*)(y + (size_t)row * 1024))[tid];
  float4 c = {0.f, 0.f, 0.f, 0.f};
  if (y2) c = ((const float4*)(y2 + (size_t)row * 1024))[tid];
  const float v0 = a.x + b.x + c.x, v1 = a.y + b.y + c.y;
  const float v2 = a.z + b.z + c.z, v3 = a.w + b.w + c.w;
  float s = v0 + v1 + v2 + v3;
  float s2 = v0 * v0 + v1 * v1 + v2 * v2 + v3 * v3;
#pragma unroll
  for (int off = 32; off > 0; off >>= 1) {
    s += __shfl_xor(s, off);
    s2 += __shfl_xor(s2, off);
  }
  __shared__ float red[2][4];
  const int wv = tid >> 6, lane = tid & 63;
  if (lane == 0) { red[0][wv] = s; red[1][wv] = s2; }
  __syncthreads();
  s = red[0][0] + red[0][1] + red[0][2] + red[0][3];
  s2 = red[1][0] + red[1][1] + red[1][2] + red[1][3];
  const float mean = s * (1.0f / 1024.0f);
  const float var = s2 * (1.0f / 1024.0f) - mean * mean;
  const float rstd = rsqrtf(var + 1e-5f);
  const float4 gg = ((const float4*)g)[tid];
  const float4 bt = ((const float4*)be)[tid];
  float4 r;
  r.x = (v0 - mean) * rstd * gg.x + bt.x;
  r.y = (v1 - mean) * rstd * gg.y + bt.y;
  r.z = (v2 - mean) * rstd * gg.z + bt.z;
  r.w = (v3 - mean) * rstd * gg.w + bt.w;
  ((float4*)(of + (size_t)row * 1024))[tid] = r;
  if (ob) {
    bf16x4 rb;
    rb[0] = (__bf16)r.x; rb[1] = (__bf16)r.y; rb[2] = (__bf16)r.z; rb[3] = (__bf16)r.w;
    *(bf16x4*)(ob + (size_t)row * 1024 + tid * 4) = rb;
  }
}

// ---------------------------------------------------------------------------
extern "C" void kernel_launch(void* const* d_in, const int* in_sizes, int n_in,
                              void* d_out, int out_size, void* d_ws, size_t ws_size,
                              hipStream_t stream) {
  const float* x = (const float*)d_in[0];
  const float* src_mask = (const float*)d_in[1];
  const float* w_q = (const float*)d_in[2];
  const float* b_q = (const float*)d_in[3];
  const float* w_k = (const float*)d_in[4];
  const float* b_k = (const float*)d_in[5];
  const float* w_v = (const float*)d_in[6];
  const float* b_v = (const float*)d_in[7];
  const float* w_o = (const float*)d_in[8];
  const float* b_o = (const float*)d_in[9];
  const float* w_ff1 = (const float*)d_in[10];
  const float* b_ff1 = (const float*)d_in[11];
  const float* w_ff2 = (const float*)d_in[12];
  const float* b_ff2 = (const float*)d_in[13];
  const float* ln1_g = (const float*)d_in[14];
  const float* ln1_b = (const float*)d_in[15];
  const float* ln2_g = (const float*)d_in[16];
  const float* ln2_b = (const float*)d_in[17];

  char* ws = (char*)d_ws;
  constexpr size_t O_WQKVT = 0;
  constexpr size_t O_WOT = O_WQKVT + 3072ull * 1024 * 2;
  constexpr size_t O_WFF1T = O_WOT + 1024ull * 1024 * 2;
  constexpr size_t O_WFF2T = O_WFF1T + 4096ull * 1024 * 2;
  constexpr size_t O_BQKV = O_WFF2T + 4096ull * 1024 * 2;
  constexpr size_t O_XBF = O_BQKV + 3072ull * 4;
  constexpr size_t O_QKV = O_XBF + 4096ull * 1024 * 2;
  constexpr size_t O_ATTN = O_QKV + 4096ull * 3072 * 2;
  constexpr size_t O_PROJ = O_ATTN + 4096ull * 1024 * 2;
  constexpr size_t O_H1F = O_PROJ + 4096ull * 1024 * 4;
  constexpr size_t O_H1B = O_H1F + 4096ull * 1024 * 4;
  constexpr size_t O_MASK2 = O_H1B + 4096ull * 1024 * 2;   // 16KB
  constexpr size_t O_ZERO = O_MASK2 + 4096ull * 4;          // 4KB zeros
  constexpr size_t O_VT = O_PROJ;    // vT: dead before proj written
  constexpr size_t O_FF = O_QKV;     // ffb 32MB spans QKV+ATTN
  constexpr size_t O_FF2A = O_PROJ;  // 16MB (proj dead after ln1)
  constexpr size_t O_FF2B = 0;       // 16MB over dead wqkvT+woT+wff1T

  __bf16* wqkvT = (__bf16*)(ws + O_WQKVT);
  __bf16* woT = (__bf16*)(ws + O_WOT);
  __bf16* wff1T = (__bf16*)(ws + O_WFF1T);
  __bf16* wff2T = (__bf16*)(ws + O_WFF2T);
  float* bqkv = (float*)(ws + O_BQKV);
  __bf16* xbf = (__bf16*)(ws + O_XBF);
  __bf16* qkvb = (__bf16*)(ws + O_QKV);
  __bf16* attnb = (__bf16*)(ws + O_ATTN);
  float* proj = (float*)(ws + O_PROJ);
  float* h1f = (float*)(ws + O_H1F);
  __bf16* h1b = (__bf16*)(ws + O_H1B);
  float* mask2 = (float*)(ws + O_MASK2);
  float* zeros = (float*)(ws + O_ZERO);
  __bf16* vT = (__bf16*)(ws + O_VT);
  __bf16* ffb = (__bf16*)(ws + O_FF);
  float* ff2a = (float*)(ws + O_FF2A);
  float* ff2b = (float*)(ws + O_FF2B);

  // weight prep
  k_transpose_to_bf16<<<dim3(32, 32), 256, 0, stream>>>(w_q, wqkvT, 1024, 1024);
  k_transpose_to_bf16<<<dim3(32, 32), 256, 0, stream>>>(w_k, wqkvT + 1024 * 1024, 1024, 1024);
  k_transpose_to_bf16<<<dim3(32, 32), 256, 0, stream>>>(w_v, wqkvT + 2 * 1024 * 1024, 1024, 1024);
  k_transpose_to_bf16<<<dim3(32, 32), 256, 0, stream>>>(w_o, woT, 1024, 1024);
  k_transpose_to_bf16<<<dim3(128, 32), 256, 0, stream>>>(w_ff1, wff1T, 1024, 4096);
  k_transpose_to_bf16<<<dim3(32, 128), 256, 0, stream>>>(w_ff2, wff2T, 4096, 1024);
  k_concat3<<<12, 256, 0, stream>>>(b_q, b_k, b_v, bqkv);
  k_scale_mask<<<16, 256, 0, stream>>>(src_mask, mask2, BATCH * SEQ);
  k_zero<<<4, 256, 0, stream>>>(zeros, 1024);
  k_cvt_bf16<<<4096, 256, 0, stream>>>(x, xbf, MTOT * DMODEL);

  // fused QKV projection (256^2 counted-vmcnt pipeline)
  k_gemm256<false, __bf16><<<dim3(12, 16), 512, 0, stream>>>(xbf, wqkvT, bqkv, qkvb,
                                                             MTOT, 3072, 1024);
  // V transpose
  k_transpose_v<<<dim3(64, 32, 2), 256, 0, stream>>>(qkvb, vT);
  // attention (R17-verified)
  k_attn<<<dim3(SEQ / 64, NHEAD, BATCH), 256, 0, stream>>>(qkvb, vT, mask2, attnb);
  // output projection
  k_gemm<2, false, float><<<dim3(8, 64), 256, 0, stream>>>(
      attnb, woT, b_o, proj, MTOT, 1024, 1024, 1024);
  // ln1
  k_add_ln<<<4096, 256, 0, stream>>>(x, proj, nullptr, ln1_g, ln1_b, h1f, h1b);
  // ff1 + relu (256^2 counted-vmcnt pipeline)
  k_gemm256<true, __bf16><<<dim3(16, 16), 512, 0, stream>>>(h1b, wff1T, b_ff1, ffb,
                                                            MTOT, DFF, 1024);
  // ff2 split-K x2 (two concurrent dispatches, independent K-halves):
  // half 0 carries the bias; half 1 adds zero bias.
  k_gemm<2, false, float><<<dim3(8, 64), 256, 0, stream>>>(
      ffb, wff2T, b_ff2, ff2a, MTOT, 1024, DFF, 2048);
  k_gemm<2, false, float><<<dim3(8, 64), 256, 0, stream>>>(
      ffb + 2048, wff2T + 2048, zeros, ff2b, MTOT, 1024, DFF, 2048);
  // ln2 -> d_out: h1 + ff2a + ff2b
  k_add_ln<<<4096, 256, 0, stream>>>(ff2a, h1f, ff2b, ln2_g, ln2_b,
                                     (float*)d_out, nullptr);
}

// Round 20
// 273.121 us; speedup vs baseline: 1.0478x; 1.0361x over previous
//
#include <hip/hip_runtime.h>
#include <cstdint>
#include <cstddef>

#define BATCH 2
#define SEQ 2048
#define DMODEL 1024
#define NHEAD 16
#define DFF 4096
#define MTOT (BATCH * SEQ) /* 4096 */

typedef __bf16 bf16x8 __attribute__((ext_vector_type(8)));
typedef __bf16 bf16x4 __attribute__((ext_vector_type(4)));
typedef short s16x4 __attribute__((ext_vector_type(4)));
typedef float f32x4 __attribute__((ext_vector_type(4)));

#define S_BARRIER() __builtin_amdgcn_s_barrier()
#define SCHED_FENCE() __builtin_amdgcn_sched_barrier(0)
#define VMCNT8() asm volatile("s_waitcnt vmcnt(8)" ::: "memory")
#define VMCNT4() asm volatile("s_waitcnt vmcnt(4)" ::: "memory")
#define VMCNT0() asm volatile("s_waitcnt vmcnt(0)" ::: "memory")

// async global->LDS, 16B/lane; LDS dest = wave-uniform base + lane*16 (m104).
__device__ __forceinline__ void gload_lds16(const void* g, void* l) {
  __builtin_amdgcn_global_load_lds(
      (__attribute__((address_space(1))) void*)(uintptr_t)g,
      (__attribute__((address_space(3))) void*)(uint32_t)(uintptr_t)l,
      16, 0, 0);
}

// ---------------------------------------------------------------------------
// fp32 [K,N] -> bf16 [N,K] transpose (weights -> B^T layout)
// ---------------------------------------------------------------------------
__global__ __launch_bounds__(256) void k_transpose_to_bf16(
    const float* __restrict__ w, __bf16* __restrict__ wt, int K, int N) {
  __shared__ float t[32][33];
  const int n0 = blockIdx.x * 32, k0 = blockIdx.y * 32;
  const int tx = threadIdx.x & 31, ty = threadIdx.x >> 5;
#pragma unroll
  for (int i = ty; i < 32; i += 8) t[i][tx] = w[(size_t)(k0 + i) * N + n0 + tx];
  __syncthreads();
#pragma unroll
  for (int i = ty; i < 32; i += 8)
    wt[(size_t)(n0 + i) * K + k0 + tx] = (__bf16)t[tx][i];
}

__global__ __launch_bounds__(256) void k_cvt_bf16(
    const float* __restrict__ in, __bf16* __restrict__ out, int n) {
  const int i = (blockIdx.x * 256 + threadIdx.x) * 4;
  if (i >= n) return;
  const float4 v = *(const float4*)(in + i);
  bf16x4 r;
  r[0] = (__bf16)v.x; r[1] = (__bf16)v.y; r[2] = (__bf16)v.z; r[3] = (__bf16)v.w;
  *(bf16x4*)(out + i) = r;
}

__global__ void k_concat3(const float* __restrict__ a, const float* __restrict__ b,
                          const float* __restrict__ c, float* __restrict__ o) {
  const int i = blockIdx.x * 256 + threadIdx.x;
  if (i >= 3072) return;
  o[i] = (i < 1024) ? a[i] : (i < 2048) ? b[i - 1024] : c[i - 2048];
}

// mask * log2(e) for exp2-domain softmax
__global__ void k_scale_mask(const float* __restrict__ in, float* __restrict__ o, int n) {
  const int i = blockIdx.x * 256 + threadIdx.x;
  if (i < n) o[i] = in[i] * 1.44269504f;
}

// bf16 V-section transpose: qkvb[b*S+s][2048+c] -> vT[b*1024+c][s]
__global__ __launch_bounds__(256) void k_transpose_v(
    const __bf16* __restrict__ qkvb, __bf16* __restrict__ vT) {
  __shared__ __bf16 t[32][33];
  const int s0 = blockIdx.x * 32, c0 = blockIdx.y * 32, b = blockIdx.z;
  const int tx = threadIdx.x & 31, ty = threadIdx.x >> 5;
#pragma unroll
  for (int i = ty; i < 32; i += 8)
    t[i][tx] = qkvb[(size_t)(b * SEQ + s0 + i) * 3072 + 2048 + c0 + tx];
  __syncthreads();
#pragma unroll
  for (int i = ty; i < 32; i += 8)
    vT[((size_t)b * 1024 + c0 + i) * SEQ + s0 + tx] = t[tx][i];
}

// ---------------------------------------------------------------------------
// 256x256 deep-pipelined MFMA GEMM (T3+T4 counted-vmcnt, ALL-BUILTIN MFMAs).
// R16-verified. 512 thr = 8 waves (2M x 4N); wave owns 128x64.
// ---------------------------------------------------------------------------
template <bool RELU, typename OutT>
__global__ __launch_bounds__(512) void k_gemm256(
    const __bf16* __restrict__ A, const __bf16* __restrict__ BT,
    const float* __restrict__ bias, OutT* __restrict__ C,
    int M, int N, int K) {
  __shared__ __align__(16) __bf16 sA[4 * 8192];
  __shared__ __align__(16) __bf16 sB[4 * 8192];
  const int tid = threadIdx.x, lane = tid & 63, wv = tid >> 6;
  const int wm = wv >> 2, wn = wv & 3;
  const int lrow = lane & 15, hi = lane >> 4;
  const int nwg = gridDim.x * gridDim.y;
  const int flat = blockIdx.y * gridDim.x + blockIdx.x;
  const int cpx = nwg >> 3;
  const int swzb = (flat & 7) * cpx + (flat >> 3);
  const int m0 = (swzb / gridDim.x) * 256;
  const int n0 = (swzb % gridDim.x) * 256;
  const int NT = K >> 6;

  const int lsub = lane >> 2;
  const int gg = (lane & 3) ^ ((lane >> 3) & 3);
  const int gr = hi ^ ((lrow >> 1) & 3);

  f32x4 acc[8][4];
#pragma unroll
  for (int r = 0; r < 8; ++r)
#pragma unroll
    for (int c = 0; c < 4; ++c) acc[r][c] = f32x4{0.f, 0.f, 0.f, 0.f};

  auto stage = [&](int p) {
    const int tile = p >> 1;
    const int slot = (((tile & 1) * 2) + (p & 1)) * 8192;
    const int kcol = tile * 64 + (p & 1) * 32 + gg * 8;
#pragma unroll
    for (int i = 0; i < 2; ++i) {
      const int c = wv * 2 + i;
      gload_lds16(A + (size_t)(m0 + c * 16 + lsub) * K + kcol, &sA[slot + c * 512]);
      gload_lds16(BT + (size_t)(n0 + c * 16 + lsub) * K + kcol, &sB[slot + c * 512]);
    }
  };

  auto compute = [&](int p) {
    const int slot = ((((p >> 1) & 1) * 2) + (p & 1)) * 8192;
    bf16x8 af[8], bfv[4];
#pragma unroll
    for (int r = 0; r < 8; ++r)
      af[r] = *(const bf16x8*)&sA[slot + (wm * 128 + r * 16 + lrow) * 32 + gr * 8];
#pragma unroll
    for (int c = 0; c < 4; ++c)
      bfv[c] = *(const bf16x8*)&sB[slot + (wn * 64 + c * 16 + lrow) * 32 + gr * 8];
    __builtin_amdgcn_s_setprio(1);
#pragma unroll
    for (int r = 0; r < 8; ++r)
#pragma unroll
      for (int c = 0; c < 4; ++c)
        acc[r][c] = __builtin_amdgcn_mfma_f32_16x16x32_bf16(af[r], bfv[c],
                                                            acc[r][c], 0, 0, 0);
    __builtin_amdgcn_s_setprio(0);
  };

  stage(0); stage(1); stage(2);
  int p = 0;
  for (; p < 2 * NT - 3; ++p) {
    VMCNT8(); S_BARRIER(); SCHED_FENCE();
    stage(p + 3);
    compute(p);
  }
  VMCNT8(); S_BARRIER(); SCHED_FENCE(); compute(p); ++p;
  VMCNT4(); S_BARRIER(); SCHED_FENCE(); compute(p); ++p;
  VMCNT0(); S_BARRIER(); SCHED_FENCE(); compute(p);

#pragma unroll
  for (int r = 0; r < 8; ++r) {
    const int row = m0 + wm * 128 + r * 16 + hi * 4;
#pragma unroll
    for (int c = 0; c < 4; ++c) {
      const int col = n0 + wn * 64 + c * 16 + lrow;
      const float bb = bias[col];
#pragma unroll
      for (int j = 0; j < 4; ++j) {
        float v = acc[r][c][j] + bb;
        if (RELU) v = fmaxf(v, 0.f);
        C[(size_t)(row + j) * N + col] = (OutT)v;
      }
    }
  }
}

// ---------------------------------------------------------------------------
// bf16 MFMA GEMM (R9-verified body + XCD swizzle) with single-dispatch
// split-K: blockIdx.z selects K-range [z*KS,(z+1)*KS), output buffer
// (z==0 -> C0 with bias, z==1 -> C1 with zero bias). BM=MF*32, BN=128, BK=64.
// ---------------------------------------------------------------------------
template <int MF, bool RELU, typename OutT>
__global__ __launch_bounds__(256) void k_gemm(
    const __bf16* __restrict__ A, const __bf16* __restrict__ BT,
    const float* __restrict__ bias, OutT* __restrict__ C0,
    OutT* __restrict__ C1, int M, int N, int lda, int KS) {
  __shared__ __bf16 sA[MF * 32 * 64];
  __shared__ __bf16 sB[128 * 64];
  const int tid = threadIdx.x, lane = tid & 63, wv = tid >> 6;
  const int wm = wv >> 1, wn = wv & 1;
  const int lrow = lane & 15, hi = lane >> 4;
  const int nwg = gridDim.x * gridDim.y;
  const int flat = blockIdx.y * gridDim.x + blockIdx.x;
  const int cpx = nwg >> 3;
  const int swzb = (flat & 7) * cpx + (flat >> 3);
  const int m0 = (swzb / gridDim.x) * (MF * 32);
  const int n0 = (swzb % gridDim.x) * 128;
  const int koff = blockIdx.z * KS;
  OutT* Cz = blockIdx.z ? C1 : C0;
  const int srow = lane >> 3;
  const int scolE = ((lane & 7) ^ srow) * 8;
  const int swz = (lrow & 7) << 4;

  f32x4 acc[MF][4];
#pragma unroll
  for (int r = 0; r < MF; ++r)
#pragma unroll
    for (int c = 0; c < 4; ++c) acc[r][c] = f32x4{0.f, 0.f, 0.f, 0.f};

  for (int k0 = 0; k0 < KS; k0 += 64) {
    __syncthreads();
#pragma unroll
    for (int rb = wv; rb < MF * 4; rb += 4) {
      const int row = rb * 8 + srow;
      gload_lds16(A + (size_t)(m0 + row) * lda + koff + k0 + scolE, &sA[rb * 512]);
    }
#pragma unroll
    for (int rb = wv; rb < 16; rb += 4) {
      const int row = rb * 8 + srow;
      gload_lds16(BT + (size_t)(n0 + row) * lda + koff + k0 + scolE, &sB[rb * 512]);
    }
    __syncthreads();
#pragma unroll
    for (int kc = 0; kc < 2; ++kc) {
      bf16x8 af[MF], bfr[4];
#pragma unroll
      for (int r = 0; r < MF; ++r) {
        const int row = wm * (MF * 16) + r * 16 + lrow;
        af[r] = *(const bf16x8*)((const char*)sA + row * 128 + ((kc * 64 + hi * 16) ^ swz));
      }
#pragma unroll
      for (int c = 0; c < 4; ++c) {
        const int row = wn * 64 + c * 16 + lrow;
        bfr[c] = *(const bf16x8*)((const char*)sB + row * 128 + ((kc * 64 + hi * 16) ^ swz));
      }
#pragma unroll
      for (int r = 0; r < MF; ++r)
#pragma unroll
        for (int c = 0; c < 4; ++c)
          acc[r][c] = __builtin_amdgcn_mfma_f32_16x16x32_bf16(af[r], bfr[c],
                                                              acc[r][c], 0, 0, 0);
    }
  }

#pragma unroll
  for (int r = 0; r < MF; ++r) {
    const int row = m0 + wm * (MF * 16) + r * 16 + hi * 4;
#pragma unroll
    for (int c = 0; c < 4; ++c) {
      const int col = n0 + wn * 64 + c * 16 + lrow;
      const float bb = (blockIdx.z == 0) ? bias[col] : 0.f;
#pragma unroll
      for (int j = 0; j < 4; ++j) {
        float v = acc[r][c][j] + bb;
        if (RELU) v = fmaxf(v, 0.f);
        Cz[(size_t)(row + j) * N + col] = (OutT)v;
      }
    }
  }
}

// ---------------------------------------------------------------------------
// Flash attention — R17-verified exactly (builtin MFMAs, KVBLK=64, dbuf
// issue-early staging, exp2-domain softmax + defer-max).
// ---------------------------------------------------------------------------
__global__ __launch_bounds__(256) void k_attn(
    const __bf16* __restrict__ qkv, const __bf16* __restrict__ vT,
    const float* __restrict__ mask2, __bf16* __restrict__ out) {
  const int qb = blockIdx.x, h = blockIdx.y, b = blockIdx.z;
  const int tid = threadIdx.x, lane = tid & 63, wv = tid >> 6;
  const int lrow = lane & 15, hi = lane >> 4;

  __shared__ __bf16 sK[2][64 * 64];
  __shared__ __bf16 sV[2][64 * 64];

  const size_t base = (size_t)b * SEQ * 3072;
  const __bf16* Qb = qkv + base + h * 64;
  const __bf16* Kb = qkv + base + 1024 + h * 64;
  const __bf16* vTb = vT + ((size_t)b * 1024 + h * 64) * SEQ;
  const float* maskb = mask2 + (size_t)b * SEQ;

  const int q0 = qb * 64 + wv * 16;
  const bf16x8 qf0 = *(const bf16x8*)&Qb[(size_t)(q0 + lrow) * 3072 + hi * 8];
  const bf16x8 qf1 = *(const bf16x8*)&Qb[(size_t)(q0 + lrow) * 3072 + 32 + hi * 8];

  float m_r = -3e38f, l_r = 0.f;
  f32x4 o[4];
#pragma unroll
  for (int d = 0; d < 4; ++d) o[d] = f32x4{0.f, 0.f, 0.f, 0.f};

  const int srow = lane >> 3;
  const int scolE = ((lane & 7) ^ srow) * 8;
  const int swz = (lrow & 7) << 4;

  auto stage = [&](int t) {
    const int k0s = t * 64;
    __bf16* dK = sK[t & 1];
    __bf16* dV = sV[t & 1];
#pragma unroll
    for (int r = 0; r < 2; ++r) {
      const int rb = r * 4 + wv;
      const int row = rb * 8 + srow;
      gload_lds16(Kb + (size_t)(k0s + row) * 3072 + scolE, &dK[rb * 512]);
      gload_lds16(vTb + (size_t)row * SEQ + k0s + scolE, &dV[rb * 512]);
    }
  };

  stage(0);
  const int NT = SEQ / 64;
  for (int t = 0; t < NT; ++t) {
    __syncthreads();
    if (t + 1 < NT) stage(t + 1);
    const __bf16* cK = sK[t & 1];
    const __bf16* cV = sV[t & 1];
    const int k0 = t * 64;

    f32x4 st[4];
#pragma unroll
    for (int t4 = 0; t4 < 4; ++t4) {
      const char* rp = (const char*)cK + (t4 * 16 + lrow) * 128;
      const bf16x8 ka = *(const bf16x8*)(rp + ((hi * 16) ^ swz));
      const bf16x8 kb = *(const bf16x8*)(rp + ((64 + hi * 16) ^ swz));
      f32x4 a = f32x4{0.f, 0.f, 0.f, 0.f};
      a = __builtin_amdgcn_mfma_f32_16x16x32_bf16(ka, qf0, a, 0, 0, 0);
      a = __builtin_amdgcn_mfma_f32_16x16x32_bf16(kb, qf1, a, 0, 0, 0);
      st[t4] = a;
    }

    float pm = -3e38f;
#pragma unroll
    for (int t4 = 0; t4 < 4; ++t4) {
      const f32x4 mk = *(const f32x4*)&maskb[k0 + t4 * 16 + hi * 4];
#pragma unroll
      for (int j = 0; j < 4; ++j) {
        st[t4][j] = st[t4][j] * 0.18033688f + mk[j];
        pm = fmaxf(pm, st[t4][j]);
      }
    }
    pm = fmaxf(pm, __shfl_xor(pm, 16));
    pm = fmaxf(pm, __shfl_xor(pm, 32));

    if (__any(pm > m_r + 11.5f)) {
      const float mn = fmaxf(m_r, pm);
      const float so = __builtin_amdgcn_exp2f(m_r - mn);
      m_r = mn;
      l_r *= so;
      float so_o[4];
#pragma unroll
      for (int jj = 0; jj < 4; ++jj) so_o[jj] = __shfl(so, hi * 4 + jj);
#pragma unroll
      for (int d = 0; d < 4; ++d)
#pragma unroll
        for (int jj = 0; jj < 4; ++jj) o[d][jj] *= so_o[jj];
    }

    float rs = 0.f;
#pragma unroll
    for (int t4 = 0; t4 < 4; ++t4)
#pragma unroll
      for (int j = 0; j < 4; ++j) {
        st[t4][j] = __builtin_amdgcn_exp2f(st[t4][j] - m_r);
        rs += st[t4][j];
      }
    rs += __shfl_xor(rs, 16);
    rs += __shfl_xor(rs, 32);
    l_r += rs;

    s16x4 pa[4];
#pragma unroll
    for (int t4 = 0; t4 < 4; ++t4)
#pragma unroll
      for (int j = 0; j < 4; ++j) {
        const __bf16 pb = (__bf16)st[t4][j];
        pa[t4][j] = __builtin_bit_cast(short, pb);
      }

#pragma unroll
    for (int d = 0; d < 4; ++d) {
      const char* rp = (const char*)cV + (d * 16 + lrow) * 128;
#pragma unroll
      for (int t4 = 0; t4 < 4; ++t4) {
        const s16x4 vb = *(const s16x4*)(rp + ((t4 * 32 + hi * 8) ^ swz));
        o[d] = __builtin_amdgcn_mfma_f32_16x16x16bf16_1k(pa[t4], vb, o[d], 0, 0, 0);
      }
    }
  }

  __syncthreads();
  float linv[4];
#pragma unroll
  for (int jj = 0; jj < 4; ++jj) linv[jj] = 1.0f / __shfl(l_r, hi * 4 + jj);
#pragma unroll
  for (int d = 0; d < 4; ++d)
#pragma unroll
    for (int jj = 0; jj < 4; ++jj)
      out[((size_t)b * SEQ + q0 + hi * 4 + jj) * DMODEL + h * 64 + d * 16 + lrow] =
          (__bf16)(o[d][jj] * linv[jj]);
}

// ---------------------------------------------------------------------------
// out = LayerNorm(x + y [+ y2]) * g + beta ; y/y2 nullable.
// ---------------------------------------------------------------------------
__global__ __launch_bounds__(256) void k_add_ln(
    const float* __restrict__ x, const float* __restrict__ y,
    const float* __restrict__ y2, const float* __restrict__ g,
    const float* __restrict__ be, float* __restrict__ of,
    __bf16* __restrict__ ob) {
  const int row = blockIdx.x, tid = threadIdx.x;
  const float4 a = ((const float4*)(x + (size_t)row * 1024))[tid];
  float4 b = {0.f, 0.f, 0.f, 0.f};
  if (y) b = ((const float4*)(y + (size_t)row * 1024))[tid];
  float4 c = {0.f, 0.f, 0.f, 0.f};
  if (y2) c = ((const float4*)(y2 + (size_t)row * 1024))[tid];
  const float v0 = a.x + b.x + c.x, v1 = a.y + b.y + c.y;
  const float v2 = a.z + b.z + c.z, v3 = a.w + b.w + c.w;
  float s = v0 + v1 + v2 + v3;
  float s2 = v0 * v0 + v1 * v1 + v2 * v2 + v3 * v3;
#pragma unroll
  for (int off = 32; off > 0; off >>= 1) {
    s += __shfl_xor(s, off);
    s2 += __shfl_xor(s2, off);
  }
  __shared__ float red[2][4];
  const int wv = tid >> 6, lane = tid & 63;
  if (lane == 0) { red[0][wv] = s; red[1][wv] = s2; }
  __syncthreads();
  s = red[0][0] + red[0][1] + red[0][2] + red[0][3];
  s2 = red[1][0] + red[1][1] + red[1][2] + red[1][3];
  const float mean = s * (1.0f / 1024.0f);
  const float var = s2 * (1.0f / 1024.0f) - mean * mean;
  const float rstd = rsqrtf(var + 1e-5f);
  const float4 gg = ((const float4*)g)[tid];
  const float4 bt = ((const float4*)be)[tid];
  float4 r;
  r.x = (v0 - mean) * rstd * gg.x + bt.x;
  r.y = (v1 - mean) * rstd * gg.y + bt.y;
  r.z = (v2 - mean) * rstd * gg.z + bt.z;
  r.w = (v3 - mean) * rstd * gg.w + bt.w;
  ((float4*)(of + (size_t)row * 1024))[tid] = r;
  if (ob) {
    bf16x4 rb;
    rb[0] = (__bf16)r.x; rb[1] = (__bf16)r.y; rb[2] = (__bf16)r.z; rb[3] = (__bf16)r.w;
    *(bf16x4*)(ob + (size_t)row * 1024 + tid * 4) = rb;
  }
}

// ---------------------------------------------------------------------------
extern "C" void kernel_launch(void* const* d_in, const int* in_sizes, int n_in,
                              void* d_out, int out_size, void* d_ws, size_t ws_size,
                              hipStream_t stream) {
  const float* x = (const float*)d_in[0];
  const float* src_mask = (const float*)d_in[1];
  const float* w_q = (const float*)d_in[2];
  const float* b_q = (const float*)d_in[3];
  const float* w_k = (const float*)d_in[4];
  const float* b_k = (const float*)d_in[5];
  const float* w_v = (const float*)d_in[6];
  const float* b_v = (const float*)d_in[7];
  const float* w_o = (const float*)d_in[8];
  const float* b_o = (const float*)d_in[9];
  const float* w_ff1 = (const float*)d_in[10];
  const float* b_ff1 = (const float*)d_in[11];
  const float* w_ff2 = (const float*)d_in[12];
  const float* b_ff2 = (const float*)d_in[13];
  const float* ln1_g = (const float*)d_in[14];
  const float* ln1_b = (const float*)d_in[15];
  const float* ln2_g = (const float*)d_in[16];
  const float* ln2_b = (const float*)d_in[17];

  char* ws = (char*)d_ws;
  constexpr size_t O_WQKVT = 0;
  constexpr size_t O_WOT = O_WQKVT + 3072ull * 1024 * 2;
  constexpr size_t O_WFF1T = O_WOT + 1024ull * 1024 * 2;
  constexpr size_t O_WFF2T = O_WFF1T + 4096ull * 1024 * 2;
  constexpr size_t O_BQKV = O_WFF2T + 4096ull * 1024 * 2;
  constexpr size_t O_XBF = O_BQKV + 3072ull * 4;
  constexpr size_t O_QKV = O_XBF + 4096ull * 1024 * 2;
  constexpr size_t O_ATTN = O_QKV + 4096ull * 3072 * 2;
  constexpr size_t O_PROJ = O_ATTN + 4096ull * 1024 * 2;
  constexpr size_t O_H1F = O_PROJ + 4096ull * 1024 * 4;
  constexpr size_t O_H1B = O_H1F + 4096ull * 1024 * 4;
  constexpr size_t O_MASK2 = O_H1B + 4096ull * 1024 * 2;   // 16KB
  constexpr size_t O_VT = O_PROJ;    // vT: dead before proj written
  constexpr size_t O_FF = O_QKV;     // ffb 32MB spans QKV+ATTN
  constexpr size_t O_FF2A = O_PROJ;  // 16MB (proj dead after ln1)
  constexpr size_t O_FF2B = 0;       // 16MB over dead wqkvT+woT+wff1T

  __bf16* wqkvT = (__bf16*)(ws + O_WQKVT);
  __bf16* woT = (__bf16*)(ws + O_WOT);
  __bf16* wff1T = (__bf16*)(ws + O_WFF1T);
  __bf16* wff2T = (__bf16*)(ws + O_WFF2T);
  float* bqkv = (float*)(ws + O_BQKV);
  __bf16* xbf = (__bf16*)(ws + O_XBF);
  __bf16* qkvb = (__bf16*)(ws + O_QKV);
  __bf16* attnb = (__bf16*)(ws + O_ATTN);
  float* proj = (float*)(ws + O_PROJ);
  float* h1f = (float*)(ws + O_H1F);
  __bf16* h1b = (__bf16*)(ws + O_H1B);
  float* mask2 = (float*)(ws + O_MASK2);
  __bf16* vT = (__bf16*)(ws + O_VT);
  __bf16* ffb = (__bf16*)(ws + O_FF);
  float* ff2a = (float*)(ws + O_FF2A);
  float* ff2b = (float*)(ws + O_FF2B);

  // weight prep
  k_transpose_to_bf16<<<dim3(32, 32), 256, 0, stream>>>(w_q, wqkvT, 1024, 1024);
  k_transpose_to_bf16<<<dim3(32, 32), 256, 0, stream>>>(w_k, wqkvT + 1024 * 1024, 1024, 1024);
  k_transpose_to_bf16<<<dim3(32, 32), 256, 0, stream>>>(w_v, wqkvT + 2 * 1024 * 1024, 1024, 1024);
  k_transpose_to_bf16<<<dim3(32, 32), 256, 0, stream>>>(w_o, woT, 1024, 1024);
  k_transpose_to_bf16<<<dim3(128, 32), 256, 0, stream>>>(w_ff1, wff1T, 1024, 4096);
  k_transpose_to_bf16<<<dim3(32, 128), 256, 0, stream>>>(w_ff2, wff2T, 4096, 1024);
  k_concat3<<<12, 256, 0, stream>>>(b_q, b_k, b_v, bqkv);
  k_scale_mask<<<16, 256, 0, stream>>>(src_mask, mask2, BATCH * SEQ);
  k_cvt_bf16<<<4096, 256, 0, stream>>>(x, xbf, MTOT * DMODEL);

  // fused QKV projection (256^2 counted-vmcnt pipeline)
  k_gemm256<false, __bf16><<<dim3(12, 16), 512, 0, stream>>>(xbf, wqkvT, bqkv, qkvb,
                                                             MTOT, 3072, 1024);
  // V transpose
  k_transpose_v<<<dim3(64, 32, 2), 256, 0, stream>>>(qkvb, vT);
  // attention (R17-verified)
  k_attn<<<dim3(SEQ / 64, NHEAD, BATCH), 256, 0, stream>>>(qkvb, vT, mask2, attnb);
  // output projection
  k_gemm<2, false, float><<<dim3(8, 64, 1), 256, 0, stream>>>(
      attnb, woT, b_o, proj, nullptr, MTOT, 1024, 1024, 1024);
  // ln1
  k_add_ln<<<4096, 256, 0, stream>>>(x, proj, nullptr, ln1_g, ln1_b, h1f, h1b);
  // ff1 + relu (256^2 counted-vmcnt pipeline)
  k_gemm256<true, __bf16><<<dim3(16, 16), 512, 0, stream>>>(h1b, wff1T, b_ff1, ffb,
                                                            MTOT, DFF, 1024);
  // ff2 split-K x2 in ONE dispatch (gridDim.z=2 -> 4 blocks/CU co-resident):
  // z=0 -> ff2a (with bias), z=1 -> ff2b (zero bias)
  k_gemm<2, false, float><<<dim3(8, 64, 2), 256, 0, stream>>>(
      ffb, wff2T, b_ff2, ff2a, ff2b, MTOT, 1024, DFF, 2048);
  // ln2 -> d_out: ff2a + h1 + ff2b
  k_add_ln<<<4096, 256, 0, stream>>>(ff2a, h1f, ff2b, ln2_g, ln2_b,
                                     (float*)d_out, nullptr);
}

// Round 21
// 270.879 us; speedup vs baseline: 1.0565x; 1.0083x over previous
//
#include <hip/hip_runtime.h>
#include <cstdint>
#include <cstddef>

#define BATCH 2
#define SEQ 2048
#define DMODEL 1024
#define NHEAD 16
#define DFF 4096
#define MTOT (BATCH * SEQ) /* 4096 */

typedef __bf16 bf16x8 __attribute__((ext_vector_type(8)));
typedef __bf16 bf16x4 __attribute__((ext_vector_type(4)));
typedef short s16x4 __attribute__((ext_vector_type(4)));
typedef float f32x4 __attribute__((ext_vector_type(4)));

#define S_BARRIER() __builtin_amdgcn_s_barrier()
#define SCHED_FENCE() __builtin_amdgcn_sched_barrier(0)
#define VMCNT8() asm volatile("s_waitcnt vmcnt(8)" ::: "memory")
#define VMCNT4() asm volatile("s_waitcnt vmcnt(4)" ::: "memory")
#define VMCNT0() asm volatile("s_waitcnt vmcnt(0)" ::: "memory")

// async global->LDS, 16B/lane; LDS dest = wave-uniform base + lane*16 (m104).
__device__ __forceinline__ void gload_lds16(const void* g, void* l) {
  __builtin_amdgcn_global_load_lds(
      (__attribute__((address_space(1))) void*)(uintptr_t)g,
      (__attribute__((address_space(3))) void*)(uint32_t)(uintptr_t)l,
      16, 0, 0);
}

// ---------------------------------------------------------------------------
// fp32 [K,N] -> bf16 [N,K] transpose (weights -> B^T layout)
// ---------------------------------------------------------------------------
__global__ __launch_bounds__(256) void k_transpose_to_bf16(
    const float* __restrict__ w, __bf16* __restrict__ wt, int K, int N) {
  __shared__ float t[32][33];
  const int n0 = blockIdx.x * 32, k0 = blockIdx.y * 32;
  const int tx = threadIdx.x & 31, ty = threadIdx.x >> 5;
#pragma unroll
  for (int i = ty; i < 32; i += 8) t[i][tx] = w[(size_t)(k0 + i) * N + n0 + tx];
  __syncthreads();
#pragma unroll
  for (int i = ty; i < 32; i += 8)
    wt[(size_t)(n0 + i) * K + k0 + tx] = (__bf16)t[tx][i];
}

__global__ __launch_bounds__(256) void k_cvt_bf16(
    const float* __restrict__ in, __bf16* __restrict__ out, int n) {
  const int i = (blockIdx.x * 256 + threadIdx.x) * 4;
  if (i >= n) return;
  const float4 v = *(const float4*)(in + i);
  bf16x4 r;
  r[0] = (__bf16)v.x; r[1] = (__bf16)v.y; r[2] = (__bf16)v.z; r[3] = (__bf16)v.w;
  *(bf16x4*)(out + i) = r;
}

__global__ void k_concat3(const float* __restrict__ a, const float* __restrict__ b,
                          const float* __restrict__ c, float* __restrict__ o) {
  const int i = blockIdx.x * 256 + threadIdx.x;
  if (i >= 3072) return;
  o[i] = (i < 1024) ? a[i] : (i < 2048) ? b[i - 1024] : c[i - 2048];
}

// mask * log2(e) for exp2-domain softmax
__global__ void k_scale_mask(const float* __restrict__ in, float* __restrict__ o, int n) {
  const int i = blockIdx.x * 256 + threadIdx.x;
  if (i < n) o[i] = in[i] * 1.44269504f;
}

// bf16 V-section transpose: qkvb[b*S+s][2048+c] -> vT[b*1024+c][s]
__global__ __launch_bounds__(256) void k_transpose_v(
    const __bf16* __restrict__ qkvb, __bf16* __restrict__ vT) {
  __shared__ __bf16 t[32][33];
  const int s0 = blockIdx.x * 32, c0 = blockIdx.y * 32, b = blockIdx.z;
  const int tx = threadIdx.x & 31, ty = threadIdx.x >> 5;
#pragma unroll
  for (int i = ty; i < 32; i += 8)
    t[i][tx] = qkvb[(size_t)(b * SEQ + s0 + i) * 3072 + 2048 + c0 + tx];
  __syncthreads();
#pragma unroll
  for (int i = ty; i < 32; i += 8)
    vT[((size_t)b * 1024 + c0 + i) * SEQ + s0 + tx] = t[tx][i];
}

// ---------------------------------------------------------------------------
// 256x256 deep-pipelined MFMA GEMM (T3+T4 counted-vmcnt, ALL-BUILTIN MFMAs).
// R16-verified. 512 thr = 8 waves (2M x 4N); wave owns 128x64.
// ---------------------------------------------------------------------------
template <bool RELU, typename OutT>
__global__ __launch_bounds__(512) void k_gemm256(
    const __bf16* __restrict__ A, const __bf16* __restrict__ BT,
    const float* __restrict__ bias, OutT* __restrict__ C,
    int M, int N, int K) {
  __shared__ __align__(16) __bf16 sA[4 * 8192];
  __shared__ __align__(16) __bf16 sB[4 * 8192];
  const int tid = threadIdx.x, lane = tid & 63, wv = tid >> 6;
  const int wm = wv >> 2, wn = wv & 3;
  const int lrow = lane & 15, hi = lane >> 4;
  const int nwg = gridDim.x * gridDim.y;
  const int flat = blockIdx.y * gridDim.x + blockIdx.x;
  const int cpx = nwg >> 3;
  const int swzb = (flat & 7) * cpx + (flat >> 3);
  const int m0 = (swzb / gridDim.x) * 256;
  const int n0 = (swzb % gridDim.x) * 256;
  const int NT = K >> 6;

  const int lsub = lane >> 2;
  const int gg = (lane & 3) ^ ((lane >> 3) & 3);
  const int gr = hi ^ ((lrow >> 1) & 3);

  f32x4 acc[8][4];
#pragma unroll
  for (int r = 0; r < 8; ++r)
#pragma unroll
    for (int c = 0; c < 4; ++c) acc[r][c] = f32x4{0.f, 0.f, 0.f, 0.f};

  auto stage = [&](int p) {
    const int tile = p >> 1;
    const int slot = (((tile & 1) * 2) + (p & 1)) * 8192;
    const int kcol = tile * 64 + (p & 1) * 32 + gg * 8;
#pragma unroll
    for (int i = 0; i < 2; ++i) {
      const int c = wv * 2 + i;
      gload_lds16(A + (size_t)(m0 + c * 16 + lsub) * K + kcol, &sA[slot + c * 512]);
      gload_lds16(BT + (size_t)(n0 + c * 16 + lsub) * K + kcol, &sB[slot + c * 512]);
    }
  };

  auto compute = [&](int p) {
    const int slot = ((((p >> 1) & 1) * 2) + (p & 1)) * 8192;
    bf16x8 af[8], bfv[4];
#pragma unroll
    for (int r = 0; r < 8; ++r)
      af[r] = *(const bf16x8*)&sA[slot + (wm * 128 + r * 16 + lrow) * 32 + gr * 8];
#pragma unroll
    for (int c = 0; c < 4; ++c)
      bfv[c] = *(const bf16x8*)&sB[slot + (wn * 64 + c * 16 + lrow) * 32 + gr * 8];
    __builtin_amdgcn_s_setprio(1);
#pragma unroll
    for (int r = 0; r < 8; ++r)
#pragma unroll
      for (int c = 0; c < 4; ++c)
        acc[r][c] = __builtin_amdgcn_mfma_f32_16x16x32_bf16(af[r], bfv[c],
                                                            acc[r][c], 0, 0, 0);
    __builtin_amdgcn_s_setprio(0);
  };

  stage(0); stage(1); stage(2);
  int p = 0;
  for (; p < 2 * NT - 3; ++p) {
    VMCNT8(); S_BARRIER(); SCHED_FENCE();
    stage(p + 3);
    compute(p);
  }
  VMCNT8(); S_BARRIER(); SCHED_FENCE(); compute(p); ++p;
  VMCNT4(); S_BARRIER(); SCHED_FENCE(); compute(p); ++p;
  VMCNT0(); S_BARRIER(); SCHED_FENCE(); compute(p);

#pragma unroll
  for (int r = 0; r < 8; ++r) {
    const int row = m0 + wm * 128 + r * 16 + hi * 4;
#pragma unroll
    for (int c = 0; c < 4; ++c) {
      const int col = n0 + wn * 64 + c * 16 + lrow;
      const float bb = bias[col];
#pragma unroll
      for (int j = 0; j < 4; ++j) {
        float v = acc[r][c][j] + bb;
        if (RELU) v = fmaxf(v, 0.f);
        C[(size_t)(row + j) * N + col] = (OutT)v;
      }
    }
  }
}

// ---------------------------------------------------------------------------
// bf16 MFMA GEMM (R9-verified body + XCD swizzle) with single-dispatch
// split-K: blockIdx.z selects K-range [z*KS,(z+1)*KS), output buffer
// (z==0 -> C0 with bias, z==1 -> C1 with zero bias). BM=MF*32, BN=128, BK=64.
// ---------------------------------------------------------------------------
template <int MF, bool RELU, typename OutT>
__global__ __launch_bounds__(256) void k_gemm(
    const __bf16* __restrict__ A, const __bf16* __restrict__ BT,
    const float* __restrict__ bias, OutT* __restrict__ C0,
    OutT* __restrict__ C1, int M, int N, int lda, int KS) {
  __shared__ __bf16 sA[MF * 32 * 64];
  __shared__ __bf16 sB[128 * 64];
  const int tid = threadIdx.x, lane = tid & 63, wv = tid >> 6;
  const int wm = wv >> 1, wn = wv & 1;
  const int lrow = lane & 15, hi = lane >> 4;
  const int nwg = gridDim.x * gridDim.y;
  const int flat = blockIdx.y * gridDim.x + blockIdx.x;
  const int cpx = nwg >> 3;
  const int swzb = (flat & 7) * cpx + (flat >> 3);
  const int m0 = (swzb / gridDim.x) * (MF * 32);
  const int n0 = (swzb % gridDim.x) * 128;
  const int koff = blockIdx.z * KS;
  OutT* Cz = blockIdx.z ? C1 : C0;
  const int srow = lane >> 3;
  const int scolE = ((lane & 7) ^ srow) * 8;
  const int swz = (lrow & 7) << 4;

  f32x4 acc[MF][4];
#pragma unroll
  for (int r = 0; r < MF; ++r)
#pragma unroll
    for (int c = 0; c < 4; ++c) acc[r][c] = f32x4{0.f, 0.f, 0.f, 0.f};

  for (int k0 = 0; k0 < KS; k0 += 64) {
    __syncthreads();
#pragma unroll
    for (int rb = wv; rb < MF * 4; rb += 4) {
      const int row = rb * 8 + srow;
      gload_lds16(A + (size_t)(m0 + row) * lda + koff + k0 + scolE, &sA[rb * 512]);
    }
#pragma unroll
    for (int rb = wv; rb < 16; rb += 4) {
      const int row = rb * 8 + srow;
      gload_lds16(BT + (size_t)(n0 + row) * lda + koff + k0 + scolE, &sB[rb * 512]);
    }
    __syncthreads();
#pragma unroll
    for (int kc = 0; kc < 2; ++kc) {
      bf16x8 af[MF], bfr[4];
#pragma unroll
      for (int r = 0; r < MF; ++r) {
        const int row = wm * (MF * 16) + r * 16 + lrow;
        af[r] = *(const bf16x8*)((const char*)sA + row * 128 + ((kc * 64 + hi * 16) ^ swz));
      }
#pragma unroll
      for (int c = 0; c < 4; ++c) {
        const int row = wn * 64 + c * 16 + lrow;
        bfr[c] = *(const bf16x8*)((const char*)sB + row * 128 + ((kc * 64 + hi * 16) ^ swz));
      }
#pragma unroll
      for (int r = 0; r < MF; ++r)
#pragma unroll
        for (int c = 0; c < 4; ++c)
          acc[r][c] = __builtin_amdgcn_mfma_f32_16x16x32_bf16(af[r], bfr[c],
                                                              acc[r][c], 0, 0, 0);
    }
  }

#pragma unroll
  for (int r = 0; r < MF; ++r) {
    const int row = m0 + wm * (MF * 16) + r * 16 + hi * 4;
#pragma unroll
    for (int c = 0; c < 4; ++c) {
      const int col = n0 + wn * 64 + c * 16 + lrow;
      const float bb = (blockIdx.z == 0) ? bias[col] : 0.f;
#pragma unroll
      for (int j = 0; j < 4; ++j) {
        float v = acc[r][c][j] + bb;
        if (RELU) v = fmaxf(v, 0.f);
        Cz[(size_t)(row + j) * N + col] = (OutT)v;
      }
    }
  }
}

// ---------------------------------------------------------------------------
// Flash attention — R17-verified per-wave body, widened block: QBLK=128 via
// 8 waves (512 thr) sharing ONE K/V staging. Halves K/V HBM/L2 re-reads and
// per-CU stage-DMA traffic; fragment layouts, softmax, and sync protocol are
// byte-identical per wave (q0 = qb*128 + wv*16). Grid (SEQ/128, H, B).
// ---------------------------------------------------------------------------
__global__ __launch_bounds__(512) void k_attn(
    const __bf16* __restrict__ qkv, const __bf16* __restrict__ vT,
    const float* __restrict__ mask2, __bf16* __restrict__ out) {
  const int qb = blockIdx.x, h = blockIdx.y, b = blockIdx.z;
  const int tid = threadIdx.x, lane = tid & 63, wv = tid >> 6;
  const int lrow = lane & 15, hi = lane >> 4;

  __shared__ __bf16 sK[2][64 * 64];  // [buf][key][d], swizzled
  __shared__ __bf16 sV[2][64 * 64];  // [buf][d][key], swizzled

  const size_t base = (size_t)b * SEQ * 3072;
  const __bf16* Qb = qkv + base + h * 64;
  const __bf16* Kb = qkv + base + 1024 + h * 64;
  const __bf16* vTb = vT + ((size_t)b * 1024 + h * 64) * SEQ;
  const float* maskb = mask2 + (size_t)b * SEQ;

  const int q0 = qb * 128 + wv * 16;
  const bf16x8 qf0 = *(const bf16x8*)&Qb[(size_t)(q0 + lrow) * 3072 + hi * 8];
  const bf16x8 qf1 = *(const bf16x8*)&Qb[(size_t)(q0 + lrow) * 3072 + 32 + hi * 8];

  float m_r = -3e38f, l_r = 0.f;
  f32x4 o[4];
#pragma unroll
  for (int d = 0; d < 4; ++d) o[d] = f32x4{0.f, 0.f, 0.f, 0.f};

  const int srow = lane >> 3;
  const int scolE = ((lane & 7) ^ srow) * 8;
  const int swz = (lrow & 7) << 4;

  // 8 waves: each stages one 8-row chunk of K and one of V (same layout as
  // the verified 4-wave version where each wave staged two chunks).
  auto stage = [&](int t) {
    const int k0s = t * 64;
    __bf16* dK = sK[t & 1];
    __bf16* dV = sV[t & 1];
    const int rb = wv;  // 0..7
    const int row = rb * 8 + srow;
    gload_lds16(Kb + (size_t)(k0s + row) * 3072 + scolE, &dK[rb * 512]);
    gload_lds16(vTb + (size_t)row * SEQ + k0s + scolE, &dV[rb * 512]);
  };

  stage(0);
  const int NT = SEQ / 64;
  for (int t = 0; t < NT; ++t) {
    __syncthreads();
    if (t + 1 < NT) stage(t + 1);
    const __bf16* cK = sK[t & 1];
    const __bf16* cV = sV[t & 1];
    const int k0 = t * 64;

    f32x4 st[4];
#pragma unroll
    for (int t4 = 0; t4 < 4; ++t4) {
      const char* rp = (const char*)cK + (t4 * 16 + lrow) * 128;
      const bf16x8 ka = *(const bf16x8*)(rp + ((hi * 16) ^ swz));
      const bf16x8 kb = *(const bf16x8*)(rp + ((64 + hi * 16) ^ swz));
      f32x4 a = f32x4{0.f, 0.f, 0.f, 0.f};
      a = __builtin_amdgcn_mfma_f32_16x16x32_bf16(ka, qf0, a, 0, 0, 0);
      a = __builtin_amdgcn_mfma_f32_16x16x32_bf16(kb, qf1, a, 0, 0, 0);
      st[t4] = a;
    }

    float pm = -3e38f;
#pragma unroll
    for (int t4 = 0; t4 < 4; ++t4) {
      const f32x4 mk = *(const f32x4*)&maskb[k0 + t4 * 16 + hi * 4];
#pragma unroll
      for (int j = 0; j < 4; ++j) {
        st[t4][j] = st[t4][j] * 0.18033688f + mk[j];
        pm = fmaxf(pm, st[t4][j]);
      }
    }
    pm = fmaxf(pm, __shfl_xor(pm, 16));
    pm = fmaxf(pm, __shfl_xor(pm, 32));

    if (__any(pm > m_r + 11.5f)) {
      const float mn = fmaxf(m_r, pm);
      const float so = __builtin_amdgcn_exp2f(m_r - mn);
      m_r = mn;
      l_r *= so;
      float so_o[4];
#pragma unroll
      for (int jj = 0; jj < 4; ++jj) so_o[jj] = __shfl(so, hi * 4 + jj);
#pragma unroll
      for (int d = 0; d < 4; ++d)
#pragma unroll
        for (int jj = 0; jj < 4; ++jj) o[d][jj] *= so_o[jj];
    }

    float rs = 0.f;
#pragma unroll
    for (int t4 = 0; t4 < 4; ++t4)
#pragma unroll
      for (int j = 0; j < 4; ++j) {
        st[t4][j] = __builtin_amdgcn_exp2f(st[t4][j] - m_r);
        rs += st[t4][j];
      }
    rs += __shfl_xor(rs, 16);
    rs += __shfl_xor(rs, 32);
    l_r += rs;

    s16x4 pa[4];
#pragma unroll
    for (int t4 = 0; t4 < 4; ++t4)
#pragma unroll
      for (int j = 0; j < 4; ++j) {
        const __bf16 pb = (__bf16)st[t4][j];
        pa[t4][j] = __builtin_bit_cast(short, pb);
      }

#pragma unroll
    for (int d = 0; d < 4; ++d) {
      const char* rp = (const char*)cV + (d * 16 + lrow) * 128;
#pragma unroll
      for (int t4 = 0; t4 < 4; ++t4) {
        const s16x4 vb = *(const s16x4*)(rp + ((t4 * 32 + hi * 8) ^ swz));
        o[d] = __builtin_amdgcn_mfma_f32_16x16x16bf16_1k(pa[t4], vb, o[d], 0, 0, 0);
      }
    }
  }

  __syncthreads();
  float linv[4];
#pragma unroll
  for (int jj = 0; jj < 4; ++jj) linv[jj] = 1.0f / __shfl(l_r, hi * 4 + jj);
#pragma unroll
  for (int d = 0; d < 4; ++d)
#pragma unroll
    for (int jj = 0; jj < 4; ++jj)
      out[((size_t)b * SEQ + q0 + hi * 4 + jj) * DMODEL + h * 64 + d * 16 + lrow] =
          (__bf16)(o[d][jj] * linv[jj]);
}

// ---------------------------------------------------------------------------
// out = LayerNorm(x + y [+ y2]) * g + beta ; y/y2 nullable.
// ---------------------------------------------------------------------------
__global__ __launch_bounds__(256) void k_add_ln(
    const float* __restrict__ x, const float* __restrict__ y,
    const float* __restrict__ y2, const float* __restrict__ g,
    const float* __restrict__ be, float* __restrict__ of,
    __bf16* __restrict__ ob) {
  const int row = blockIdx.x, tid = threadIdx.x;
  const float4 a = ((const float4*)(x + (size_t)row * 1024))[tid];
  float4 b = {0.f, 0.f, 0.f, 0.f};
  if (y) b = ((const float4*)(y + (size_t)row * 1024))[tid];
  float4 c = {0.f, 0.f, 0.f, 0.f};
  if (y2) c = ((const float4*)(y2 + (size_t)row * 1024))[tid];
  const float v0 = a.x + b.x + c.x, v1 = a.y + b.y + c.y;
  const float v2 = a.z + b.z + c.z, v3 = a.w + b.w + c.w;
  float s = v0 + v1 + v2 + v3;
  float s2 = v0 * v0 + v1 * v1 + v2 * v2 + v3 * v3;
#pragma unroll
  for (int off = 32; off > 0; off >>= 1) {
    s += __shfl_xor(s, off);
    s2 += __shfl_xor(s2, off);
  }
  __shared__ float red[2][4];
  const int wv = tid >> 6, lane = tid & 63;
  if (lane == 0) { red[0][wv] = s; red[1][wv] = s2; }
  __syncthreads();
  s = red[0][0] + red[0][1] + red[0][2] + red[0][3];
  s2 = red[1][0] + red[1][1] + red[1][2] + red[1][3];
  const float mean = s * (1.0f / 1024.0f);
  const float var = s2 * (1.0f / 1024.0f) - mean * mean;
  const float rstd = rsqrtf(var + 1e-5f);
  const float4 gg = ((const float4*)g)[tid];
  const float4 bt = ((const float4*)be)[tid];
  float4 r;
  r.x = (v0 - mean) * rstd * gg.x + bt.x;
  r.y = (v1 - mean) * rstd * gg.y + bt.y;
  r.z = (v2 - mean) * rstd * gg.z + bt.z;
  r.w = (v3 - mean) * rstd * gg.w + bt.w;
  ((float4*)(of + (size_t)row * 1024))[tid] = r;
  if (ob) {
    bf16x4 rb;
    rb[0] = (__bf16)r.x; rb[1] = (__bf16)r.y; rb[2] = (__bf16)r.z; rb[3] = (__bf16)r.w;
    *(bf16x4*)(ob + (size_t)row * 1024 + tid * 4) = rb;
  }
}

// ---------------------------------------------------------------------------
extern "C" void kernel_launch(void* const* d_in, const int* in_sizes, int n_in,
                              void* d_out, int out_size, void* d_ws, size_t ws_size,
                              hipStream_t stream) {
  const float* x = (const float*)d_in[0];
  const float* src_mask = (const float*)d_in[1];
  const float* w_q = (const float*)d_in[2];
  const float* b_q = (const float*)d_in[3];
  const float* w_k = (const float*)d_in[4];
  const float* b_k = (const float*)d_in[5];
  const float* w_v = (const float*)d_in[6];
  const float* b_v = (const float*)d_in[7];
  const float* w_o = (const float*)d_in[8];
  const float* b_o = (const float*)d_in[9];
  const float* w_ff1 = (const float*)d_in[10];
  const float* b_ff1 = (const float*)d_in[11];
  const float* w_ff2 = (const float*)d_in[12];
  const float* b_ff2 = (const float*)d_in[13];
  const float* ln1_g = (const float*)d_in[14];
  const float* ln1_b = (const float*)d_in[15];
  const float* ln2_g = (const float*)d_in[16];
  const float* ln2_b = (const float*)d_in[17];

  char* ws = (char*)d_ws;
  constexpr size_t O_WQKVT = 0;
  constexpr size_t O_WOT = O_WQKVT + 3072ull * 1024 * 2;
  constexpr size_t O_WFF1T = O_WOT + 1024ull * 1024 * 2;
  constexpr size_t O_WFF2T = O_WFF1T + 4096ull * 1024 * 2;
  constexpr size_t O_BQKV = O_WFF2T + 4096ull * 1024 * 2;
  constexpr size_t O_XBF = O_BQKV + 3072ull * 4;
  constexpr size_t O_QKV = O_XBF + 4096ull * 1024 * 2;
  constexpr size_t O_ATTN = O_QKV + 4096ull * 3072 * 2;
  constexpr size_t O_PROJ = O_ATTN + 4096ull * 1024 * 2;
  constexpr size_t O_H1F = O_PROJ + 4096ull * 1024 * 4;
  constexpr size_t O_H1B = O_H1F + 4096ull * 1024 * 4;
  constexpr size_t O_MASK2 = O_H1B + 4096ull * 1024 * 2;   // 16KB
  constexpr size_t O_VT = O_PROJ;    // vT: dead before proj written
  constexpr size_t O_FF = O_QKV;     // ffb 32MB spans QKV+ATTN
  constexpr size_t O_FF2A = O_PROJ;  // 16MB (proj dead after ln1)
  constexpr size_t O_FF2B = 0;       // 16MB over dead wqkvT+woT+wff1T

  __bf16* wqkvT = (__bf16*)(ws + O_WQKVT);
  __bf16* woT = (__bf16*)(ws + O_WOT);
  __bf16* wff1T = (__bf16*)(ws + O_WFF1T);
  __bf16* wff2T = (__bf16*)(ws + O_WFF2T);
  float* bqkv = (float*)(ws + O_BQKV);
  __bf16* xbf = (__bf16*)(ws + O_XBF);
  __bf16* qkvb = (__bf16*)(ws + O_QKV);
  __bf16* attnb = (__bf16*)(ws + O_ATTN);
  float* proj = (float*)(ws + O_PROJ);
  float* h1f = (float*)(ws + O_H1F);
  __bf16* h1b = (__bf16*)(ws + O_H1B);
  float* mask2 = (float*)(ws + O_MASK2);
  __bf16* vT = (__bf16*)(ws + O_VT);
  __bf16* ffb = (__bf16*)(ws + O_FF);
  float* ff2a = (float*)(ws + O_FF2A);
  float* ff2b = (float*)(ws + O_FF2B);

  // weight prep
  k_transpose_to_bf16<<<dim3(32, 32), 256, 0, stream>>>(w_q, wqkvT, 1024, 1024);
  k_transpose_to_bf16<<<dim3(32, 32), 256, 0, stream>>>(w_k, wqkvT + 1024 * 1024, 1024, 1024);
  k_transpose_to_bf16<<<dim3(32, 32), 256, 0, stream>>>(w_v, wqkvT + 2 * 1024 * 1024, 1024, 1024);
  k_transpose_to_bf16<<<dim3(32, 32), 256, 0, stream>>>(w_o, woT, 1024, 1024);
  k_transpose_to_bf16<<<dim3(128, 32), 256, 0, stream>>>(w_ff1, wff1T, 1024, 4096);
  k_transpose_to_bf16<<<dim3(32, 128), 256, 0, stream>>>(w_ff2, wff2T, 4096, 1024);
  k_concat3<<<12, 256, 0, stream>>>(b_q, b_k, b_v, bqkv);
  k_scale_mask<<<16, 256, 0, stream>>>(src_mask, mask2, BATCH * SEQ);
  k_cvt_bf16<<<4096, 256, 0, stream>>>(x, xbf, MTOT * DMODEL);

  // fused QKV projection (256^2 counted-vmcnt pipeline)
  k_gemm256<false, __bf16><<<dim3(12, 16), 512, 0, stream>>>(xbf, wqkvT, bqkv, qkvb,
                                                             MTOT, 3072, 1024);
  // V transpose
  k_transpose_v<<<dim3(64, 32, 2), 256, 0, stream>>>(qkvb, vT);
  // attention (QBLK=128: 8 waves share one K/V staging)
  k_attn<<<dim3(SEQ / 128, NHEAD, BATCH), 512, 0, stream>>>(qkvb, vT, mask2, attnb);
  // output projection
  k_gemm<2, false, float><<<dim3(8, 64, 1), 256, 0, stream>>>(
      attnb, woT, b_o, proj, nullptr, MTOT, 1024, 1024, 1024);
  // ln1
  k_add_ln<<<4096, 256, 0, stream>>>(x, proj, nullptr, ln1_g, ln1_b, h1f, h1b);
  // ff1 + relu (256^2 counted-vmcnt pipeline)
  k_gemm256<true, __bf16><<<dim3(16, 16), 512, 0, stream>>>(h1b, wff1T, b_ff1, ffb,
                                                            MTOT, DFF, 1024);
  // ff2 split-K x2 in ONE dispatch (4 blocks/CU co-resident)
  k_gemm<2, false, float><<<dim3(8, 64, 2), 256, 0, stream>>>(
      ffb, wff2T, b_ff2, ff2a, ff2b, MTOT, 1024, DFF, 2048);
  // ln2 -> d_out: ff2a + h1 + ff2b
  k_add_ln<<<4096, 256, 0, stream>>>(ff2a, h1f, ff2b, ln2_g, ln2_b,
                                     (float*)d_out, nullptr);
}

// Round 22
// 263.457 us; speedup vs baseline: 1.0863x; 1.0282x over previous
//
#include <hip/hip_runtime.h>
#include <cstdint>
#include <cstddef>

#define BATCH 2
#define SEQ 2048
#define DMODEL 1024
#define NHEAD 16
#define DFF 4096
#define MTOT (BATCH * SEQ) /* 4096 */

typedef __bf16 bf16x8 __attribute__((ext_vector_type(8)));
typedef __bf16 bf16x4 __attribute__((ext_vector_type(4)));
typedef short s16x4 __attribute__((ext_vector_type(4)));
typedef float f32x4 __attribute__((ext_vector_type(4)));

#define S_BARRIER() __builtin_amdgcn_s_barrier()
#define SCHED_FENCE() __builtin_amdgcn_sched_barrier(0)
#define VMCNT8() asm volatile("s_waitcnt vmcnt(8)" ::: "memory")
#define VMCNT4() asm volatile("s_waitcnt vmcnt(4)" ::: "memory")
#define VMCNT0() asm volatile("s_waitcnt vmcnt(0)" ::: "memory")

// async global->LDS, 16B/lane; LDS dest = wave-uniform base + lane*16 (m104).
__device__ __forceinline__ void gload_lds16(const void* g, void* l) {
  __builtin_amdgcn_global_load_lds(
      (__attribute__((address_space(1))) void*)(uintptr_t)g,
      (__attribute__((address_space(3))) void*)(uint32_t)(uintptr_t)l,
      16, 0, 0);
}

// ---------------------------------------------------------------------------
// fp32 [K,N] -> bf16 [N,K] transpose (weights -> B^T layout)
// ---------------------------------------------------------------------------
__global__ __launch_bounds__(256) void k_transpose_to_bf16(
    const float* __restrict__ w, __bf16* __restrict__ wt, int K, int N) {
  __shared__ float t[32][33];
  const int n0 = blockIdx.x * 32, k0 = blockIdx.y * 32;
  const int tx = threadIdx.x & 31, ty = threadIdx.x >> 5;
#pragma unroll
  for (int i = ty; i < 32; i += 8) t[i][tx] = w[(size_t)(k0 + i) * N + n0 + tx];
  __syncthreads();
#pragma unroll
  for (int i = ty; i < 32; i += 8)
    wt[(size_t)(n0 + i) * K + k0 + tx] = (__bf16)t[tx][i];
}

__global__ __launch_bounds__(256) void k_cvt_bf16(
    const float* __restrict__ in, __bf16* __restrict__ out, int n) {
  const int i = (blockIdx.x * 256 + threadIdx.x) * 4;
  if (i >= n) return;
  const float4 v = *(const float4*)(in + i);
  bf16x4 r;
  r[0] = (__bf16)v.x; r[1] = (__bf16)v.y; r[2] = (__bf16)v.z; r[3] = (__bf16)v.w;
  *(bf16x4*)(out + i) = r;
}

__global__ void k_concat3(const float* __restrict__ a, const float* __restrict__ b,
                          const float* __restrict__ c, float* __restrict__ o) {
  const int i = blockIdx.x * 256 + threadIdx.x;
  if (i >= 3072) return;
  o[i] = (i < 1024) ? a[i] : (i < 2048) ? b[i - 1024] : c[i - 2048];
}

// mask * log2(e) for exp2-domain softmax
__global__ void k_scale_mask(const float* __restrict__ in, float* __restrict__ o, int n) {
  const int i = blockIdx.x * 256 + threadIdx.x;
  if (i < n) o[i] = in[i] * 1.44269504f;
}

// bf16 V-section transpose: qkvb[b*S+s][2048+c] -> vT[b*1024+c][s]
__global__ __launch_bounds__(256) void k_transpose_v(
    const __bf16* __restrict__ qkvb, __bf16* __restrict__ vT) {
  __shared__ __bf16 t[32][33];
  const int s0 = blockIdx.x * 32, c0 = blockIdx.y * 32, b = blockIdx.z;
  const int tx = threadIdx.x & 31, ty = threadIdx.x >> 5;
#pragma unroll
  for (int i = ty; i < 32; i += 8)
    t[i][tx] = qkvb[(size_t)(b * SEQ + s0 + i) * 3072 + 2048 + c0 + tx];
  __syncthreads();
#pragma unroll
  for (int i = ty; i < 32; i += 8)
    vT[((size_t)b * 1024 + c0 + i) * SEQ + s0 + tx] = t[tx][i];
}

// ---------------------------------------------------------------------------
// 256x256 deep-pipelined MFMA GEMM (T3+T4 counted-vmcnt, ALL-BUILTIN MFMAs).
// R16-verified. 512 thr = 8 waves (2M x 4N); wave owns 128x64.
// ---------------------------------------------------------------------------
template <bool RELU, typename OutT>
__global__ __launch_bounds__(512) void k_gemm256(
    const __bf16* __restrict__ A, const __bf16* __restrict__ BT,
    const float* __restrict__ bias, OutT* __restrict__ C,
    int M, int N, int K) {
  __shared__ __align__(16) __bf16 sA[4 * 8192];
  __shared__ __align__(16) __bf16 sB[4 * 8192];
  const int tid = threadIdx.x, lane = tid & 63, wv = tid >> 6;
  const int wm = wv >> 2, wn = wv & 3;
  const int lrow = lane & 15, hi = lane >> 4;
  const int nwg = gridDim.x * gridDim.y;
  const int flat = blockIdx.y * gridDim.x + blockIdx.x;
  const int cpx = nwg >> 3;
  const int swzb = (flat & 7) * cpx + (flat >> 3);
  const int m0 = (swzb / gridDim.x) * 256;
  const int n0 = (swzb % gridDim.x) * 256;
  const int NT = K >> 6;

  const int lsub = lane >> 2;
  const int gg = (lane & 3) ^ ((lane >> 3) & 3);
  const int gr = hi ^ ((lrow >> 1) & 3);

  f32x4 acc[8][4];
#pragma unroll
  for (int r = 0; r < 8; ++r)
#pragma unroll
    for (int c = 0; c < 4; ++c) acc[r][c] = f32x4{0.f, 0.f, 0.f, 0.f};

  auto stage = [&](int p) {
    const int tile = p >> 1;
    const int slot = (((tile & 1) * 2) + (p & 1)) * 8192;
    const int kcol = tile * 64 + (p & 1) * 32 + gg * 8;
#pragma unroll
    for (int i = 0; i < 2; ++i) {
      const int c = wv * 2 + i;
      gload_lds16(A + (size_t)(m0 + c * 16 + lsub) * K + kcol, &sA[slot + c * 512]);
      gload_lds16(BT + (size_t)(n0 + c * 16 + lsub) * K + kcol, &sB[slot + c * 512]);
    }
  };

  auto compute = [&](int p) {
    const int slot = ((((p >> 1) & 1) * 2) + (p & 1)) * 8192;
    bf16x8 af[8], bfv[4];
#pragma unroll
    for (int r = 0; r < 8; ++r)
      af[r] = *(const bf16x8*)&sA[slot + (wm * 128 + r * 16 + lrow) * 32 + gr * 8];
#pragma unroll
    for (int c = 0; c < 4; ++c)
      bfv[c] = *(const bf16x8*)&sB[slot + (wn * 64 + c * 16 + lrow) * 32 + gr * 8];
    __builtin_amdgcn_s_setprio(1);
#pragma unroll
    for (int r = 0; r < 8; ++r)
#pragma unroll
      for (int c = 0; c < 4; ++c)
        acc[r][c] = __builtin_amdgcn_mfma_f32_16x16x32_bf16(af[r], bfv[c],
                                                            acc[r][c], 0, 0, 0);
    __builtin_amdgcn_s_setprio(0);
  };

  stage(0); stage(1); stage(2);
  int p = 0;
  for (; p < 2 * NT - 3; ++p) {
    VMCNT8(); S_BARRIER(); SCHED_FENCE();
    stage(p + 3);
    compute(p);
  }
  VMCNT8(); S_BARRIER(); SCHED_FENCE(); compute(p); ++p;
  VMCNT4(); S_BARRIER(); SCHED_FENCE(); compute(p); ++p;
  VMCNT0(); S_BARRIER(); SCHED_FENCE(); compute(p);

#pragma unroll
  for (int r = 0; r < 8; ++r) {
    const int row = m0 + wm * 128 + r * 16 + hi * 4;
#pragma unroll
    for (int c = 0; c < 4; ++c) {
      const int col = n0 + wn * 64 + c * 16 + lrow;
      const float bb = bias[col];
#pragma unroll
      for (int j = 0; j < 4; ++j) {
        float v = acc[r][c][j] + bb;
        if (RELU) v = fmaxf(v, 0.f);
        C[(size_t)(row + j) * N + col] = (OutT)v;
      }
    }
  }
}

// ---------------------------------------------------------------------------
// bf16 MFMA GEMM (R9-verified body + XCD swizzle) with single-dispatch
// split-K: blockIdx.z selects K-range [z*KS,(z+1)*KS), output buffer
// (z==0 -> C0 with bias, z==1 -> C1 with zero bias). BM=MF*32, BN=128, BK=64.
// ---------------------------------------------------------------------------
template <int MF, bool RELU, typename OutT>
__global__ __launch_bounds__(256) void k_gemm(
    const __bf16* __restrict__ A, const __bf16* __restrict__ BT,
    const float* __restrict__ bias, OutT* __restrict__ C0,
    OutT* __restrict__ C1, int M, int N, int lda, int KS) {
  __shared__ __bf16 sA[MF * 32 * 64];
  __shared__ __bf16 sB[128 * 64];
  const int tid = threadIdx.x, lane = tid & 63, wv = tid >> 6;
  const int wm = wv >> 1, wn = wv & 1;
  const int lrow = lane & 15, hi = lane >> 4;
  const int nwg = gridDim.x * gridDim.y;
  const int flat = blockIdx.y * gridDim.x + blockIdx.x;
  const int cpx = nwg >> 3;
  const int swzb = (flat & 7) * cpx + (flat >> 3);
  const int m0 = (swzb / gridDim.x) * (MF * 32);
  const int n0 = (swzb % gridDim.x) * 128;
  const int koff = blockIdx.z * KS;
  OutT* Cz = blockIdx.z ? C1 : C0;
  const int srow = lane >> 3;
  const int scolE = ((lane & 7) ^ srow) * 8;
  const int swz = (lrow & 7) << 4;

  f32x4 acc[MF][4];
#pragma unroll
  for (int r = 0; r < MF; ++r)
#pragma unroll
    for (int c = 0; c < 4; ++c) acc[r][c] = f32x4{0.f, 0.f, 0.f, 0.f};

  for (int k0 = 0; k0 < KS; k0 += 64) {
    __syncthreads();
#pragma unroll
    for (int rb = wv; rb < MF * 4; rb += 4) {
      const int row = rb * 8 + srow;
      gload_lds16(A + (size_t)(m0 + row) * lda + koff + k0 + scolE, &sA[rb * 512]);
    }
#pragma unroll
    for (int rb = wv; rb < 16; rb += 4) {
      const int row = rb * 8 + srow;
      gload_lds16(BT + (size_t)(n0 + row) * lda + koff + k0 + scolE, &sB[rb * 512]);
    }
    __syncthreads();
#pragma unroll
    for (int kc = 0; kc < 2; ++kc) {
      bf16x8 af[MF], bfr[4];
#pragma unroll
      for (int r = 0; r < MF; ++r) {
        const int row = wm * (MF * 16) + r * 16 + lrow;
        af[r] = *(const bf16x8*)((const char*)sA + row * 128 + ((kc * 64 + hi * 16) ^ swz));
      }
#pragma unroll
      for (int c = 0; c < 4; ++c) {
        const int row = wn * 64 + c * 16 + lrow;
        bfr[c] = *(const bf16x8*)((const char*)sB + row * 128 + ((kc * 64 + hi * 16) ^ swz));
      }
#pragma unroll
      for (int r = 0; r < MF; ++r)
#pragma unroll
        for (int c = 0; c < 4; ++c)
          acc[r][c] = __builtin_amdgcn_mfma_f32_16x16x32_bf16(af[r], bfr[c],
                                                              acc[r][c], 0, 0, 0);
    }
  }

#pragma unroll
  for (int r = 0; r < MF; ++r) {
    const int row = m0 + wm * (MF * 16) + r * 16 + hi * 4;
#pragma unroll
    for (int c = 0; c < 4; ++c) {
      const int col = n0 + wn * 64 + c * 16 + lrow;
      const float bb = (blockIdx.z == 0) ? bias[col] : 0.f;
#pragma unroll
      for (int j = 0; j < 4; ++j) {
        float v = acc[r][c][j] + bb;
        if (RELU) v = fmaxf(v, 0.f);
        Cz[(size_t)(row + j) * N + col] = (OutT)v;
      }
    }
  }
}

// ---------------------------------------------------------------------------
// Flash attention — QBLK=128 (8 waves, R21-verified sharing) x KVBLK=128:
// 16 iterations, 2 barriers each (halved vs R21). Per-wave loads per barrier
// stay at 4 gload_lds (K chunks wv, wv+8; V chunk wv of each 64-key half) —
// same issue rate as the verified config. Per-wave softmax/PV body is the
// R17-verified code unrolled over 8 key-groups (R14-verified arithmetic).
// LDS: dbuf x (16KB K + 2x8KB V) = 64KB.
// ---------------------------------------------------------------------------
__global__ __launch_bounds__(512) void k_attn(
    const __bf16* __restrict__ qkv, const __bf16* __restrict__ vT,
    const float* __restrict__ mask2, __bf16* __restrict__ out) {
  const int qb = blockIdx.x, h = blockIdx.y, b = blockIdx.z;
  const int tid = threadIdx.x, lane = tid & 63, wv = tid >> 6;
  const int lrow = lane & 15, hi = lane >> 4;

  __shared__ __bf16 sK[2][128 * 64];  // [buf][key][d], swizzled
  __shared__ __bf16 sV0[2][64 * 64];  // [buf][d][key 0..64)
  __shared__ __bf16 sV1[2][64 * 64];  // [buf][d][key 64..128)

  const size_t base = (size_t)b * SEQ * 3072;
  const __bf16* Qb = qkv + base + h * 64;
  const __bf16* Kb = qkv + base + 1024 + h * 64;
  const __bf16* vTb = vT + ((size_t)b * 1024 + h * 64) * SEQ;
  const float* maskb = mask2 + (size_t)b * SEQ;

  const int q0 = qb * 128 + wv * 16;
  const bf16x8 qf0 = *(const bf16x8*)&Qb[(size_t)(q0 + lrow) * 3072 + hi * 8];
  const bf16x8 qf1 = *(const bf16x8*)&Qb[(size_t)(q0 + lrow) * 3072 + 32 + hi * 8];

  float m_r = -3e38f, l_r = 0.f;
  f32x4 o[4];
#pragma unroll
  for (int d = 0; d < 4; ++d) o[d] = f32x4{0.f, 0.f, 0.f, 0.f};

  const int srow = lane >> 3;
  const int scolE = ((lane & 7) ^ srow) * 8;
  const int swz = (lrow & 7) << 4;

  auto stage = [&](int t) {
    const int k0s = t * 128;
    __bf16* dK = sK[t & 1];
    __bf16* dV0 = sV0[t & 1];
    __bf16* dV1 = sV1[t & 1];
#pragma unroll
    for (int r = 0; r < 2; ++r) {  // K: 16 chunks over 8 waves
      const int rb = wv + r * 8;
      const int row = rb * 8 + srow;
      gload_lds16(Kb + (size_t)(k0s + row) * 3072 + scolE, &dK[rb * 512]);
    }
    const int vrow = wv * 8 + srow;  // V: chunk wv of each half
    gload_lds16(vTb + (size_t)vrow * SEQ + k0s + scolE, &dV0[wv * 512]);
    gload_lds16(vTb + (size_t)vrow * SEQ + k0s + 64 + scolE, &dV1[wv * 512]);
  };

  stage(0);
  const int NT = SEQ / 128;
  for (int t = 0; t < NT; ++t) {
    __syncthreads();
    if (t + 1 < NT) stage(t + 1);
    const __bf16* cK = sK[t & 1];
    const __bf16* cV0 = sV0[t & 1];
    const __bf16* cV1 = sV1[t & 1];
    const int k0 = t * 128;

    // S^T = K * Q^T : st[t4][j] = S[key = t4*16 + 4hi + j][q = lrow]
    f32x4 st[8];
#pragma unroll
    for (int t4 = 0; t4 < 8; ++t4) {
      const char* rp = (const char*)cK + (t4 * 16 + lrow) * 128;
      const bf16x8 ka = *(const bf16x8*)(rp + ((hi * 16) ^ swz));
      const bf16x8 kb = *(const bf16x8*)(rp + ((64 + hi * 16) ^ swz));
      f32x4 a = f32x4{0.f, 0.f, 0.f, 0.f};
      a = __builtin_amdgcn_mfma_f32_16x16x32_bf16(ka, qf0, a, 0, 0, 0);
      a = __builtin_amdgcn_mfma_f32_16x16x32_bf16(kb, qf1, a, 0, 0, 0);
      st[t4] = a;
    }

    // exp2-domain logits: st*0.125*log2e + mask2
    float pm = -3e38f;
#pragma unroll
    for (int t4 = 0; t4 < 8; ++t4) {
      const f32x4 mk = *(const f32x4*)&maskb[k0 + t4 * 16 + hi * 4];
#pragma unroll
      for (int j = 0; j < 4; ++j) {
        st[t4][j] = st[t4][j] * 0.18033688f + mk[j];
        pm = fmaxf(pm, st[t4][j]);
      }
    }
    pm = fmaxf(pm, __shfl_xor(pm, 16));
    pm = fmaxf(pm, __shfl_xor(pm, 32));

    // T13 defer-max
    if (__any(pm > m_r + 11.5f)) {
      const float mn = fmaxf(m_r, pm);
      const float so = __builtin_amdgcn_exp2f(m_r - mn);
      m_r = mn;
      l_r *= so;
      float so_o[4];
#pragma unroll
      for (int jj = 0; jj < 4; ++jj) so_o[jj] = __shfl(so, hi * 4 + jj);
#pragma unroll
      for (int d = 0; d < 4; ++d)
#pragma unroll
        for (int jj = 0; jj < 4; ++jj) o[d][jj] *= so_o[jj];
    }

    float rs = 0.f;
#pragma unroll
    for (int t4 = 0; t4 < 8; ++t4)
#pragma unroll
      for (int j = 0; j < 4; ++j) {
        st[t4][j] = __builtin_amdgcn_exp2f(st[t4][j] - m_r);
        rs += st[t4][j];
      }
    rs += __shfl_xor(rs, 16);
    rs += __shfl_xor(rs, 32);
    l_r += rs;

    // P -> bf16 A-frags of 16x16x16 (k = 4hi+j)
    s16x4 pa[8];
#pragma unroll
    for (int t4 = 0; t4 < 8; ++t4)
#pragma unroll
      for (int j = 0; j < 4; ++j) {
        const __bf16 pb = (__bf16)st[t4][j];
        pa[t4][j] = __builtin_bit_cast(short, pb);
      }

#pragma unroll
    for (int d = 0; d < 4; ++d) {
      const char* rp0 = (const char*)cV0 + (d * 16 + lrow) * 128;
      const char* rp1 = (const char*)cV1 + (d * 16 + lrow) * 128;
#pragma unroll
      for (int t4 = 0; t4 < 4; ++t4) {
        const s16x4 vb0 = *(const s16x4*)(rp0 + ((t4 * 32 + hi * 8) ^ swz));
        o[d] = __builtin_amdgcn_mfma_f32_16x16x16bf16_1k(pa[t4], vb0, o[d], 0, 0, 0);
        const s16x4 vb1 = *(const s16x4*)(rp1 + ((t4 * 32 + hi * 8) ^ swz));
        o[d] = __builtin_amdgcn_mfma_f32_16x16x16bf16_1k(pa[4 + t4], vb1, o[d], 0, 0, 0);
      }
    }
  }

  __syncthreads();
  float linv[4];
#pragma unroll
  for (int jj = 0; jj < 4; ++jj) linv[jj] = 1.0f / __shfl(l_r, hi * 4 + jj);
#pragma unroll
  for (int d = 0; d < 4; ++d)
#pragma unroll
    for (int jj = 0; jj < 4; ++jj)
      out[((size_t)b * SEQ + q0 + hi * 4 + jj) * DMODEL + h * 64 + d * 16 + lrow] =
          (__bf16)(o[d][jj] * linv[jj]);
}

// ---------------------------------------------------------------------------
// out = LayerNorm(x + y [+ y2]) * g + beta ; y/y2 nullable.
// ---------------------------------------------------------------------------
__global__ __launch_bounds__(256) void k_add_ln(
    const float* __restrict__ x, const float* __restrict__ y,
    const float* __restrict__ y2, const float* __restrict__ g,
    const float* __restrict__ be, float* __restrict__ of,
    __bf16* __restrict__ ob) {
  const int row = blockIdx.x, tid = threadIdx.x;
  const float4 a = ((const float4*)(x + (size_t)row * 1024))[tid];
  float4 b = {0.f, 0.f, 0.f, 0.f};
  if (y) b = ((const float4*)(y + (size_t)row * 1024))[tid];
  float4 c = {0.f, 0.f, 0.f, 0.f};
  if (y2) c = ((const float4*)(y2 + (size_t)row * 1024))[tid];
  const float v0 = a.x + b.x + c.x, v1 = a.y + b.y + c.y;
  const float v2 = a.z + b.z + c.z, v3 = a.w + b.w + c.w;
  float s = v0 + v1 + v2 + v3;
  float s2 = v0 * v0 + v1 * v1 + v2 * v2 + v3 * v3;
#pragma unroll
  for (int off = 32; off > 0; off >>= 1) {
    s += __shfl_xor(s, off);
    s2 += __shfl_xor(s2, off);
  }
  __shared__ float red[2][4];
  const int wv = tid >> 6, lane = tid & 63;
  if (lane == 0) { red[0][wv] = s; red[1][wv] = s2; }
  __syncthreads();
  s = red[0][0] + red[0][1] + red[0][2] + red[0][3];
  s2 = red[1][0] + red[1][1] + red[1][2] + red[1][3];
  const float mean = s * (1.0f / 1024.0f);
  const float var = s2 * (1.0f / 1024.0f) - mean * mean;
  const float rstd = rsqrtf(var + 1e-5f);
  const float4 gg = ((const float4*)g)[tid];
  const float4 bt = ((const float4*)be)[tid];
  float4 r;
  r.x = (v0 - mean) * rstd * gg.x + bt.x;
  r.y = (v1 - mean) * rstd * gg.y + bt.y;
  r.z = (v2 - mean) * rstd * gg.z + bt.z;
  r.w = (v3 - mean) * rstd * gg.w + bt.w;
  ((float4*)(of + (size_t)row * 1024))[tid] = r;
  if (ob) {
    bf16x4 rb;
    rb[0] = (__bf16)r.x; rb[1] = (__bf16)r.y; rb[2] = (__bf16)r.z; rb[3] = (__bf16)r.w;
    *(bf16x4*)(ob + (size_t)row * 1024 + tid * 4) = rb;
  }
}

// ---------------------------------------------------------------------------
extern "C" void kernel_launch(void* const* d_in, const int* in_sizes, int n_in,
                              void* d_out, int out_size, void* d_ws, size_t ws_size,
                              hipStream_t stream) {
  const float* x = (const float*)d_in[0];
  const float* src_mask = (const float*)d_in[1];
  const float* w_q = (const float*)d_in[2];
  const float* b_q = (const float*)d_in[3];
  const float* w_k = (const float*)d_in[4];
  const float* b_k = (const float*)d_in[5];
  const float* w_v = (const float*)d_in[6];
  const float* b_v = (const float*)d_in[7];
  const float* w_o = (const float*)d_in[8];
  const float* b_o = (const float*)d_in[9];
  const float* w_ff1 = (const float*)d_in[10];
  const float* b_ff1 = (const float*)d_in[11];
  const float* w_ff2 = (const float*)d_in[12];
  const float* b_ff2 = (const float*)d_in[13];
  const float* ln1_g = (const float*)d_in[14];
  const float* ln1_b = (const float*)d_in[15];
  const float* ln2_g = (const float*)d_in[16];
  const float* ln2_b = (const float*)d_in[17];

  char* ws = (char*)d_ws;
  constexpr size_t O_WQKVT = 0;
  constexpr size_t O_WOT = O_WQKVT + 3072ull * 1024 * 2;
  constexpr size_t O_WFF1T = O_WOT + 1024ull * 1024 * 2;
  constexpr size_t O_WFF2T = O_WFF1T + 4096ull * 1024 * 2;
  constexpr size_t O_BQKV = O_WFF2T + 4096ull * 1024 * 2;
  constexpr size_t O_XBF = O_BQKV + 3072ull * 4;
  constexpr size_t O_QKV = O_XBF + 4096ull * 1024 * 2;
  constexpr size_t O_ATTN = O_QKV + 4096ull * 3072 * 2;
  constexpr size_t O_PROJ = O_ATTN + 4096ull * 1024 * 2;
  constexpr size_t O_H1F = O_PROJ + 4096ull * 1024 * 4;
  constexpr size_t O_H1B = O_H1F + 4096ull * 1024 * 4;
  constexpr size_t O_MASK2 = O_H1B + 4096ull * 1024 * 2;   // 16KB
  constexpr size_t O_VT = O_PROJ;    // vT: dead before proj written
  constexpr size_t O_FF = O_QKV;     // ffb 32MB spans QKV+ATTN
  constexpr size_t O_FF2A = O_PROJ;  // 16MB (proj dead after ln1)
  constexpr size_t O_FF2B = 0;       // 16MB over dead wqkvT+woT+wff1T

  __bf16* wqkvT = (__bf16*)(ws + O_WQKVT);
  __bf16* woT = (__bf16*)(ws + O_WOT);
  __bf16* wff1T = (__bf16*)(ws + O_WFF1T);
  __bf16* wff2T = (__bf16*)(ws + O_WFF2T);
  float* bqkv = (float*)(ws + O_BQKV);
  __bf16* xbf = (__bf16*)(ws + O_XBF);
  __bf16* qkvb = (__bf16*)(ws + O_QKV);
  __bf16* attnb = (__bf16*)(ws + O_ATTN);
  float* proj = (float*)(ws + O_PROJ);
  float* h1f = (float*)(ws + O_H1F);
  __bf16* h1b = (__bf16*)(ws + O_H1B);
  float* mask2 = (float*)(ws + O_MASK2);
  __bf16* vT = (__bf16*)(ws + O_VT);
  __bf16* ffb = (__bf16*)(ws + O_FF);
  float* ff2a = (float*)(ws + O_FF2A);
  float* ff2b = (float*)(ws + O_FF2B);

  // weight prep
  k_transpose_to_bf16<<<dim3(32, 32), 256, 0, stream>>>(w_q, wqkvT, 1024, 1024);
  k_transpose_to_bf16<<<dim3(32, 32), 256, 0, stream>>>(w_k, wqkvT + 1024 * 1024, 1024, 1024);
  k_transpose_to_bf16<<<dim3(32, 32), 256, 0, stream>>>(w_v, wqkvT + 2 * 1024 * 1024, 1024, 1024);
  k_transpose_to_bf16<<<dim3(32, 32), 256, 0, stream>>>(w_o, woT, 1024, 1024);
  k_transpose_to_bf16<<<dim3(128, 32), 256, 0, stream>>>(w_ff1, wff1T, 1024, 4096);
  k_transpose_to_bf16<<<dim3(32, 128), 256, 0, stream>>>(w_ff2, wff2T, 4096, 1024);
  k_concat3<<<12, 256, 0, stream>>>(b_q, b_k, b_v, bqkv);
  k_scale_mask<<<16, 256, 0, stream>>>(src_mask, mask2, BATCH * SEQ);
  k_cvt_bf16<<<4096, 256, 0, stream>>>(x, xbf, MTOT * DMODEL);

  // fused QKV projection (256^2 counted-vmcnt pipeline)
  k_gemm256<false, __bf16><<<dim3(12, 16), 512, 0, stream>>>(xbf, wqkvT, bqkv, qkvb,
                                                             MTOT, 3072, 1024);
  // V transpose
  k_transpose_v<<<dim3(64, 32, 2), 256, 0, stream>>>(qkvb, vT);
  // attention (QBLK=128 x KVBLK=128: 16 iters, barriers halved)
  k_attn<<<dim3(SEQ / 128, NHEAD, BATCH), 512, 0, stream>>>(qkvb, vT, mask2, attnb);
  // output projection
  k_gemm<2, false, float><<<dim3(8, 64, 1), 256, 0, stream>>>(
      attnb, woT, b_o, proj, nullptr, MTOT, 1024, 1024, 1024);
  // ln1
  k_add_ln<<<4096, 256, 0, stream>>>(x, proj, nullptr, ln1_g, ln1_b, h1f, h1b);
  // ff1 + relu (256^2 counted-vmcnt pipeline)
  k_gemm256<true, __bf16><<<dim3(16, 16), 512, 0, stream>>>(h1b, wff1T, b_ff1, ffb,
                                                            MTOT, DFF, 1024);
  // ff2 split-K x2 in ONE dispatch (4 blocks/CU co-resident)
  k_gemm<2, false, float><<<dim3(8, 64, 2), 256, 0, stream>>>(
      ffb, wff2T, b_ff2, ff2a, ff2b, MTOT, 1024, DFF, 2048);
  // ln2 -> d_out: ff2a + h1 + ff2b
  k_add_ln<<<4096, 256, 0, stream>>>(ff2a, h1f, ff2b, ln2_g, ln2_b,
                                     (float*)d_out, nullptr);
}

// Round 23
// 255.368 us; speedup vs baseline: 1.1207x; 1.0317x over previous
//
#include <hip/hip_runtime.h>
#include <cstdint>
#include <cstddef>

#define BATCH 2
#define SEQ 2048
#define DMODEL 1024
#define NHEAD 16
#define DFF 4096
#define MTOT (BATCH * SEQ) /* 4096 */

typedef __bf16 bf16x8 __attribute__((ext_vector_type(8)));
typedef __bf16 bf16x4 __attribute__((ext_vector_type(4)));
typedef short s16x4 __attribute__((ext_vector_type(4)));
typedef float f32x4 __attribute__((ext_vector_type(4)));

#define S_BARRIER() __builtin_amdgcn_s_barrier()
#define SCHED_FENCE() __builtin_amdgcn_sched_barrier(0)
#define VMCNT8() asm volatile("s_waitcnt vmcnt(8)" ::: "memory")
#define VMCNT4() asm volatile("s_waitcnt vmcnt(4)" ::: "memory")
#define VMCNT0() asm volatile("s_waitcnt vmcnt(0)" ::: "memory")

// async global->LDS, 16B/lane; LDS dest = wave-uniform base + lane*16 (m104).
__device__ __forceinline__ void gload_lds16(const void* g, void* l) {
  __builtin_amdgcn_global_load_lds(
      (__attribute__((address_space(1))) void*)(uintptr_t)g,
      (__attribute__((address_space(3))) void*)(uint32_t)(uintptr_t)l,
      16, 0, 0);
}

// ---------------------------------------------------------------------------
// fp32 [K,N] -> bf16 [N,K] transpose (weights -> B^T layout)
// ---------------------------------------------------------------------------
__global__ __launch_bounds__(256) void k_transpose_to_bf16(
    const float* __restrict__ w, __bf16* __restrict__ wt, int K, int N) {
  __shared__ float t[32][33];
  const int n0 = blockIdx.x * 32, k0 = blockIdx.y * 32;
  const int tx = threadIdx.x & 31, ty = threadIdx.x >> 5;
#pragma unroll
  for (int i = ty; i < 32; i += 8) t[i][tx] = w[(size_t)(k0 + i) * N + n0 + tx];
  __syncthreads();
#pragma unroll
  for (int i = ty; i < 32; i += 8)
    wt[(size_t)(n0 + i) * K + k0 + tx] = (__bf16)t[tx][i];
}

// fused q/k/v 1024x1024 transposes: blockIdx.z selects the source
__global__ __launch_bounds__(256) void k_transpose_qkv(
    const float* __restrict__ wq, const float* __restrict__ wk,
    const float* __restrict__ wv, __bf16* __restrict__ wt) {
  __shared__ float t[32][33];
  const float* w = (blockIdx.z == 0) ? wq : (blockIdx.z == 1) ? wk : wv;
  __bf16* dst = wt + (size_t)blockIdx.z * 1024 * 1024;
  const int n0 = blockIdx.x * 32, k0 = blockIdx.y * 32;
  const int tx = threadIdx.x & 31, ty = threadIdx.x >> 5;
#pragma unroll
  for (int i = ty; i < 32; i += 8) t[i][tx] = w[(size_t)(k0 + i) * 1024 + n0 + tx];
  __syncthreads();
#pragma unroll
  for (int i = ty; i < 32; i += 8)
    dst[(size_t)(n0 + i) * 1024 + k0 + tx] = (__bf16)t[tx][i];
}

__global__ __launch_bounds__(256) void k_cvt_bf16(
    const float* __restrict__ in, __bf16* __restrict__ out, int n) {
  const int i = (blockIdx.x * 256 + threadIdx.x) * 4;
  if (i >= n) return;
  const float4 v = *(const float4*)(in + i);
  bf16x4 r;
  r[0] = (__bf16)v.x; r[1] = (__bf16)v.y; r[2] = (__bf16)v.z; r[3] = (__bf16)v.w;
  *(bf16x4*)(out + i) = r;
}

__global__ void k_concat3(const float* __restrict__ a, const float* __restrict__ b,
                          const float* __restrict__ c, float* __restrict__ o) {
  const int i = blockIdx.x * 256 + threadIdx.x;
  if (i >= 3072) return;
  o[i] = (i < 1024) ? a[i] : (i < 2048) ? b[i - 1024] : c[i - 2048];
}

// mask * log2(e) for exp2-domain softmax
__global__ void k_scale_mask(const float* __restrict__ in, float* __restrict__ o, int n) {
  const int i = blockIdx.x * 256 + threadIdx.x;
  if (i < n) o[i] = in[i] * 1.44269504f;
}

// bf16 V-section transpose: qkvb[b*S+s][2048+c] -> vT[b*1024+c][s]
__global__ __launch_bounds__(256) void k_transpose_v(
    const __bf16* __restrict__ qkvb, __bf16* __restrict__ vT) {
  __shared__ __bf16 t[32][33];
  const int s0 = blockIdx.x * 32, c0 = blockIdx.y * 32, b = blockIdx.z;
  const int tx = threadIdx.x & 31, ty = threadIdx.x >> 5;
#pragma unroll
  for (int i = ty; i < 32; i += 8)
    t[i][tx] = qkvb[(size_t)(b * SEQ + s0 + i) * 3072 + 2048 + c0 + tx];
  __syncthreads();
#pragma unroll
  for (int i = ty; i < 32; i += 8)
    vT[((size_t)b * 1024 + c0 + i) * SEQ + s0 + tx] = t[tx][i];
}

// ---------------------------------------------------------------------------
// 256x256 deep-pipelined MFMA GEMM (T3+T4 counted-vmcnt, ALL-BUILTIN MFMAs).
// R16-verified. 512 thr = 8 waves (2M x 4N); wave owns 128x64.
// ---------------------------------------------------------------------------
template <bool RELU, typename OutT>
__global__ __launch_bounds__(512) void k_gemm256(
    const __bf16* __restrict__ A, const __bf16* __restrict__ BT,
    const float* __restrict__ bias, OutT* __restrict__ C,
    int M, int N, int K) {
  __shared__ __align__(16) __bf16 sA[4 * 8192];
  __shared__ __align__(16) __bf16 sB[4 * 8192];
  const int tid = threadIdx.x, lane = tid & 63, wv = tid >> 6;
  const int wm = wv >> 2, wn = wv & 3;
  const int lrow = lane & 15, hi = lane >> 4;
  const int nwg = gridDim.x * gridDim.y;
  const int flat = blockIdx.y * gridDim.x + blockIdx.x;
  const int cpx = nwg >> 3;
  const int swzb = (flat & 7) * cpx + (flat >> 3);
  const int m0 = (swzb / gridDim.x) * 256;
  const int n0 = (swzb % gridDim.x) * 256;
  const int NT = K >> 6;

  const int lsub = lane >> 2;
  const int gg = (lane & 3) ^ ((lane >> 3) & 3);
  const int gr = hi ^ ((lrow >> 1) & 3);

  f32x4 acc[8][4];
#pragma unroll
  for (int r = 0; r < 8; ++r)
#pragma unroll
    for (int c = 0; c < 4; ++c) acc[r][c] = f32x4{0.f, 0.f, 0.f, 0.f};

  auto stage = [&](int p) {
    const int tile = p >> 1;
    const int slot = (((tile & 1) * 2) + (p & 1)) * 8192;
    const int kcol = tile * 64 + (p & 1) * 32 + gg * 8;
#pragma unroll
    for (int i = 0; i < 2; ++i) {
      const int c = wv * 2 + i;
      gload_lds16(A + (size_t)(m0 + c * 16 + lsub) * K + kcol, &sA[slot + c * 512]);
      gload_lds16(BT + (size_t)(n0 + c * 16 + lsub) * K + kcol, &sB[slot + c * 512]);
    }
  };

  auto compute = [&](int p) {
    const int slot = ((((p >> 1) & 1) * 2) + (p & 1)) * 8192;
    bf16x8 af[8], bfv[4];
#pragma unroll
    for (int r = 0; r < 8; ++r)
      af[r] = *(const bf16x8*)&sA[slot + (wm * 128 + r * 16 + lrow) * 32 + gr * 8];
#pragma unroll
    for (int c = 0; c < 4; ++c)
      bfv[c] = *(const bf16x8*)&sB[slot + (wn * 64 + c * 16 + lrow) * 32 + gr * 8];
    __builtin_amdgcn_s_setprio(1);
#pragma unroll
    for (int r = 0; r < 8; ++r)
#pragma unroll
      for (int c = 0; c < 4; ++c)
        acc[r][c] = __builtin_amdgcn_mfma_f32_16x16x32_bf16(af[r], bfv[c],
                                                            acc[r][c], 0, 0, 0);
    __builtin_amdgcn_s_setprio(0);
  };

  stage(0); stage(1); stage(2);
  int p = 0;
  for (; p < 2 * NT - 3; ++p) {
    VMCNT8(); S_BARRIER(); SCHED_FENCE();
    stage(p + 3);
    compute(p);
  }
  VMCNT8(); S_BARRIER(); SCHED_FENCE(); compute(p); ++p;
  VMCNT4(); S_BARRIER(); SCHED_FENCE(); compute(p); ++p;
  VMCNT0(); S_BARRIER(); SCHED_FENCE(); compute(p);

#pragma unroll
  for (int r = 0; r < 8; ++r) {
    const int row = m0 + wm * 128 + r * 16 + hi * 4;
#pragma unroll
    for (int c = 0; c < 4; ++c) {
      const int col = n0 + wn * 64 + c * 16 + lrow;
      const float bb = bias[col];
#pragma unroll
      for (int j = 0; j < 4; ++j) {
        float v = acc[r][c][j] + bb;
        if (RELU) v = fmaxf(v, 0.f);
        C[(size_t)(row + j) * N + col] = (OutT)v;
      }
    }
  }
}

// ---------------------------------------------------------------------------
// bf16 MFMA GEMM (R9-verified body + XCD swizzle) with single-dispatch
// split-K: blockIdx.z selects K-range [z*KS,(z+1)*KS), output buffer
// (z==0 -> C0 with bias, z==1 -> C1 with zero bias). BM=MF*32, BN=128, BK=64.
// ---------------------------------------------------------------------------
template <int MF, bool RELU, typename OutT>
__global__ __launch_bounds__(256) void k_gemm(
    const __bf16* __restrict__ A, const __bf16* __restrict__ BT,
    const float* __restrict__ bias, OutT* __restrict__ C0,
    OutT* __restrict__ C1, int M, int N, int lda, int KS) {
  __shared__ __bf16 sA[MF * 32 * 64];
  __shared__ __bf16 sB[128 * 64];
  const int tid = threadIdx.x, lane = tid & 63, wv = tid >> 6;
  const int wm = wv >> 1, wn = wv & 1;
  const int lrow = lane & 15, hi = lane >> 4;
  const int nwg = gridDim.x * gridDim.y;
  const int flat = blockIdx.y * gridDim.x + blockIdx.x;
  const int cpx = nwg >> 3;
  const int swzb = (flat & 7) * cpx + (flat >> 3);
  const int m0 = (swzb / gridDim.x) * (MF * 32);
  const int n0 = (swzb % gridDim.x) * 128;
  const int koff = blockIdx.z * KS;
  OutT* Cz = blockIdx.z ? C1 : C0;
  const int srow = lane >> 3;
  const int scolE = ((lane & 7) ^ srow) * 8;
  const int swz = (lrow & 7) << 4;

  f32x4 acc[MF][4];
#pragma unroll
  for (int r = 0; r < MF; ++r)
#pragma unroll
    for (int c = 0; c < 4; ++c) acc[r][c] = f32x4{0.f, 0.f, 0.f, 0.f};

  for (int k0 = 0; k0 < KS; k0 += 64) {
    __syncthreads();
#pragma unroll
    for (int rb = wv; rb < MF * 4; rb += 4) {
      const int row = rb * 8 + srow;
      gload_lds16(A + (size_t)(m0 + row) * lda + koff + k0 + scolE, &sA[rb * 512]);
    }
#pragma unroll
    for (int rb = wv; rb < 16; rb += 4) {
      const int row = rb * 8 + srow;
      gload_lds16(BT + (size_t)(n0 + row) * lda + koff + k0 + scolE, &sB[rb * 512]);
    }
    __syncthreads();
#pragma unroll
    for (int kc = 0; kc < 2; ++kc) {
      bf16x8 af[MF], bfr[4];
#pragma unroll
      for (int r = 0; r < MF; ++r) {
        const int row = wm * (MF * 16) + r * 16 + lrow;
        af[r] = *(const bf16x8*)((const char*)sA + row * 128 + ((kc * 64 + hi * 16) ^ swz));
      }
#pragma unroll
      for (int c = 0; c < 4; ++c) {
        const int row = wn * 64 + c * 16 + lrow;
        bfr[c] = *(const bf16x8*)((const char*)sB + row * 128 + ((kc * 64 + hi * 16) ^ swz));
      }
#pragma unroll
      for (int r = 0; r < MF; ++r)
#pragma unroll
        for (int c = 0; c < 4; ++c)
          acc[r][c] = __builtin_amdgcn_mfma_f32_16x16x32_bf16(af[r], bfr[c],
                                                              acc[r][c], 0, 0, 0);
    }
  }

#pragma unroll
  for (int r = 0; r < MF; ++r) {
    const int row = m0 + wm * (MF * 16) + r * 16 + hi * 4;
#pragma unroll
    for (int c = 0; c < 4; ++c) {
      const int col = n0 + wn * 64 + c * 16 + lrow;
      const float bb = (blockIdx.z == 0) ? bias[col] : 0.f;
#pragma unroll
      for (int j = 0; j < 4; ++j) {
        float v = acc[r][c][j] + bb;
        if (RELU) v = fmaxf(v, 0.f);
        Cz[(size_t)(row + j) * N + col] = (OutT)v;
      }
    }
  }
}

// ---------------------------------------------------------------------------
// Flash attention — R22-verified body (QBLK=128 x KVBLK=128, 8 waves, dbuf
// issue-early staging) + T1 XCD swizzle on the grid: the 16 qb-tiles sharing
// one (h,b)'s K/V (512KB) are clustered onto one XCD so K/V stays in that
// XCD's 4MB L2 (fixes the measured 4x FETCH over-read; stage-drain latency
// drops from HBM-class to L2-class). Pure bijective index remap (512 blocks,
// %8==0); compute/staging/sync byte-identical to R22.
// ---------------------------------------------------------------------------
__global__ __launch_bounds__(512) void k_attn(
    const __bf16* __restrict__ qkv, const __bf16* __restrict__ vT,
    const float* __restrict__ mask2, __bf16* __restrict__ out) {
  // XCD swizzle: flat over (x,y,z), 512 blocks -> 8 chunks of 64 (4 (h,b)
  // groups each); chunk c stays on XCD c.
  const int nwg = gridDim.x * gridDim.y * gridDim.z;          // 512
  const int flat = (blockIdx.z * gridDim.y + blockIdx.y) * gridDim.x + blockIdx.x;
  const int cpx = nwg >> 3;                                   // 64
  const int swzb = (flat & 7) * cpx + (flat >> 3);
  const int qb = swzb & (gridDim.x - 1);                      // gridDim.x = 16
  const int h = (swzb >> 4) & 15;
  const int b = swzb >> 8;
  const int tid = threadIdx.x, lane = tid & 63, wv = tid >> 6;
  const int lrow = lane & 15, hi = lane >> 4;

  __shared__ __bf16 sK[2][128 * 64];  // [buf][key][d], swizzled
  __shared__ __bf16 sV0[2][64 * 64];  // [buf][d][key 0..64)
  __shared__ __bf16 sV1[2][64 * 64];  // [buf][d][key 64..128)

  const size_t base = (size_t)b * SEQ * 3072;
  const __bf16* Qb = qkv + base + h * 64;
  const __bf16* Kb = qkv + base + 1024 + h * 64;
  const __bf16* vTb = vT + ((size_t)b * 1024 + h * 64) * SEQ;
  const float* maskb = mask2 + (size_t)b * SEQ;

  const int q0 = qb * 128 + wv * 16;
  const bf16x8 qf0 = *(const bf16x8*)&Qb[(size_t)(q0 + lrow) * 3072 + hi * 8];
  const bf16x8 qf1 = *(const bf16x8*)&Qb[(size_t)(q0 + lrow) * 3072 + 32 + hi * 8];

  float m_r = -3e38f, l_r = 0.f;
  f32x4 o[4];
#pragma unroll
  for (int d = 0; d < 4; ++d) o[d] = f32x4{0.f, 0.f, 0.f, 0.f};

  const int srow = lane >> 3;
  const int scolE = ((lane & 7) ^ srow) * 8;
  const int swz = (lrow & 7) << 4;

  auto stage = [&](int t) {
    const int k0s = t * 128;
    __bf16* dK = sK[t & 1];
    __bf16* dV0 = sV0[t & 1];
    __bf16* dV1 = sV1[t & 1];
#pragma unroll
    for (int r = 0; r < 2; ++r) {  // K: 16 chunks over 8 waves
      const int rb = wv + r * 8;
      const int row = rb * 8 + srow;
      gload_lds16(Kb + (size_t)(k0s + row) * 3072 + scolE, &dK[rb * 512]);
    }
    const int vrow = wv * 8 + srow;  // V: chunk wv of each half
    gload_lds16(vTb + (size_t)vrow * SEQ + k0s + scolE, &dV0[wv * 512]);
    gload_lds16(vTb + (size_t)vrow * SEQ + k0s + 64 + scolE, &dV1[wv * 512]);
  };

  stage(0);
  const int NT = SEQ / 128;
  for (int t = 0; t < NT; ++t) {
    __syncthreads();
    if (t + 1 < NT) stage(t + 1);
    const __bf16* cK = sK[t & 1];
    const __bf16* cV0 = sV0[t & 1];
    const __bf16* cV1 = sV1[t & 1];
    const int k0 = t * 128;

    // S^T = K * Q^T : st[t4][j] = S[key = t4*16 + 4hi + j][q = lrow]
    f32x4 st[8];
#pragma unroll
    for (int t4 = 0; t4 < 8; ++t4) {
      const char* rp = (const char*)cK + (t4 * 16 + lrow) * 128;
      const bf16x8 ka = *(const bf16x8*)(rp + ((hi * 16) ^ swz));
      const bf16x8 kb = *(const bf16x8*)(rp + ((64 + hi * 16) ^ swz));
      f32x4 a = f32x4{0.f, 0.f, 0.f, 0.f};
      a = __builtin_amdgcn_mfma_f32_16x16x32_bf16(ka, qf0, a, 0, 0, 0);
      a = __builtin_amdgcn_mfma_f32_16x16x32_bf16(kb, qf1, a, 0, 0, 0);
      st[t4] = a;
    }

    // exp2-domain logits: st*0.125*log2e + mask2
    float pm = -3e38f;
#pragma unroll
    for (int t4 = 0; t4 < 8; ++t4) {
      const f32x4 mk = *(const f32x4*)&maskb[k0 + t4 * 16 + hi * 4];
#pragma unroll
      for (int j = 0; j < 4; ++j) {
        st[t4][j] = st[t4][j] * 0.18033688f + mk[j];
        pm = fmaxf(pm, st[t4][j]);
      }
    }
    pm = fmaxf(pm, __shfl_xor(pm, 16));
    pm = fmaxf(pm, __shfl_xor(pm, 32));

    // T13 defer-max
    if (__any(pm > m_r + 11.5f)) {
      const float mn = fmaxf(m_r, pm);
      const float so = __builtin_amdgcn_exp2f(m_r - mn);
      m_r = mn;
      l_r *= so;
      float so_o[4];
#pragma unroll
      for (int jj = 0; jj < 4; ++jj) so_o[jj] = __shfl(so, hi * 4 + jj);
#pragma unroll
      for (int d = 0; d < 4; ++d)
#pragma unroll
        for (int jj = 0; jj < 4; ++jj) o[d][jj] *= so_o[jj];
    }

    float rs = 0.f;
#pragma unroll
    for (int t4 = 0; t4 < 8; ++t4)
#pragma unroll
      for (int j = 0; j < 4; ++j) {
        st[t4][j] = __builtin_amdgcn_exp2f(st[t4][j] - m_r);
        rs += st[t4][j];
      }
    rs += __shfl_xor(rs, 16);
    rs += __shfl_xor(rs, 32);
    l_r += rs;

    // P -> bf16 A-frags of 16x16x16 (k = 4hi+j)
    s16x4 pa[8];
#pragma unroll
    for (int t4 = 0; t4 < 8; ++t4)
#pragma unroll
      for (int j = 0; j < 4; ++j) {
        const __bf16 pb = (__bf16)st[t4][j];
        pa[t4][j] = __builtin_bit_cast(short, pb);
      }

#pragma unroll
    for (int d = 0; d < 4; ++d) {
      const char* rp0 = (const char*)cV0 + (d * 16 + lrow) * 128;
      const char* rp1 = (const char*)cV1 + (d * 16 + lrow) * 128;
#pragma unroll
      for (int t4 = 0; t4 < 4; ++t4) {
        const s16x4 vb0 = *(const s16x4*)(rp0 + ((t4 * 32 + hi * 8) ^ swz));
        o[d] = __builtin_amdgcn_mfma_f32_16x16x16bf16_1k(pa[t4], vb0, o[d], 0, 0, 0);
        const s16x4 vb1 = *(const s16x4*)(rp1 + ((t4 * 32 + hi * 8) ^ swz));
        o[d] = __builtin_amdgcn_mfma_f32_16x16x16bf16_1k(pa[4 + t4], vb1, o[d], 0, 0, 0);
      }
    }
  }

  __syncthreads();
  float linv[4];
#pragma unroll
  for (int jj = 0; jj < 4; ++jj) linv[jj] = 1.0f / __shfl(l_r, hi * 4 + jj);
#pragma unroll
  for (int d = 0; d < 4; ++d)
#pragma unroll
    for (int jj = 0; jj < 4; ++jj)
      out[((size_t)b * SEQ + q0 + hi * 4 + jj) * DMODEL + h * 64 + d * 16 + lrow] =
          (__bf16)(o[d][jj] * linv[jj]);
}

// ---------------------------------------------------------------------------
// out = LayerNorm(x + y [+ y2]) * g + beta ; y/y2 nullable.
// ---------------------------------------------------------------------------
__global__ __launch_bounds__(256) void k_add_ln(
    const float* __restrict__ x, const float* __restrict__ y,
    const float* __restrict__ y2, const float* __restrict__ g,
    const float* __restrict__ be, float* __restrict__ of,
    __bf16* __restrict__ ob) {
  const int row = blockIdx.x, tid = threadIdx.x;
  const float4 a = ((const float4*)(x + (size_t)row * 1024))[tid];
  float4 b = {0.f, 0.f, 0.f, 0.f};
  if (y) b = ((const float4*)(y + (size_t)row * 1024))[tid];
  float4 c = {0.f, 0.f, 0.f, 0.f};
  if (y2) c = ((const float4*)(y2 + (size_t)row * 1024))[tid];
  const float v0 = a.x + b.x + c.x, v1 = a.y + b.y + c.y;
  const float v2 = a.z + b.z + c.z, v3 = a.w + b.w + c.w;
  float s = v0 + v1 + v2 + v3;
  float s2 = v0 * v0 + v1 * v1 + v2 * v2 + v3 * v3;
#pragma unroll
  for (int off = 32; off > 0; off >>= 1) {
    s += __shfl_xor(s, off);
    s2 += __shfl_xor(s2, off);
  }
  __shared__ float red[2][4];
  const int wv = tid >> 6, lane = tid & 63;
  if (lane == 0) { red[0][wv] = s; red[1][wv] = s2; }
  __syncthreads();
  s = red[0][0] + red[0][1] + red[0][2] + red[0][3];
  s2 = red[1][0] + red[1][1] + red[1][2] + red[1][3];
  const float mean = s * (1.0f / 1024.0f);
  const float var = s2 * (1.0f / 1024.0f) - mean * mean;
  const float rstd = rsqrtf(var + 1e-5f);
  const float4 gg = ((const float4*)g)[tid];
  const float4 bt = ((const float4*)be)[tid];
  float4 r;
  r.x = (v0 - mean) * rstd * gg.x + bt.x;
  r.y = (v1 - mean) * rstd * gg.y + bt.y;
  r.z = (v2 - mean) * rstd * gg.z + bt.z;
  r.w = (v3 - mean) * rstd * gg.w + bt.w;
  ((float4*)(of + (size_t)row * 1024))[tid] = r;
  if (ob) {
    bf16x4 rb;
    rb[0] = (__bf16)r.x; rb[1] = (__bf16)r.y; rb[2] = (__bf16)r.z; rb[3] = (__bf16)r.w;
    *(bf16x4*)(ob + (size_t)row * 1024 + tid * 4) = rb;
  }
}

// ---------------------------------------------------------------------------
extern "C" void kernel_launch(void* const* d_in, const int* in_sizes, int n_in,
                              void* d_out, int out_size, void* d_ws, size_t ws_size,
                              hipStream_t stream) {
  const float* x = (const float*)d_in[0];
  const float* src_mask = (const float*)d_in[1];
  const float* w_q = (const float*)d_in[2];
  const float* b_q = (const float*)d_in[3];
  const float* w_k = (const float*)d_in[4];
  const float* b_k = (const float*)d_in[5];
  const float* w_v = (const float*)d_in[6];
  const float* b_v = (const float*)d_in[7];
  const float* w_o = (const float*)d_in[8];
  const float* b_o = (const float*)d_in[9];
  const float* w_ff1 = (const float*)d_in[10];
  const float* b_ff1 = (const float*)d_in[11];
  const float* w_ff2 = (const float*)d_in[12];
  const float* b_ff2 = (const float*)d_in[13];
  const float* ln1_g = (const float*)d_in[14];
  const float* ln1_b = (const float*)d_in[15];
  const float* ln2_g = (const float*)d_in[16];
  const float* ln2_b = (const float*)d_in[17];

  char* ws = (char*)d_ws;
  constexpr size_t O_WQKVT = 0;
  constexpr size_t O_WOT = O_WQKVT + 3072ull * 1024 * 2;
  constexpr size_t O_WFF1T = O_WOT + 1024ull * 1024 * 2;
  constexpr size_t O_WFF2T = O_WFF1T + 4096ull * 1024 * 2;
  constexpr size_t O_BQKV = O_WFF2T + 4096ull * 1024 * 2;
  constexpr size_t O_XBF = O_BQKV + 3072ull * 4;
  constexpr size_t O_QKV = O_XBF + 4096ull * 1024 * 2;
  constexpr size_t O_ATTN = O_QKV + 4096ull * 3072 * 2;
  constexpr size_t O_PROJ = O_ATTN + 4096ull * 1024 * 2;
  constexpr size_t O_H1F = O_PROJ + 4096ull * 1024 * 4;
  constexpr size_t O_H1B = O_H1F + 4096ull * 1024 * 4;
  constexpr size_t O_MASK2 = O_H1B + 4096ull * 1024 * 2;   // 16KB
  constexpr size_t O_VT = O_PROJ;    // vT: dead before proj written
  constexpr size_t O_FF = O_QKV;     // ffb 32MB spans QKV+ATTN
  constexpr size_t O_FF2A = O_PROJ;  // 16MB (proj dead after ln1)
  constexpr size_t O_FF2B = 0;       // 16MB over dead wqkvT+woT+wff1T

  __bf16* wqkvT = (__bf16*)(ws + O_WQKVT);
  __bf16* woT = (__bf16*)(ws + O_WOT);
  __bf16* wff1T = (__bf16*)(ws + O_WFF1T);
  __bf16* wff2T = (__bf16*)(ws + O_WFF2T);
  float* bqkv = (float*)(ws + O_BQKV);
  __bf16* xbf = (__bf16*)(ws + O_XBF);
  __bf16* qkvb = (__bf16*)(ws + O_QKV);
  __bf16* attnb = (__bf16*)(ws + O_ATTN);
  float* proj = (float*)(ws + O_PROJ);
  float* h1f = (float*)(ws + O_H1F);
  __bf16* h1b = (__bf16*)(ws + O_H1B);
  float* mask2 = (float*)(ws + O_MASK2);
  __bf16* vT = (__bf16*)(ws + O_VT);
  __bf16* ffb = (__bf16*)(ws + O_FF);
  float* ff2a = (float*)(ws + O_FF2A);
  float* ff2b = (float*)(ws + O_FF2B);

  // weight prep (q/k/v transposes fused into one dispatch)
  k_transpose_qkv<<<dim3(32, 32, 3), 256, 0, stream>>>(w_q, w_k, w_v, wqkvT);
  k_transpose_to_bf16<<<dim3(32, 32), 256, 0, stream>>>(w_o, woT, 1024, 1024);
  k_transpose_to_bf16<<<dim3(128, 32), 256, 0, stream>>>(w_ff1, wff1T, 1024, 4096);
  k_transpose_to_bf16<<<dim3(32, 128), 256, 0, stream>>>(w_ff2, wff2T, 4096, 1024);
  k_concat3<<<12, 256, 0, stream>>>(b_q, b_k, b_v, bqkv);
  k_scale_mask<<<16, 256, 0, stream>>>(src_mask, mask2, BATCH * SEQ);
  k_cvt_bf16<<<4096, 256, 0, stream>>>(x, xbf, MTOT * DMODEL);

  // fused QKV projection (256^2 counted-vmcnt pipeline)
  k_gemm256<false, __bf16><<<dim3(12, 16), 512, 0, stream>>>(xbf, wqkvT, bqkv, qkvb,
                                                             MTOT, 3072, 1024);
  // V transpose
  k_transpose_v<<<dim3(64, 32, 2), 256, 0, stream>>>(qkvb, vT);
  // attention (QBLK=128 x KVBLK=128 + XCD-clustered K/V reuse)
  k_attn<<<dim3(SEQ / 128, NHEAD, BATCH), 512, 0, stream>>>(qkvb, vT, mask2, attnb);
  // output projection
  k_gemm<2, false, float><<<dim3(8, 64, 1), 256, 0, stream>>>(
      attnb, woT, b_o, proj, nullptr, MTOT, 1024, 1024, 1024);
  // ln1
  k_add_ln<<<4096, 256, 0, stream>>>(x, proj, nullptr, ln1_g, ln1_b, h1f, h1b);
  // ff1 + relu (256^2 counted-vmcnt pipeline)
  k_gemm256<true, __bf16><<<dim3(16, 16), 512, 0, stream>>>(h1b, wff1T, b_ff1, ffb,
                                                            MTOT, DFF, 1024);
  // ff2 split-K x2 in ONE dispatch (4 blocks/CU co-resident)
  k_gemm<2, false, float><<<dim3(8, 64, 2), 256, 0, stream>>>(
      ffb, wff2T, b_ff2, ff2a, ff2b, MTOT, 1024, DFF, 2048);
  // ln2 -> d_out: ff2a + h1 + ff2b
  k_add_ln<<<4096, 256, 0, stream>>>(ff2a, h1f, ff2b, ln2_g, ln2_b,
                                     (float*)d_out, nullptr);
}

// Round 24
// 243.301 us; speedup vs baseline: 1.1763x; 1.0496x over previous
//
#include <hip/hip_runtime.h>
#include <cstdint>
#include <cstddef>

#define BATCH 2
#define SEQ 2048
#define DMODEL 1024
#define NHEAD 16
#define DFF 4096
#define MTOT (BATCH * SEQ) /* 4096 */

typedef __bf16 bf16x8 __attribute__((ext_vector_type(8)));
typedef __bf16 bf16x4 __attribute__((ext_vector_type(4)));
typedef short s16x4 __attribute__((ext_vector_type(4)));
typedef float f32x4 __attribute__((ext_vector_type(4)));

#define S_BARRIER() __builtin_amdgcn_s_barrier()
#define SCHED_FENCE() __builtin_amdgcn_sched_barrier(0)
#define VMCNT8() asm volatile("s_waitcnt vmcnt(8)" ::: "memory")
#define VMCNT4() asm volatile("s_waitcnt vmcnt(4)" ::: "memory")
#define VMCNT0() asm volatile("s_waitcnt vmcnt(0)" ::: "memory")

// async global->LDS, 16B/lane; LDS dest = wave-uniform base + lane*16 (m104).
__device__ __forceinline__ void gload_lds16(const void* g, void* l) {
  __builtin_amdgcn_global_load_lds(
      (__attribute__((address_space(1))) void*)(uintptr_t)g,
      (__attribute__((address_space(3))) void*)(uint32_t)(uintptr_t)l,
      16, 0, 0);
}

// ---------------------------------------------------------------------------
// Fused prep: ALL weight transposes + bias concat + mask scale + x->bf16 in
// ONE dispatch (was 7 serial dispatches). Block role by flat blockIdx range;
// each block's logic is byte-identical to its verified standalone kernel.
//   [0,12)      concat3 (3072 elems)
//   [12,28)     mask * log2e (4096 elems)
//   [28,4124)   x fp32->bf16 (4M elems, 4/thread)
//   [4124,7196) wq/wk/wv transpose (3 x 1024 tiles)
//   [7196,8220) wo transpose (1024 tiles)
//   [8220,12316) ff1 transpose (4096 tiles, N=4096)
//   [12316,16412) ff2 transpose (4096 tiles, K=4096)
// ---------------------------------------------------------------------------
__global__ __launch_bounds__(256) void k_prep(
    const float* __restrict__ wq, const float* __restrict__ wk,
    const float* __restrict__ wv, const float* __restrict__ wo,
    const float* __restrict__ wff1, const float* __restrict__ wff2,
    __bf16* __restrict__ wqkvT, __bf16* __restrict__ woT,
    __bf16* __restrict__ wff1T, __bf16* __restrict__ wff2T,
    const float* __restrict__ bq, const float* __restrict__ bk,
    const float* __restrict__ bv, float* __restrict__ bqkv,
    const float* __restrict__ mask, float* __restrict__ mask2,
    const float* __restrict__ x, __bf16* __restrict__ xbf) {
  int f = blockIdx.x;
  if (f < 12) {  // concat3
    const int i = f * 256 + threadIdx.x;
    if (i < 3072)
      bqkv[i] = (i < 1024) ? bq[i] : (i < 2048) ? bk[i - 1024] : bv[i - 2048];
    return;
  }
  f -= 12;
  if (f < 16) {  // scale_mask
    const int i = f * 256 + threadIdx.x;
    if (i < BATCH * SEQ) mask2[i] = mask[i] * 1.44269504f;
    return;
  }
  f -= 16;
  if (f < 4096) {  // cvt_bf16
    const int i = (f * 256 + threadIdx.x) * 4;
    const float4 v = *(const float4*)(x + i);
    bf16x4 r;
    r[0] = (__bf16)v.x; r[1] = (__bf16)v.y; r[2] = (__bf16)v.z; r[3] = (__bf16)v.w;
    *(bf16x4*)(xbf + i) = r;
    return;
  }
  f -= 4096;
  // transposes: src[K,N] -> dst[N,K] bf16, 32x32 tiles
  const float* src;
  __bf16* dst;
  int Kd, Nd, n0, k0;
  if (f < 3072) {  // q/k/v
    const int zz = f / 1024, r = f % 1024;
    src = (zz == 0) ? wq : (zz == 1) ? wk : wv;
    dst = wqkvT + (size_t)zz * 1024 * 1024;
    Kd = 1024; Nd = 1024; n0 = (r & 31) * 32; k0 = (r >> 5) * 32;
  } else if (f < 4096) {  // wo
    const int r = f - 3072;
    src = wo; dst = woT;
    Kd = 1024; Nd = 1024; n0 = (r & 31) * 32; k0 = (r >> 5) * 32;
  } else if (f < 8192) {  // ff1: K=1024, N=4096, grid(128,32)
    const int r = f - 4096;
    src = wff1; dst = wff1T;
    Kd = 1024; Nd = 4096; n0 = (r & 127) * 32; k0 = (r >> 7) * 32;
  } else {  // ff2: K=4096, N=1024, grid(32,128)
    const int r = f - 8192;
    src = wff2; dst = wff2T;
    Kd = 4096; Nd = 1024; n0 = (r & 31) * 32; k0 = (r >> 5) * 32;
  }
  __shared__ float t[32][33];
  const int tx = threadIdx.x & 31, ty = threadIdx.x >> 5;
#pragma unroll
  for (int i = ty; i < 32; i += 8) t[i][tx] = src[(size_t)(k0 + i) * Nd + n0 + tx];
  __syncthreads();
#pragma unroll
  for (int i = ty; i < 32; i += 8)
    dst[(size_t)(n0 + i) * Kd + k0 + tx] = (__bf16)t[tx][i];
}

// bf16 V-section transpose: qkvb[b*S+s][2048+c] -> vT[b*1024+c][s]
__global__ __launch_bounds__(256) void k_transpose_v(
    const __bf16* __restrict__ qkvb, __bf16* __restrict__ vT) {
  __shared__ __bf16 t[32][33];
  const int s0 = blockIdx.x * 32, c0 = blockIdx.y * 32, b = blockIdx.z;
  const int tx = threadIdx.x & 31, ty = threadIdx.x >> 5;
#pragma unroll
  for (int i = ty; i < 32; i += 8)
    t[i][tx] = qkvb[(size_t)(b * SEQ + s0 + i) * 3072 + 2048 + c0 + tx];
  __syncthreads();
#pragma unroll
  for (int i = ty; i < 32; i += 8)
    vT[((size_t)b * 1024 + c0 + i) * SEQ + s0 + tx] = t[tx][i];
}

// ---------------------------------------------------------------------------
// 256x256 deep-pipelined MFMA GEMM (T3+T4 counted-vmcnt, ALL-BUILTIN MFMAs).
// R16-verified. 512 thr = 8 waves (2M x 4N); wave owns 128x64.
// ---------------------------------------------------------------------------
template <bool RELU, typename OutT>
__global__ __launch_bounds__(512) void k_gemm256(
    const __bf16* __restrict__ A, const __bf16* __restrict__ BT,
    const float* __restrict__ bias, OutT* __restrict__ C,
    int M, int N, int K) {
  __shared__ __align__(16) __bf16 sA[4 * 8192];
  __shared__ __align__(16) __bf16 sB[4 * 8192];
  const int tid = threadIdx.x, lane = tid & 63, wv = tid >> 6;
  const int wm = wv >> 2, wn = wv & 3;
  const int lrow = lane & 15, hi = lane >> 4;
  const int nwg = gridDim.x * gridDim.y;
  const int flat = blockIdx.y * gridDim.x + blockIdx.x;
  const int cpx = nwg >> 3;
  const int swzb = (flat & 7) * cpx + (flat >> 3);
  const int m0 = (swzb / gridDim.x) * 256;
  const int n0 = (swzb % gridDim.x) * 256;
  const int NT = K >> 6;

  const int lsub = lane >> 2;
  const int gg = (lane & 3) ^ ((lane >> 3) & 3);
  const int gr = hi ^ ((lrow >> 1) & 3);

  f32x4 acc[8][4];
#pragma unroll
  for (int r = 0; r < 8; ++r)
#pragma unroll
    for (int c = 0; c < 4; ++c) acc[r][c] = f32x4{0.f, 0.f, 0.f, 0.f};

  auto stage = [&](int p) {
    const int tile = p >> 1;
    const int slot = (((tile & 1) * 2) + (p & 1)) * 8192;
    const int kcol = tile * 64 + (p & 1) * 32 + gg * 8;
#pragma unroll
    for (int i = 0; i < 2; ++i) {
      const int c = wv * 2 + i;
      gload_lds16(A + (size_t)(m0 + c * 16 + lsub) * K + kcol, &sA[slot + c * 512]);
      gload_lds16(BT + (size_t)(n0 + c * 16 + lsub) * K + kcol, &sB[slot + c * 512]);
    }
  };

  auto compute = [&](int p) {
    const int slot = ((((p >> 1) & 1) * 2) + (p & 1)) * 8192;
    bf16x8 af[8], bfv[4];
#pragma unroll
    for (int r = 0; r < 8; ++r)
      af[r] = *(const bf16x8*)&sA[slot + (wm * 128 + r * 16 + lrow) * 32 + gr * 8];
#pragma unroll
    for (int c = 0; c < 4; ++c)
      bfv[c] = *(const bf16x8*)&sB[slot + (wn * 64 + c * 16 + lrow) * 32 + gr * 8];
    __builtin_amdgcn_s_setprio(1);
#pragma unroll
    for (int r = 0; r < 8; ++r)
#pragma unroll
      for (int c = 0; c < 4; ++c)
        acc[r][c] = __builtin_amdgcn_mfma_f32_16x16x32_bf16(af[r], bfv[c],
                                                            acc[r][c], 0, 0, 0);
    __builtin_amdgcn_s_setprio(0);
  };

  stage(0); stage(1); stage(2);
  int p = 0;
  for (; p < 2 * NT - 3; ++p) {
    VMCNT8(); S_BARRIER(); SCHED_FENCE();
    stage(p + 3);
    compute(p);
  }
  VMCNT8(); S_BARRIER(); SCHED_FENCE(); compute(p); ++p;
  VMCNT4(); S_BARRIER(); SCHED_FENCE(); compute(p); ++p;
  VMCNT0(); S_BARRIER(); SCHED_FENCE(); compute(p);

#pragma unroll
  for (int r = 0; r < 8; ++r) {
    const int row = m0 + wm * 128 + r * 16 + hi * 4;
#pragma unroll
    for (int c = 0; c < 4; ++c) {
      const int col = n0 + wn * 64 + c * 16 + lrow;
      const float bb = bias[col];
#pragma unroll
      for (int j = 0; j < 4; ++j) {
        float v = acc[r][c][j] + bb;
        if (RELU) v = fmaxf(v, 0.f);
        C[(size_t)(row + j) * N + col] = (OutT)v;
      }
    }
  }
}

// ---------------------------------------------------------------------------
// bf16 MFMA GEMM (R9-verified body + XCD swizzle) with single-dispatch
// split-K: blockIdx.z selects K-range [z*KS,(z+1)*KS), output buffer
// (z==0 -> C0 with bias, z==1 -> C1 with zero bias). BM=MF*32, BN=128, BK=64.
// ---------------------------------------------------------------------------
template <int MF, bool RELU, typename OutT>
__global__ __launch_bounds__(256) void k_gemm(
    const __bf16* __restrict__ A, const __bf16* __restrict__ BT,
    const float* __restrict__ bias, OutT* __restrict__ C0,
    OutT* __restrict__ C1, int M, int N, int lda, int KS) {
  __shared__ __bf16 sA[MF * 32 * 64];
  __shared__ __bf16 sB[128 * 64];
  const int tid = threadIdx.x, lane = tid & 63, wv = tid >> 6;
  const int wm = wv >> 1, wn = wv & 1;
  const int lrow = lane & 15, hi = lane >> 4;
  const int nwg = gridDim.x * gridDim.y;
  const int flat = blockIdx.y * gridDim.x + blockIdx.x;
  const int cpx = nwg >> 3;
  const int swzb = (flat & 7) * cpx + (flat >> 3);
  const int m0 = (swzb / gridDim.x) * (MF * 32);
  const int n0 = (swzb % gridDim.x) * 128;
  const int koff = blockIdx.z * KS;
  OutT* Cz = blockIdx.z ? C1 : C0;
  const int srow = lane >> 3;
  const int scolE = ((lane & 7) ^ srow) * 8;
  const int swz = (lrow & 7) << 4;

  f32x4 acc[MF][4];
#pragma unroll
  for (int r = 0; r < MF; ++r)
#pragma unroll
    for (int c = 0; c < 4; ++c) acc[r][c] = f32x4{0.f, 0.f, 0.f, 0.f};

  for (int k0 = 0; k0 < KS; k0 += 64) {
    __syncthreads();
#pragma unroll
    for (int rb = wv; rb < MF * 4; rb += 4) {
      const int row = rb * 8 + srow;
      gload_lds16(A + (size_t)(m0 + row) * lda + koff + k0 + scolE, &sA[rb * 512]);
    }
#pragma unroll
    for (int rb = wv; rb < 16; rb += 4) {
      const int row = rb * 8 + srow;
      gload_lds16(BT + (size_t)(n0 + row) * lda + koff + k0 + scolE, &sB[rb * 512]);
    }
    __syncthreads();
#pragma unroll
    for (int kc = 0; kc < 2; ++kc) {
      bf16x8 af[MF], bfr[4];
#pragma unroll
      for (int r = 0; r < MF; ++r) {
        const int row = wm * (MF * 16) + r * 16 + lrow;
        af[r] = *(const bf16x8*)((const char*)sA + row * 128 + ((kc * 64 + hi * 16) ^ swz));
      }
#pragma unroll
      for (int c = 0; c < 4; ++c) {
        const int row = wn * 64 + c * 16 + lrow;
        bfr[c] = *(const bf16x8*)((const char*)sB + row * 128 + ((kc * 64 + hi * 16) ^ swz));
      }
#pragma unroll
      for (int r = 0; r < MF; ++r)
#pragma unroll
        for (int c = 0; c < 4; ++c)
          acc[r][c] = __builtin_amdgcn_mfma_f32_16x16x32_bf16(af[r], bfr[c],
                                                              acc[r][c], 0, 0, 0);
    }
  }

#pragma unroll
  for (int r = 0; r < MF; ++r) {
    const int row = m0 + wm * (MF * 16) + r * 16 + hi * 4;
#pragma unroll
    for (int c = 0; c < 4; ++c) {
      const int col = n0 + wn * 64 + c * 16 + lrow;
      const float bb = (blockIdx.z == 0) ? bias[col] : 0.f;
#pragma unroll
      for (int j = 0; j < 4; ++j) {
        float v = acc[r][c][j] + bb;
        if (RELU) v = fmaxf(v, 0.f);
        Cz[(size_t)(row + j) * N + col] = (OutT)v;
      }
    }
  }
}

// ---------------------------------------------------------------------------
// Flash attention — R23-verified exactly (QBLK=128 x KVBLK=128, 8 waves,
// dbuf issue-early staging, exp2+defer-max softmax, XCD-clustered grid).
// ---------------------------------------------------------------------------
__global__ __launch_bounds__(512) void k_attn(
    const __bf16* __restrict__ qkv, const __bf16* __restrict__ vT,
    const float* __restrict__ mask2, __bf16* __restrict__ out) {
  const int nwg = gridDim.x * gridDim.y * gridDim.z;          // 512
  const int flat = (blockIdx.z * gridDim.y + blockIdx.y) * gridDim.x + blockIdx.x;
  const int cpx = nwg >> 3;                                   // 64
  const int swzb = (flat & 7) * cpx + (flat >> 3);
  const int qb = swzb & (gridDim.x - 1);                      // gridDim.x = 16
  const int h = (swzb >> 4) & 15;
  const int b = swzb >> 8;
  const int tid = threadIdx.x, lane = tid & 63, wv = tid >> 6;
  const int lrow = lane & 15, hi = lane >> 4;

  __shared__ __bf16 sK[2][128 * 64];
  __shared__ __bf16 sV0[2][64 * 64];
  __shared__ __bf16 sV1[2][64 * 64];

  const size_t base = (size_t)b * SEQ * 3072;
  const __bf16* Qb = qkv + base + h * 64;
  const __bf16* Kb = qkv + base + 1024 + h * 64;
  const __bf16* vTb = vT + ((size_t)b * 1024 + h * 64) * SEQ;
  const float* maskb = mask2 + (size_t)b * SEQ;

  const int q0 = qb * 128 + wv * 16;
  const bf16x8 qf0 = *(const bf16x8*)&Qb[(size_t)(q0 + lrow) * 3072 + hi * 8];
  const bf16x8 qf1 = *(const bf16x8*)&Qb[(size_t)(q0 + lrow) * 3072 + 32 + hi * 8];

  float m_r = -3e38f, l_r = 0.f;
  f32x4 o[4];
#pragma unroll
  for (int d = 0; d < 4; ++d) o[d] = f32x4{0.f, 0.f, 0.f, 0.f};

  const int srow = lane >> 3;
  const int scolE = ((lane & 7) ^ srow) * 8;
  const int swz = (lrow & 7) << 4;

  auto stage = [&](int t) {
    const int k0s = t * 128;
    __bf16* dK = sK[t & 1];
    __bf16* dV0 = sV0[t & 1];
    __bf16* dV1 = sV1[t & 1];
#pragma unroll
    for (int r = 0; r < 2; ++r) {
      const int rb = wv + r * 8;
      const int row = rb * 8 + srow;
      gload_lds16(Kb + (size_t)(k0s + row) * 3072 + scolE, &dK[rb * 512]);
    }
    const int vrow = wv * 8 + srow;
    gload_lds16(vTb + (size_t)vrow * SEQ + k0s + scolE, &dV0[wv * 512]);
    gload_lds16(vTb + (size_t)vrow * SEQ + k0s + 64 + scolE, &dV1[wv * 512]);
  };

  stage(0);
  const int NT = SEQ / 128;
  for (int t = 0; t < NT; ++t) {
    __syncthreads();
    if (t + 1 < NT) stage(t + 1);
    const __bf16* cK = sK[t & 1];
    const __bf16* cV0 = sV0[t & 1];
    const __bf16* cV1 = sV1[t & 1];
    const int k0 = t * 128;

    f32x4 st[8];
#pragma unroll
    for (int t4 = 0; t4 < 8; ++t4) {
      const char* rp = (const char*)cK + (t4 * 16 + lrow) * 128;
      const bf16x8 ka = *(const bf16x8*)(rp + ((hi * 16) ^ swz));
      const bf16x8 kb = *(const bf16x8*)(rp + ((64 + hi * 16) ^ swz));
      f32x4 a = f32x4{0.f, 0.f, 0.f, 0.f};
      a = __builtin_amdgcn_mfma_f32_16x16x32_bf16(ka, qf0, a, 0, 0, 0);
      a = __builtin_amdgcn_mfma_f32_16x16x32_bf16(kb, qf1, a, 0, 0, 0);
      st[t4] = a;
    }

    float pm = -3e38f;
#pragma unroll
    for (int t4 = 0; t4 < 8; ++t4) {
      const f32x4 mk = *(const f32x4*)&maskb[k0 + t4 * 16 + hi * 4];
#pragma unroll
      for (int j = 0; j < 4; ++j) {
        st[t4][j] = st[t4][j] * 0.18033688f + mk[j];
        pm = fmaxf(pm, st[t4][j]);
      }
    }
    pm = fmaxf(pm, __shfl_xor(pm, 16));
    pm = fmaxf(pm, __shfl_xor(pm, 32));

    if (__any(pm > m_r + 11.5f)) {
      const float mn = fmaxf(m_r, pm);
      const float so = __builtin_amdgcn_exp2f(m_r - mn);
      m_r = mn;
      l_r *= so;
      float so_o[4];
#pragma unroll
      for (int jj = 0; jj < 4; ++jj) so_o[jj] = __shfl(so, hi * 4 + jj);
#pragma unroll
      for (int d = 0; d < 4; ++d)
#pragma unroll
        for (int jj = 0; jj < 4; ++jj) o[d][jj] *= so_o[jj];
    }

    float rs = 0.f;
#pragma unroll
    for (int t4 = 0; t4 < 8; ++t4)
#pragma unroll
      for (int j = 0; j < 4; ++j) {
        st[t4][j] = __builtin_amdgcn_exp2f(st[t4][j] - m_r);
        rs += st[t4][j];
      }
    rs += __shfl_xor(rs, 16);
    rs += __shfl_xor(rs, 32);
    l_r += rs;

    s16x4 pa[8];
#pragma unroll
    for (int t4 = 0; t4 < 8; ++t4)
#pragma unroll
      for (int j = 0; j < 4; ++j) {
        const __bf16 pb = (__bf16)st[t4][j];
        pa[t4][j] = __builtin_bit_cast(short, pb);
      }

#pragma unroll
    for (int d = 0; d < 4; ++d) {
      const char* rp0 = (const char*)cV0 + (d * 16 + lrow) * 128;
      const char* rp1 = (const char*)cV1 + (d * 16 + lrow) * 128;
#pragma unroll
      for (int t4 = 0; t4 < 4; ++t4) {
        const s16x4 vb0 = *(const s16x4*)(rp0 + ((t4 * 32 + hi * 8) ^ swz));
        o[d] = __builtin_amdgcn_mfma_f32_16x16x16bf16_1k(pa[t4], vb0, o[d], 0, 0, 0);
        const s16x4 vb1 = *(const s16x4*)(rp1 + ((t4 * 32 + hi * 8) ^ swz));
        o[d] = __builtin_amdgcn_mfma_f32_16x16x16bf16_1k(pa[4 + t4], vb1, o[d], 0, 0, 0);
      }
    }
  }

  __syncthreads();
  float linv[4];
#pragma unroll
  for (int jj = 0; jj < 4; ++jj) linv[jj] = 1.0f / __shfl(l_r, hi * 4 + jj);
#pragma unroll
  for (int d = 0; d < 4; ++d)
#pragma unroll
    for (int jj = 0; jj < 4; ++jj)
      out[((size_t)b * SEQ + q0 + hi * 4 + jj) * DMODEL + h * 64 + d * 16 + lrow] =
          (__bf16)(o[d][jj] * linv[jj]);
}

// ---------------------------------------------------------------------------
// out = LayerNorm(x + y [+ y2]) * g + beta ; y/y2 nullable.
// ---------------------------------------------------------------------------
__global__ __launch_bounds__(256) void k_add_ln(
    const float* __restrict__ x, const float* __restrict__ y,
    const float* __restrict__ y2, const float* __restrict__ g,
    const float* __restrict__ be, float* __restrict__ of,
    __bf16* __restrict__ ob) {
  const int row = blockIdx.x, tid = threadIdx.x;
  const float4 a = ((const float4*)(x + (size_t)row * 1024))[tid];
  float4 b = {0.f, 0.f, 0.f, 0.f};
  if (y) b = ((const float4*)(y + (size_t)row * 1024))[tid];
  float4 c = {0.f, 0.f, 0.f, 0.f};
  if (y2) c = ((const float4*)(y2 + (size_t)row * 1024))[tid];
  const float v0 = a.x + b.x + c.x, v1 = a.y + b.y + c.y;
  const float v2 = a.z + b.z + c.z, v3 = a.w + b.w + c.w;
  float s = v0 + v1 + v2 + v3;
  float s2 = v0 * v0 + v1 * v1 + v2 * v2 + v3 * v3;
#pragma unroll
  for (int off = 32; off > 0; off >>= 1) {
    s += __shfl_xor(s, off);
    s2 += __shfl_xor(s2, off);
  }
  __shared__ float red[2][4];
  const int wv = tid >> 6, lane = tid & 63;
  if (lane == 0) { red[0][wv] = s; red[1][wv] = s2; }
  __syncthreads();
  s = red[0][0] + red[0][1] + red[0][2] + red[0][3];
  s2 = red[1][0] + red[1][1] + red[1][2] + red[1][3];
  const float mean = s * (1.0f / 1024.0f);
  const float var = s2 * (1.0f / 1024.0f) - mean * mean;
  const float rstd = rsqrtf(var + 1e-5f);
  const float4 gg = ((const float4*)g)[tid];
  const float4 bt = ((const float4*)be)[tid];
  float4 r;
  r.x = (v0 - mean) * rstd * gg.x + bt.x;
  r.y = (v1 - mean) * rstd * gg.y + bt.y;
  r.z = (v2 - mean) * rstd * gg.z + bt.z;
  r.w = (v3 - mean) * rstd * gg.w + bt.w;
  ((float4*)(of + (size_t)row * 1024))[tid] = r;
  if (ob) {
    bf16x4 rb;
    rb[0] = (__bf16)r.x; rb[1] = (__bf16)r.y; rb[2] = (__bf16)r.z; rb[3] = (__bf16)r.w;
    *(bf16x4*)(ob + (size_t)row * 1024 + tid * 4) = rb;
  }
}

// ---------------------------------------------------------------------------
extern "C" void kernel_launch(void* const* d_in, const int* in_sizes, int n_in,
                              void* d_out, int out_size, void* d_ws, size_t ws_size,
                              hipStream_t stream) {
  const float* x = (const float*)d_in[0];
  const float* src_mask = (const float*)d_in[1];
  const float* w_q = (const float*)d_in[2];
  const float* b_q = (const float*)d_in[3];
  const float* w_k = (const float*)d_in[4];
  const float* b_k = (const float*)d_in[5];
  const float* w_v = (const float*)d_in[6];
  const float* b_v = (const float*)d_in[7];
  const float* w_o = (const float*)d_in[8];
  const float* b_o = (const float*)d_in[9];
  const float* w_ff1 = (const float*)d_in[10];
  const float* b_ff1 = (const float*)d_in[11];
  const float* w_ff2 = (const float*)d_in[12];
  const float* b_ff2 = (const float*)d_in[13];
  const float* ln1_g = (const float*)d_in[14];
  const float* ln1_b = (const float*)d_in[15];
  const float* ln2_g = (const float*)d_in[16];
  const float* ln2_b = (const float*)d_in[17];

  char* ws = (char*)d_ws;
  constexpr size_t O_WQKVT = 0;
  constexpr size_t O_WOT = O_WQKVT + 3072ull * 1024 * 2;
  constexpr size_t O_WFF1T = O_WOT + 1024ull * 1024 * 2;
  constexpr size_t O_WFF2T = O_WFF1T + 4096ull * 1024 * 2;
  constexpr size_t O_BQKV = O_WFF2T + 4096ull * 1024 * 2;
  constexpr size_t O_XBF = O_BQKV + 3072ull * 4;
  constexpr size_t O_QKV = O_XBF + 4096ull * 1024 * 2;
  constexpr size_t O_ATTN = O_QKV + 4096ull * 3072 * 2;
  constexpr size_t O_PROJ = O_ATTN + 4096ull * 1024 * 2;
  constexpr size_t O_H1F = O_PROJ + 4096ull * 1024 * 4;
  constexpr size_t O_H1B = O_H1F + 4096ull * 1024 * 4;
  constexpr size_t O_MASK2 = O_H1B + 4096ull * 1024 * 2;   // 16KB
  constexpr size_t O_VT = O_PROJ;    // vT: dead before proj written
  constexpr size_t O_FF = O_QKV;     // ffb 32MB spans QKV+ATTN
  constexpr size_t O_FF2A = O_PROJ;  // 16MB (proj dead after ln1)
  constexpr size_t O_FF2B = 0;       // 16MB over dead wqkvT+woT+wff1T

  __bf16* wqkvT = (__bf16*)(ws + O_WQKVT);
  __bf16* woT = (__bf16*)(ws + O_WOT);
  __bf16* wff1T = (__bf16*)(ws + O_WFF1T);
  __bf16* wff2T = (__bf16*)(ws + O_WFF2T);
  float* bqkv = (float*)(ws + O_BQKV);
  __bf16* xbf = (__bf16*)(ws + O_XBF);
  __bf16* qkvb = (__bf16*)(ws + O_QKV);
  __bf16* attnb = (__bf16*)(ws + O_ATTN);
  float* proj = (float*)(ws + O_PROJ);
  float* h1f = (float*)(ws + O_H1F);
  __bf16* h1b = (__bf16*)(ws + O_H1B);
  float* mask2 = (float*)(ws + O_MASK2);
  __bf16* vT = (__bf16*)(ws + O_VT);
  __bf16* ffb = (__bf16*)(ws + O_FF);
  float* ff2a = (float*)(ws + O_FF2A);
  float* ff2b = (float*)(ws + O_FF2B);

  // fused prep: all transposes + concat + mask scale + x->bf16, ONE dispatch
  k_prep<<<16412, 256, 0, stream>>>(w_q, w_k, w_v, w_o, w_ff1, w_ff2,
                                    wqkvT, woT, wff1T, wff2T,
                                    b_q, b_k, b_v, bqkv,
                                    src_mask, mask2, x, xbf);

  // fused QKV projection (256^2 counted-vmcnt pipeline)
  k_gemm256<false, __bf16><<<dim3(12, 16), 512, 0, stream>>>(xbf, wqkvT, bqkv, qkvb,
                                                             MTOT, 3072, 1024);
  // V transpose
  k_transpose_v<<<dim3(64, 32, 2), 256, 0, stream>>>(qkvb, vT);
  // attention (QBLK=128 x KVBLK=128 + XCD-clustered K/V reuse)
  k_attn<<<dim3(SEQ / 128, NHEAD, BATCH), 512, 0, stream>>>(qkvb, vT, mask2, attnb);
  // output projection
  k_gemm<2, false, float><<<dim3(8, 64, 1), 256, 0, stream>>>(
      attnb, woT, b_o, proj, nullptr, MTOT, 1024, 1024, 1024);
  // ln1
  k_add_ln<<<4096, 256, 0, stream>>>(x, proj, nullptr, ln1_g, ln1_b, h1f, h1b);
  // ff1 + relu (256^2 counted-vmcnt pipeline)
  k_gemm256<true, __bf16><<<dim3(16, 16), 512, 0, stream>>>(h1b, wff1T, b_ff1, ffb,
                                                            MTOT, DFF, 1024);
  // ff2 split-K x2 in ONE dispatch (4 blocks/CU co-resident)
  k_gemm<2, false, float><<<dim3(8, 64, 2), 256, 0, stream>>>(
      ffb, wff2T, b_ff2, ff2a, ff2b, MTOT, 1024, DFF, 2048);
  // ln2 -> d_out: ff2a + h1 + ff2b
  k_add_ln<<<4096, 256, 0, stream>>>(ff2a, h1f, ff2b, ln2_g, ln2_b,
                                     (float*)d_out, nullptr);
}

// Round 25
// 235.231 us; speedup vs baseline: 1.2166x; 1.0343x over previous
//
#include <hip/hip_runtime.h>
#include <cstdint>
#include <cstddef>

#define BATCH 2
#define SEQ 2048
#define DMODEL 1024
#define NHEAD 16
#define DFF 4096
#define MTOT (BATCH * SEQ) /* 4096 */

typedef __bf16 bf16x8 __attribute__((ext_vector_type(8)));
typedef __bf16 bf16x4 __attribute__((ext_vector_type(4)));
typedef short s16x4 __attribute__((ext_vector_type(4)));
typedef float f32x4 __attribute__((ext_vector_type(4)));

#define S_BARRIER() __builtin_amdgcn_s_barrier()
#define SCHED_FENCE() __builtin_amdgcn_sched_barrier(0)
#define VMCNT8() asm volatile("s_waitcnt vmcnt(8)" ::: "memory")
#define VMCNT4() asm volatile("s_waitcnt vmcnt(4)" ::: "memory")
#define VMCNT0() asm volatile("s_waitcnt vmcnt(0)" ::: "memory")

// async global->LDS, 16B/lane; LDS dest = wave-uniform base + lane*16 (m104).
__device__ __forceinline__ void gload_lds16(const void* g, void* l) {
  __builtin_amdgcn_global_load_lds(
      (__attribute__((address_space(1))) void*)(uintptr_t)g,
      (__attribute__((address_space(3))) void*)(uint32_t)(uintptr_t)l,
      16, 0, 0);
}

// dtype-generic 4-wide loader for LN inputs
__device__ __forceinline__ float4 load4(const float* p, size_t idx) {
  return ((const float4*)p)[idx];
}
__device__ __forceinline__ float4 load4(const __bf16* p, size_t idx) {
  const bf16x4 v = ((const bf16x4*)p)[idx];
  return float4{(float)v[0], (float)v[1], (float)v[2], (float)v[3]};
}

// ---------------------------------------------------------------------------
// Fused prep (R24-verified): all weight transposes + bias concat + mask scale
// + x->bf16 in ONE dispatch. Block role by flat blockIdx range.
// ---------------------------------------------------------------------------
__global__ __launch_bounds__(256) void k_prep(
    const float* __restrict__ wq, const float* __restrict__ wk,
    const float* __restrict__ wv, const float* __restrict__ wo,
    const float* __restrict__ wff1, const float* __restrict__ wff2,
    __bf16* __restrict__ wqkvT, __bf16* __restrict__ woT,
    __bf16* __restrict__ wff1T, __bf16* __restrict__ wff2T,
    const float* __restrict__ bq, const float* __restrict__ bk,
    const float* __restrict__ bv, float* __restrict__ bqkv,
    const float* __restrict__ mask, float* __restrict__ mask2,
    const float* __restrict__ x, __bf16* __restrict__ xbf) {
  int f = blockIdx.x;
  if (f < 12) {  // concat3
    const int i = f * 256 + threadIdx.x;
    if (i < 3072)
      bqkv[i] = (i < 1024) ? bq[i] : (i < 2048) ? bk[i - 1024] : bv[i - 2048];
    return;
  }
  f -= 12;
  if (f < 16) {  // scale_mask
    const int i = f * 256 + threadIdx.x;
    if (i < BATCH * SEQ) mask2[i] = mask[i] * 1.44269504f;
    return;
  }
  f -= 16;
  if (f < 4096) {  // cvt_bf16
    const int i = (f * 256 + threadIdx.x) * 4;
    const float4 v = *(const float4*)(x + i);
    bf16x4 r;
    r[0] = (__bf16)v.x; r[1] = (__bf16)v.y; r[2] = (__bf16)v.z; r[3] = (__bf16)v.w;
    *(bf16x4*)(xbf + i) = r;
    return;
  }
  f -= 4096;
  const float* src;
  __bf16* dst;
  int Kd, Nd, n0, k0;
  if (f < 3072) {  // q/k/v
    const int zz = f / 1024, r = f % 1024;
    src = (zz == 0) ? wq : (zz == 1) ? wk : wv;
    dst = wqkvT + (size_t)zz * 1024 * 1024;
    Kd = 1024; Nd = 1024; n0 = (r & 31) * 32; k0 = (r >> 5) * 32;
  } else if (f < 4096) {  // wo
    const int r = f - 3072;
    src = wo; dst = woT;
    Kd = 1024; Nd = 1024; n0 = (r & 31) * 32; k0 = (r >> 5) * 32;
  } else if (f < 8192) {  // ff1
    const int r = f - 4096;
    src = wff1; dst = wff1T;
    Kd = 1024; Nd = 4096; n0 = (r & 127) * 32; k0 = (r >> 7) * 32;
  } else {  // ff2
    const int r = f - 8192;
    src = wff2; dst = wff2T;
    Kd = 4096; Nd = 1024; n0 = (r & 31) * 32; k0 = (r >> 5) * 32;
  }
  __shared__ float t[32][33];
  const int tx = threadIdx.x & 31, ty = threadIdx.x >> 5;
#pragma unroll
  for (int i = ty; i < 32; i += 8) t[i][tx] = src[(size_t)(k0 + i) * Nd + n0 + tx];
  __syncthreads();
#pragma unroll
  for (int i = ty; i < 32; i += 8)
    dst[(size_t)(n0 + i) * Kd + k0 + tx] = (__bf16)t[tx][i];
}

// ---------------------------------------------------------------------------
// Vectorized V transpose: qkvb[b*S+s][2048+c] -> vT[b*1024+c][s].
// 64x64 tiles, bf16x8 (16B/lane) global loads AND stores via padded LDS
// (was 2B-scalar per element). Grid (32, 16, 2).
// ---------------------------------------------------------------------------
__global__ __launch_bounds__(256) void k_transpose_v(
    const __bf16* __restrict__ qkvb, __bf16* __restrict__ vT) {
  __shared__ __bf16 t[64][72];  // +8 pad
  const int s0 = blockIdx.x * 64, c0 = blockIdx.y * 64, b = blockIdx.z;
  const int vc = threadIdx.x & 7;        // vector column (8 bf16 each)
  const int rw = threadIdx.x >> 3;       // 0..31
#pragma unroll
  for (int half = 0; half < 2; ++half) {
    const int row = rw + half * 32;
    *(bf16x8*)&t[row][vc * 8] =
        *(const bf16x8*)&qkvb[(size_t)(b * SEQ + s0 + row) * 3072 + 2048 + c0 + vc * 8];
  }
  __syncthreads();
#pragma unroll
  for (int half = 0; half < 2; ++half) {
    const int c = rw + half * 32;        // output row = channel
    bf16x8 v;
#pragma unroll
    for (int i = 0; i < 8; ++i) v[i] = t[vc * 8 + i][c];
    *(bf16x8*)&vT[((size_t)b * 1024 + c0 + c) * SEQ + s0 + vc * 8] = v;
  }
}

// ---------------------------------------------------------------------------
// 256x256 deep-pipelined MFMA GEMM (T3+T4 counted-vmcnt, ALL-BUILTIN MFMAs).
// R16-verified. 512 thr = 8 waves (2M x 4N); wave owns 128x64.
// ---------------------------------------------------------------------------
template <bool RELU, typename OutT>
__global__ __launch_bounds__(512) void k_gemm256(
    const __bf16* __restrict__ A, const __bf16* __restrict__ BT,
    const float* __restrict__ bias, OutT* __restrict__ C,
    int M, int N, int K) {
  __shared__ __align__(16) __bf16 sA[4 * 8192];
  __shared__ __align__(16) __bf16 sB[4 * 8192];
  const int tid = threadIdx.x, lane = tid & 63, wv = tid >> 6;
  const int wm = wv >> 2, wn = wv & 3;
  const int lrow = lane & 15, hi = lane >> 4;
  const int nwg = gridDim.x * gridDim.y;
  const int flat = blockIdx.y * gridDim.x + blockIdx.x;
  const int cpx = nwg >> 3;
  const int swzb = (flat & 7) * cpx + (flat >> 3);
  const int m0 = (swzb / gridDim.x) * 256;
  const int n0 = (swzb % gridDim.x) * 256;
  const int NT = K >> 6;

  const int lsub = lane >> 2;
  const int gg = (lane & 3) ^ ((lane >> 3) & 3);
  const int gr = hi ^ ((lrow >> 1) & 3);

  f32x4 acc[8][4];
#pragma unroll
  for (int r = 0; r < 8; ++r)
#pragma unroll
    for (int c = 0; c < 4; ++c) acc[r][c] = f32x4{0.f, 0.f, 0.f, 0.f};

  auto stage = [&](int p) {
    const int tile = p >> 1;
    const int slot = (((tile & 1) * 2) + (p & 1)) * 8192;
    const int kcol = tile * 64 + (p & 1) * 32 + gg * 8;
#pragma unroll
    for (int i = 0; i < 2; ++i) {
      const int c = wv * 2 + i;
      gload_lds16(A + (size_t)(m0 + c * 16 + lsub) * K + kcol, &sA[slot + c * 512]);
      gload_lds16(BT + (size_t)(n0 + c * 16 + lsub) * K + kcol, &sB[slot + c * 512]);
    }
  };

  auto compute = [&](int p) {
    const int slot = ((((p >> 1) & 1) * 2) + (p & 1)) * 8192;
    bf16x8 af[8], bfv[4];
#pragma unroll
    for (int r = 0; r < 8; ++r)
      af[r] = *(const bf16x8*)&sA[slot + (wm * 128 + r * 16 + lrow) * 32 + gr * 8];
#pragma unroll
    for (int c = 0; c < 4; ++c)
      bfv[c] = *(const bf16x8*)&sB[slot + (wn * 64 + c * 16 + lrow) * 32 + gr * 8];
    __builtin_amdgcn_s_setprio(1);
#pragma unroll
    for (int r = 0; r < 8; ++r)
#pragma unroll
      for (int c = 0; c < 4; ++c)
        acc[r][c] = __builtin_amdgcn_mfma_f32_16x16x32_bf16(af[r], bfv[c],
                                                            acc[r][c], 0, 0, 0);
    __builtin_amdgcn_s_setprio(0);
  };

  stage(0); stage(1); stage(2);
  int p = 0;
  for (; p < 2 * NT - 3; ++p) {
    VMCNT8(); S_BARRIER(); SCHED_FENCE();
    stage(p + 3);
    compute(p);
  }
  VMCNT8(); S_BARRIER(); SCHED_FENCE(); compute(p); ++p;
  VMCNT4(); S_BARRIER(); SCHED_FENCE(); compute(p); ++p;
  VMCNT0(); S_BARRIER(); SCHED_FENCE(); compute(p);

#pragma unroll
  for (int r = 0; r < 8; ++r) {
    const int row = m0 + wm * 128 + r * 16 + hi * 4;
#pragma unroll
    for (int c = 0; c < 4; ++c) {
      const int col = n0 + wn * 64 + c * 16 + lrow;
      const float bb = bias[col];
#pragma unroll
      for (int j = 0; j < 4; ++j) {
        float v = acc[r][c][j] + bb;
        if (RELU) v = fmaxf(v, 0.f);
        C[(size_t)(row + j) * N + col] = (OutT)v;
      }
    }
  }
}

// ---------------------------------------------------------------------------
// bf16 MFMA GEMM (R9-verified body + XCD swizzle) with single-dispatch
// split-K: blockIdx.z selects K-range, output buffer (z==0 -> C0 with bias,
// z==1 -> C1 with zero bias). BM=MF*32, BN=128, BK=64.
// ---------------------------------------------------------------------------
template <int MF, bool RELU, typename OutT>
__global__ __launch_bounds__(256) void k_gemm(
    const __bf16* __restrict__ A, const __bf16* __restrict__ BT,
    const float* __restrict__ bias, OutT* __restrict__ C0,
    OutT* __restrict__ C1, int M, int N, int lda, int KS) {
  __shared__ __bf16 sA[MF * 32 * 64];
  __shared__ __bf16 sB[128 * 64];
  const int tid = threadIdx.x, lane = tid & 63, wv = tid >> 6;
  const int wm = wv >> 1, wn = wv & 1;
  const int lrow = lane & 15, hi = lane >> 4;
  const int nwg = gridDim.x * gridDim.y;
  const int flat = blockIdx.y * gridDim.x + blockIdx.x;
  const int cpx = nwg >> 3;
  const int swzb = (flat & 7) * cpx + (flat >> 3);
  const int m0 = (swzb / gridDim.x) * (MF * 32);
  const int n0 = (swzb % gridDim.x) * 128;
  const int koff = blockIdx.z * KS;
  OutT* Cz = blockIdx.z ? C1 : C0;
  const int srow = lane >> 3;
  const int scolE = ((lane & 7) ^ srow) * 8;
  const int swz = (lrow & 7) << 4;

  f32x4 acc[MF][4];
#pragma unroll
  for (int r = 0; r < MF; ++r)
#pragma unroll
    for (int c = 0; c < 4; ++c) acc[r][c] = f32x4{0.f, 0.f, 0.f, 0.f};

  for (int k0 = 0; k0 < KS; k0 += 64) {
    __syncthreads();
#pragma unroll
    for (int rb = wv; rb < MF * 4; rb += 4) {
      const int row = rb * 8 + srow;
      gload_lds16(A + (size_t)(m0 + row) * lda + koff + k0 + scolE, &sA[rb * 512]);
    }
#pragma unroll
    for (int rb = wv; rb < 16; rb += 4) {
      const int row = rb * 8 + srow;
      gload_lds16(BT + (size_t)(n0 + row) * lda + koff + k0 + scolE, &sB[rb * 512]);
    }
    __syncthreads();
#pragma unroll
    for (int kc = 0; kc < 2; ++kc) {
      bf16x8 af[MF], bfr[4];
#pragma unroll
      for (int r = 0; r < MF; ++r) {
        const int row = wm * (MF * 16) + r * 16 + lrow;
        af[r] = *(const bf16x8*)((const char*)sA + row * 128 + ((kc * 64 + hi * 16) ^ swz));
      }
#pragma unroll
      for (int c = 0; c < 4; ++c) {
        const int row = wn * 64 + c * 16 + lrow;
        bfr[c] = *(const bf16x8*)((const char*)sB + row * 128 + ((kc * 64 + hi * 16) ^ swz));
      }
#pragma unroll
      for (int r = 0; r < MF; ++r)
#pragma unroll
        for (int c = 0; c < 4; ++c)
          acc[r][c] = __builtin_amdgcn_mfma_f32_16x16x32_bf16(af[r], bfr[c],
                                                              acc[r][c], 0, 0, 0);
    }
  }

#pragma unroll
  for (int r = 0; r < MF; ++r) {
    const int row = m0 + wm * (MF * 16) + r * 16 + hi * 4;
#pragma unroll
    for (int c = 0; c < 4; ++c) {
      const int col = n0 + wn * 64 + c * 16 + lrow;
      const float bb = (blockIdx.z == 0) ? bias[col] : 0.f;
#pragma unroll
      for (int j = 0; j < 4; ++j) {
        float v = acc[r][c][j] + bb;
        if (RELU) v = fmaxf(v, 0.f);
        Cz[(size_t)(row + j) * N + col] = (OutT)v;
      }
    }
  }
}

// ---------------------------------------------------------------------------
// Flash attention — R23-verified exactly (QBLK=128 x KVBLK=128, 8 waves,
// dbuf issue-early staging, exp2+defer-max softmax, XCD-clustered grid).
// ---------------------------------------------------------------------------
__global__ __launch_bounds__(512) void k_attn(
    const __bf16* __restrict__ qkv, const __bf16* __restrict__ vT,
    const float* __restrict__ mask2, __bf16* __restrict__ out) {
  const int nwg = gridDim.x * gridDim.y * gridDim.z;          // 512
  const int flat = (blockIdx.z * gridDim.y + blockIdx.y) * gridDim.x + blockIdx.x;
  const int cpx = nwg >> 3;                                   // 64
  const int swzb = (flat & 7) * cpx + (flat >> 3);
  const int qb = swzb & (gridDim.x - 1);
  const int h = (swzb >> 4) & 15;
  const int b = swzb >> 8;
  const int tid = threadIdx.x, lane = tid & 63, wv = tid >> 6;
  const int lrow = lane & 15, hi = lane >> 4;

  __shared__ __bf16 sK[2][128 * 64];
  __shared__ __bf16 sV0[2][64 * 64];
  __shared__ __bf16 sV1[2][64 * 64];

  const size_t base = (size_t)b * SEQ * 3072;
  const __bf16* Qb = qkv + base + h * 64;
  const __bf16* Kb = qkv + base + 1024 + h * 64;
  const __bf16* vTb = vT + ((size_t)b * 1024 + h * 64) * SEQ;
  const float* maskb = mask2 + (size_t)b * SEQ;

  const int q0 = qb * 128 + wv * 16;
  const bf16x8 qf0 = *(const bf16x8*)&Qb[(size_t)(q0 + lrow) * 3072 + hi * 8];
  const bf16x8 qf1 = *(const bf16x8*)&Qb[(size_t)(q0 + lrow) * 3072 + 32 + hi * 8];

  float m_r = -3e38f, l_r = 0.f;
  f32x4 o[4];
#pragma unroll
  for (int d = 0; d < 4; ++d) o[d] = f32x4{0.f, 0.f, 0.f, 0.f};

  const int srow = lane >> 3;
  const int scolE = ((lane & 7) ^ srow) * 8;
  const int swz = (lrow & 7) << 4;

  auto stage = [&](int t) {
    const int k0s = t * 128;
    __bf16* dK = sK[t & 1];
    __bf16* dV0 = sV0[t & 1];
    __bf16* dV1 = sV1[t & 1];
#pragma unroll
    for (int r = 0; r < 2; ++r) {
      const int rb = wv + r * 8;
      const int row = rb * 8 + srow;
      gload_lds16(Kb + (size_t)(k0s + row) * 3072 + scolE, &dK[rb * 512]);
    }
    const int vrow = wv * 8 + srow;
    gload_lds16(vTb + (size_t)vrow * SEQ + k0s + scolE, &dV0[wv * 512]);
    gload_lds16(vTb + (size_t)vrow * SEQ + k0s + 64 + scolE, &dV1[wv * 512]);
  };

  stage(0);
  const int NT = SEQ / 128;
  for (int t = 0; t < NT; ++t) {
    __syncthreads();
    if (t + 1 < NT) stage(t + 1);
    const __bf16* cK = sK[t & 1];
    const __bf16* cV0 = sV0[t & 1];
    const __bf16* cV1 = sV1[t & 1];
    const int k0 = t * 128;

    f32x4 st[8];
#pragma unroll
    for (int t4 = 0; t4 < 8; ++t4) {
      const char* rp = (const char*)cK + (t4 * 16 + lrow) * 128;
      const bf16x8 ka = *(const bf16x8*)(rp + ((hi * 16) ^ swz));
      const bf16x8 kb = *(const bf16x8*)(rp + ((64 + hi * 16) ^ swz));
      f32x4 a = f32x4{0.f, 0.f, 0.f, 0.f};
      a = __builtin_amdgcn_mfma_f32_16x16x32_bf16(ka, qf0, a, 0, 0, 0);
      a = __builtin_amdgcn_mfma_f32_16x16x32_bf16(kb, qf1, a, 0, 0, 0);
      st[t4] = a;
    }

    float pm = -3e38f;
#pragma unroll
    for (int t4 = 0; t4 < 8; ++t4) {
      const f32x4 mk = *(const f32x4*)&maskb[k0 + t4 * 16 + hi * 4];
#pragma unroll
      for (int j = 0; j < 4; ++j) {
        st[t4][j] = st[t4][j] * 0.18033688f + mk[j];
        pm = fmaxf(pm, st[t4][j]);
      }
    }
    pm = fmaxf(pm, __shfl_xor(pm, 16));
    pm = fmaxf(pm, __shfl_xor(pm, 32));

    if (__any(pm > m_r + 11.5f)) {
      const float mn = fmaxf(m_r, pm);
      const float so = __builtin_amdgcn_exp2f(m_r - mn);
      m_r = mn;
      l_r *= so;
      float so_o[4];
#pragma unroll
      for (int jj = 0; jj < 4; ++jj) so_o[jj] = __shfl(so, hi * 4 + jj);
#pragma unroll
      for (int d = 0; d < 4; ++d)
#pragma unroll
        for (int jj = 0; jj < 4; ++jj) o[d][jj] *= so_o[jj];
    }

    float rs = 0.f;
#pragma unroll
    for (int t4 = 0; t4 < 8; ++t4)
#pragma unroll
      for (int j = 0; j < 4; ++j) {
        st[t4][j] = __builtin_amdgcn_exp2f(st[t4][j] - m_r);
        rs += st[t4][j];
      }
    rs += __shfl_xor(rs, 16);
    rs += __shfl_xor(rs, 32);
    l_r += rs;

    s16x4 pa[8];
#pragma unroll
    for (int t4 = 0; t4 < 8; ++t4)
#pragma unroll
      for (int j = 0; j < 4; ++j) {
        const __bf16 pb = (__bf16)st[t4][j];
        pa[t4][j] = __builtin_bit_cast(short, pb);
      }

#pragma unroll
    for (int d = 0; d < 4; ++d) {
      const char* rp0 = (const char*)cV0 + (d * 16 + lrow) * 128;
      const char* rp1 = (const char*)cV1 + (d * 16 + lrow) * 128;
#pragma unroll
      for (int t4 = 0; t4 < 4; ++t4) {
        const s16x4 vb0 = *(const s16x4*)(rp0 + ((t4 * 32 + hi * 8) ^ swz));
        o[d] = __builtin_amdgcn_mfma_f32_16x16x16bf16_1k(pa[t4], vb0, o[d], 0, 0, 0);
        const s16x4 vb1 = *(const s16x4*)(rp1 + ((t4 * 32 + hi * 8) ^ swz));
        o[d] = __builtin_amdgcn_mfma_f32_16x16x16bf16_1k(pa[4 + t4], vb1, o[d], 0, 0, 0);
      }
    }
  }

  __syncthreads();
  float linv[4];
#pragma unroll
  for (int jj = 0; jj < 4; ++jj) linv[jj] = 1.0f / __shfl(l_r, hi * 4 + jj);
#pragma unroll
  for (int d = 0; d < 4; ++d)
#pragma unroll
    for (int jj = 0; jj < 4; ++jj)
      out[((size_t)b * SEQ + q0 + hi * 4 + jj) * DMODEL + h * 64 + d * 16 + lrow] =
          (__bf16)(o[d][jj] * linv[jj]);
}

// ---------------------------------------------------------------------------
// out = LayerNorm(x + y [+ y2]) * g + beta. Inputs dtype-templated (f32 or
// bf16); y/y2 nullable; f32 out (of) and bf16 out (ob) each optional.
// ---------------------------------------------------------------------------
template <typename TX, typename TY, typename TY2>
__global__ __launch_bounds__(256) void k_add_ln(
    const TX* __restrict__ x, const TY* __restrict__ y,
    const TY2* __restrict__ y2, const float* __restrict__ g,
    const float* __restrict__ be, float* __restrict__ of,
    __bf16* __restrict__ ob) {
  const int row = blockIdx.x, tid = threadIdx.x;
  const size_t idx = (size_t)row * 256 + tid;
  const float4 a = load4(x, idx);
  float4 b = {0.f, 0.f, 0.f, 0.f};
  if (y) b = load4(y, idx);
  float4 c = {0.f, 0.f, 0.f, 0.f};
  if (y2) c = load4(y2, idx);
  const float v0 = a.x + b.x + c.x, v1 = a.y + b.y + c.y;
  const float v2 = a.z + b.z + c.z, v3 = a.w + b.w + c.w;
  float s = v0 + v1 + v2 + v3;
  float s2 = v0 * v0 + v1 * v1 + v2 * v2 + v3 * v3;
#pragma unroll
  for (int off = 32; off > 0; off >>= 1) {
    s += __shfl_xor(s, off);
    s2 += __shfl_xor(s2, off);
  }
  __shared__ float red[2][4];
  const int wv = tid >> 6, lane = tid & 63;
  if (lane == 0) { red[0][wv] = s; red[1][wv] = s2; }
  __syncthreads();
  s = red[0][0] + red[0][1] + red[0][2] + red[0][3];
  s2 = red[1][0] + red[1][1] + red[1][2] + red[1][3];
  const float mean = s * (1.0f / 1024.0f);
  const float var = s2 * (1.0f / 1024.0f) - mean * mean;
  const float rstd = rsqrtf(var + 1e-5f);
  const float4 gg = ((const float4*)g)[tid];
  const float4 bt = ((const float4*)be)[tid];
  float4 r;
  r.x = (v0 - mean) * rstd * gg.x + bt.x;
  r.y = (v1 - mean) * rstd * gg.y + bt.y;
  r.z = (v2 - mean) * rstd * gg.z + bt.z;
  r.w = (v3 - mean) * rstd * gg.w + bt.w;
  if (of) ((float4*)(of + (size_t)row * 1024))[tid] = r;
  if (ob) {
    bf16x4 rb;
    rb[0] = (__bf16)r.x; rb[1] = (__bf16)r.y; rb[2] = (__bf16)r.z; rb[3] = (__bf16)r.w;
    *(bf16x4*)(ob + (size_t)row * 1024 + tid * 4) = rb;
  }
}

// ---------------------------------------------------------------------------
extern "C" void kernel_launch(void* const* d_in, const int* in_sizes, int n_in,
                              void* d_out, int out_size, void* d_ws, size_t ws_size,
                              hipStream_t stream) {
  const float* x = (const float*)d_in[0];
  const float* src_mask = (const float*)d_in[1];
  const float* w_q = (const float*)d_in[2];
  const float* b_q = (const float*)d_in[3];
  const float* w_k = (const float*)d_in[4];
  const float* b_k = (const float*)d_in[5];
  const float* w_v = (const float*)d_in[6];
  const float* b_v = (const float*)d_in[7];
  const float* w_o = (const float*)d_in[8];
  const float* b_o = (const float*)d_in[9];
  const float* w_ff1 = (const float*)d_in[10];
  const float* b_ff1 = (const float*)d_in[11];
  const float* w_ff2 = (const float*)d_in[12];
  const float* b_ff2 = (const float*)d_in[13];
  const float* ln1_g = (const float*)d_in[14];
  const float* ln1_b = (const float*)d_in[15];
  const float* ln2_g = (const float*)d_in[16];
  const float* ln2_b = (const float*)d_in[17];

  char* ws = (char*)d_ws;
  constexpr size_t O_WQKVT = 0;
  constexpr size_t O_WOT = O_WQKVT + 3072ull * 1024 * 2;
  constexpr size_t O_WFF1T = O_WOT + 1024ull * 1024 * 2;
  constexpr size_t O_WFF2T = O_WFF1T + 4096ull * 1024 * 2;
  constexpr size_t O_BQKV = O_WFF2T + 4096ull * 1024 * 2;
  constexpr size_t O_XBF = O_BQKV + 3072ull * 4;
  constexpr size_t O_QKV = O_XBF + 4096ull * 1024 * 2;
  constexpr size_t O_ATTN = O_QKV + 4096ull * 3072 * 2;
  constexpr size_t O_PROJ = O_ATTN + 4096ull * 1024 * 2;   // region reused 3x
  constexpr size_t O_H1F = O_PROJ + 4096ull * 1024 * 4;
  constexpr size_t O_H1B = O_H1F + 4096ull * 1024 * 4;
  constexpr size_t O_MASK2 = O_H1B + 4096ull * 1024 * 2;   // 16KB
  constexpr size_t O_VT = O_PROJ;    // vT (8MB): dead once proj written
  constexpr size_t O_FF = O_QKV;     // ffb 32MB spans QKV+ATTN
  constexpr size_t O_PROJB = O_PROJ; // proj bf16 8MB (after vT dead)
  constexpr size_t O_FF2A = O_PROJ;  // ff2a bf16 8MB (projb dead after ln1)
  constexpr size_t O_FF2B = 0;       // ff2b bf16 8MB over dead wqkvT+woT

  __bf16* wqkvT = (__bf16*)(ws + O_WQKVT);
  __bf16* woT = (__bf16*)(ws + O_WOT);
  __bf16* wff1T = (__bf16*)(ws + O_WFF1T);
  __bf16* wff2T = (__bf16*)(ws + O_WFF2T);
  float* bqkv = (float*)(ws + O_BQKV);
  __bf16* xbf = (__bf16*)(ws + O_XBF);
  __bf16* qkvb = (__bf16*)(ws + O_QKV);
  __bf16* attnb = (__bf16*)(ws + O_ATTN);
  __bf16* projb = (__bf16*)(ws + O_PROJB);
  __bf16* h1b = (__bf16*)(ws + O_H1B);
  float* mask2 = (float*)(ws + O_MASK2);
  __bf16* vT = (__bf16*)(ws + O_VT);
  __bf16* ffb = (__bf16*)(ws + O_FF);
  __bf16* ff2a = (__bf16*)(ws + O_FF2A);
  __bf16* ff2b = (__bf16*)(ws + O_FF2B);

  // fused prep: all transposes + concat + mask scale + x->bf16, ONE dispatch
  k_prep<<<16412, 256, 0, stream>>>(w_q, w_k, w_v, w_o, w_ff1, w_ff2,
                                    wqkvT, woT, wff1T, wff2T,
                                    b_q, b_k, b_v, bqkv,
                                    src_mask, mask2, x, xbf);

  // fused QKV projection (256^2 counted-vmcnt pipeline)
  k_gemm256<false, __bf16><<<dim3(12, 16), 512, 0, stream>>>(xbf, wqkvT, bqkv, qkvb,
                                                             MTOT, 3072, 1024);
  // V transpose (vectorized 64x64 tiles)
  k_transpose_v<<<dim3(32, 16, 2), 256, 0, stream>>>(qkvb, vT);
  // attention (QBLK=128 x KVBLK=128 + XCD-clustered K/V reuse)
  k_attn<<<dim3(SEQ / 128, NHEAD, BATCH), 512, 0, stream>>>(qkvb, vT, mask2, attnb);
  // output projection -> bf16
  k_gemm<2, false, __bf16><<<dim3(8, 64, 1), 256, 0, stream>>>(
      attnb, woT, b_o, projb, nullptr, MTOT, 1024, 1024, 1024);
  // ln1: h1 = LN(x + proj) -> bf16 only
  k_add_ln<float, __bf16, float><<<4096, 256, 0, stream>>>(
      x, projb, (const float*)nullptr, ln1_g, ln1_b, nullptr, h1b);
  // ff1 + relu (256^2 counted-vmcnt pipeline)
  k_gemm256<true, __bf16><<<dim3(16, 16), 512, 0, stream>>>(h1b, wff1T, b_ff1, ffb,
                                                            MTOT, DFF, 1024);
  // ff2 split-K x2 in ONE dispatch, bf16 partials
  k_gemm<2, false, __bf16><<<dim3(8, 64, 2), 256, 0, stream>>>(
      ffb, wff2T, b_ff2, ff2a, ff2b, MTOT, 1024, DFF, 2048);
  // ln2 -> d_out: ff2a + h1b + ff2b (all bf16 in, f32 out)
  k_add_ln<__bf16, __bf16, __bf16><<<4096, 256, 0, stream>>>(
      ff2a, h1b, ff2b, ln2_g, ln2_b, (float*)d_out, nullptr);
}